// Round 12
// baseline (1508.302 us; speedup 1.0000x reference)
//
#include <hip/hip_runtime.h>
#include <cstdio>
#include <cstdint>

// ---------------------------------------------------------------------------
// HopfieldPoolingRouter on MI355X — V-free, fixed-base softmax, mergeless
// hop chain (atomic block-partial accumulation, q recomputed on the fly).
//   k: KB = LN(mem)@WTk^T + BKVk  (bf16 MFMA, BK=64, swizzled, vmcnt(8))
//   slot buffers: ACC[7][32][48], L[7][32].  slot0 = q0 (L=1).
//   hop pass s (s=0..4): q = 0.25*ACC[s]/L[s]; stream KB; block-reduce;
//     atomicAdd into ACC[s+1],L[s+1]; block 0 zeroes slot s+2.
//   escore: q from slot 5; writes S; atomicAdd l into L[6].
//   upass: w = exp(S)/L[6]; u = sum w*XH  (rank-32)
//   outproj: out = u@WTv^T + BKVv  (v eliminated);  pooled/norm/sim/top4.
// ---------------------------------------------------------------------------

#define NMEM 100000
#define NPAD 100096          // 782 * 128
#define HOPB 1024            // hop-pass blocks
#define CBLK 98              // rows per hop block (1024*98 >= 100000)
#define UKS  512
#define UROWS 196
#define SCALING_ 0.25f

typedef __attribute__((ext_vector_type(8))) short bf16x8;
typedef __attribute__((ext_vector_type(4))) float f32x4;

__device__ __forceinline__ unsigned short f2bf(float f) {
  union { float f; unsigned u; } c; c.f = f;
  unsigned u = c.u + 0x7fffu + ((c.u >> 16) & 1u);   // RNE
  return (unsigned short)(u >> 16);
}
__device__ __forceinline__ float bf2f(unsigned short h) {
  union { unsigned u; float f; } c; c.u = ((unsigned)h) << 16;
  return c.f;
}
__device__ __forceinline__ void gl_lds16(const void* g, void* l) {
  __builtin_amdgcn_global_load_lds(
      (const __attribute__((address_space(1))) unsigned int*)g,
      (__attribute__((address_space(3))) unsigned int*)l, 16, 0, 0);
}

__device__ __forceinline__ bool bet(float s, int n, float v, int i) {
  return (s > v) || (s == v && n < i);
}
struct Top4 {
  float v0, v1, v2, v3;
  int   i0, i1, i2, i3;
  __device__ __forceinline__ void init() {
    v0 = v1 = v2 = v3 = -INFINITY;
    i0 = i1 = i2 = i3 = 0x7fffffff;
  }
  __device__ __forceinline__ void ins(float s, int n) {
    bool c0 = bet(s, n, v0, i0), c1 = bet(s, n, v1, i1);
    bool c2 = bet(s, n, v2, i2), c3 = bet(s, n, v3, i3);
    float w0 = c0 ? s : v0;             int j0 = c0 ? n : i0;
    float w1 = c0 ? v0 : (c1 ? s : v1); int j1 = c0 ? i0 : (c1 ? n : i1);
    float w2 = c1 ? v1 : (c2 ? s : v2); int j2 = c1 ? i1 : (c2 ? n : i2);
    float w3 = c2 ? v2 : (c3 ? s : v3); int j3 = c2 ? i2 : (c3 ? n : i3);
    v0 = w0; v1 = w1; v2 = w2; v3 = w3;
    i0 = j0; i1 = j1; i2 = j2; i3 = j3;
  }
};
__device__ __forceinline__ void bfly(Top4& a, int omax) {
  for (int o = omax; o >= 1; o >>= 1) {
    float w0 = __shfl_xor(a.v0, o), w1 = __shfl_xor(a.v1, o);
    float w2 = __shfl_xor(a.v2, o), w3 = __shfl_xor(a.v3, o);
    int   j0 = __shfl_xor(a.i0, o), j1 = __shfl_xor(a.i1, o);
    int   j2 = __shfl_xor(a.i2, o), j3 = __shfl_xor(a.i3, o);
    a.ins(w0, j0); a.ins(w1, j1); a.ins(w2, j2); a.ins(w3, j3);
  }
}

// ------------------------- weight folding ----------------------------------
__global__ __launch_bounds__(256) void k_fold_wt(const float* __restrict__ Wk,
                                                 const float* __restrict__ Wv,
                                                 const float* __restrict__ gs,
                                                 const float* __restrict__ gp,
                                                 unsigned short* __restrict__ WT) {
  __shared__ float ts[64][65];
  int d0 = blockIdx.x * 64, j0 = blockIdx.y * 64, z = blockIdx.z;
  const float* W = z ? Wv : Wk;
  const float* g = z ? gp : gs;
  int t = threadIdx.x, c = t & 63, r4 = t >> 6;
#pragma unroll
  for (int p = 0; p < 16; ++p) {
    int r = p * 4 + r4;
    ts[r][c] = g[d0 + r] * W[(size_t)(d0 + r) * 768 + j0 + c];
  }
  __syncthreads();
#pragma unroll
  for (int p = 0; p < 16; ++p) {
    int jr = p * 4 + r4;
    WT[(size_t)(z * 768 + j0 + jr) * 768 + d0 + c] = f2bf(ts[c][jr]);
  }
}

__global__ __launch_bounds__(256) void k_fold_bias(const float* __restrict__ Wk,
                                                   const float* __restrict__ Wv,
                                                   const float* __restrict__ bs,
                                                   const float* __restrict__ bp,
                                                   float* __restrict__ PB) {
  int jc = blockIdx.x, dz = blockIdx.y, t = threadIdx.x;
  int j = jc * 256 + t;
  const float* W  = (j < 768) ? Wk : Wv;
  const float* bb = (j < 768) ? bs : bp;
  int jj = (j < 768) ? j : j - 768;
  float a = 0.f;
  int dend = dz * 96 + 96;
  for (int d = dz * 96; d < dend; ++d) a = fmaf(bb[d], W[(size_t)d * 768 + jj], a);
  PB[dz * 1536 + j] = a;
}

__global__ __launch_bounds__(256) void k_bias_red(const float* __restrict__ PB,
                                                  const float* __restrict__ bk,
                                                  const float* __restrict__ bv,
                                                  float* __restrict__ BKV) {
  int j = blockIdx.x * 256 + threadIdx.x;
  float a = (j < 768) ? bk[j] : bv[j - 768];
#pragma unroll
  for (int dz = 0; dz < 8; ++dz) a += PB[dz * 1536 + j];
  BKV[j] = a;
}

// ------------------------- q0 -> ACC slot 0 (L=1) ---------------------------
__global__ __launch_bounds__(256) void k_q0(const float* __restrict__ qe,
                                            const float* __restrict__ gq,
                                            const float* __restrict__ bq_ln,
                                            const float* __restrict__ Wq,
                                            const float* __restrict__ bq,
                                            float* __restrict__ ACCb,
                                            float* __restrict__ Lb) {
  int b = blockIdx.y, jc = blockIdx.x, t = threadIdx.x;
  __shared__ float xs[768];
  __shared__ float sred[16];
  __shared__ float pr[256];
  // housekeeping: block (0,0) zeroes slot1 and sets L0 = 1
  if (jc == 0 && b == 0) {
    for (int i = t; i < 1536; i += 256) ACCb[1536 + i] = 0.f;
    if (t < 32) { Lb[t] = 1.0f; Lb[32 + t] = 0.f; }
  }
  float x0 = qe[b * 768 + t], x1 = qe[b * 768 + 256 + t], x2 = qe[b * 768 + 512 + t];
  float s = x0 + x1 + x2, s2 = x0 * x0 + x1 * x1 + x2 * x2;
#pragma unroll
  for (int o = 32; o >= 1; o >>= 1) { s += __shfl_xor(s, o); s2 += __shfl_xor(s2, o); }
  int lane = t & 63, w = t >> 6;
  if (lane == 0) { sred[w] = s; sred[8 + w] = s2; }
  __syncthreads();
  s  = sred[0] + sred[1] + sred[2] + sred[3];
  s2 = sred[8] + sred[9] + sred[10] + sred[11];
  float mean = s * (1.f / 768.f);
  float var  = s2 * (1.f / 768.f) - mean * mean;
  float rstd = rsqrtf(var + 1e-5f);
  xs[t]       = (x0 - mean) * rstd * gq[t]       + bq_ln[t];
  xs[t + 256] = (x1 - mean) * rstd * gq[t + 256] + bq_ln[t + 256];
  xs[t + 512] = (x2 - mean) * rstd * gq[t + 512] + bq_ln[t + 512];
  __syncthreads();
  int j = jc * 64 + lane;
  float a = 0.f;
  int d0 = w * 192;
  for (int d = d0; d < d0 + 192; ++d) a = fmaf(xs[d], Wq[(size_t)d * 768 + j], a);
  pr[t] = a;
  __syncthreads();
  if (t < 64) {
    float sv = pr[t] + pr[64 + t] + pr[128 + t] + pr[192 + t];
    int j2 = jc * 64 + t;
    int h = j2 / 48, dh = j2 - h * 48;
    ACCb[(h * 2 + b) * 48 + dh] = sv + bq[j2];   // slot 0, unscaled; L0 = 1
  }
}

// ------------------------- memory LN + rnorm --------------------------------
__global__ __launch_bounds__(256) void k_ln(const float* __restrict__ mem,
                                            unsigned short* __restrict__ XH,
                                            float* __restrict__ rnorm) {
  int gw = (blockIdx.x * 256 + threadIdx.x) >> 6;   // 4096 waves
  int lane = threadIdx.x & 63;
  int n0 = gw * 25;
  int nend = n0 + 25; if (nend > NPAD) nend = NPAD;
  for (int n = n0; n < nend; ++n) {
    ushort4* orow = (ushort4*)(XH + (size_t)n * 768);
    if (n >= NMEM) {
      ushort4 z; z.x = z.y = z.z = z.w = 0;
      orow[lane] = z; orow[lane + 64] = z; orow[lane + 128] = z;
      continue;
    }
    const float4* r = (const float4*)(mem + (size_t)n * 768);
    float4 x0 = r[lane], x1 = r[lane + 64], x2 = r[lane + 128];
    float s  = x0.x + x0.y + x0.z + x0.w + x1.x + x1.y + x1.z + x1.w +
               x2.x + x2.y + x2.z + x2.w;
    float s2 = x0.x * x0.x + x0.y * x0.y + x0.z * x0.z + x0.w * x0.w +
               x1.x * x1.x + x1.y * x1.y + x1.z * x1.z + x1.w * x1.w +
               x2.x * x2.x + x2.y * x2.y + x2.z * x2.z + x2.w * x2.w;
#pragma unroll
    for (int o = 32; o >= 1; o >>= 1) { s += __shfl_xor(s, o); s2 += __shfl_xor(s2, o); }
    float mean = s * (1.f / 768.f);
    float var  = s2 * (1.f / 768.f) - mean * mean;
    float rstd = rsqrtf(var + 1e-5f);
    if (lane == 0) rnorm[n] = rsqrtf(s2);
    ushort4 o0, o1, o2;
    o0.x = f2bf((x0.x - mean) * rstd); o0.y = f2bf((x0.y - mean) * rstd);
    o0.z = f2bf((x0.z - mean) * rstd); o0.w = f2bf((x0.w - mean) * rstd);
    o1.x = f2bf((x1.x - mean) * rstd); o1.y = f2bf((x1.y - mean) * rstd);
    o1.z = f2bf((x1.z - mean) * rstd); o1.w = f2bf((x1.w - mean) * rstd);
    o2.x = f2bf((x2.x - mean) * rstd); o2.y = f2bf((x2.y - mean) * rstd);
    o2.z = f2bf((x2.z - mean) * rstd); o2.w = f2bf((x2.w - mean) * rstd);
    orow[lane] = o0; orow[lane + 64] = o1; orow[lane + 128] = o2;
  }
}

// ------------------------- projection GEMM (R10: BK=64, swizzle, vmcnt8) ----
__global__ __launch_bounds__(256) void k_gemm(const unsigned short* __restrict__ XH,
                                              const unsigned short* __restrict__ WT,
                                              const float* __restrict__ BKV,
                                              unsigned short* __restrict__ KB) {
  __shared__ __align__(16) unsigned short SM[32768];
  int f = blockIdx.x;
  int xcd = f & 7, s = f >> 3;
  int g = s / 6, jt = s - g * 6;
  int mt = g * 8 + xcd;
  if (mt >= 782) return;
  int m0 = mt * 128, j0 = jt * 128;
  int tid = threadIdx.x;
  int wave = tid >> 6, lane = tid & 63;
  int wm = wave >> 1, wn = wave & 1;
  int fr_r = lane & 15, chb = lane >> 4;
  f32x4 acc[4][4] = {};

  auto stage = [&](int kt, int bb) {   // 8 gl_lds per thread
    unsigned short* As = SM + bb * 16384;
    unsigned short* Bs = As + 8192;
    int k0 = kt * 64;
#pragma unroll
    for (int it = 0; it < 4; ++it) {
      int c = it * 256 + tid;
      int row = c >> 3, kk = c & 7;
      int src = (kk ^ (row & 7)) * 8;
      gl_lds16(XH + (size_t)(m0 + row) * 768 + k0 + src, As + c * 8);
      gl_lds16(WT + (size_t)(j0 + row) * 768 + k0 + src, Bs + c * 8);
    }
  };

  stage(0, 0);
  int cur = 0;
  for (int kt = 0; kt < 12; ++kt) {
    if (kt < 11) {
      stage(kt + 1, cur ^ 1);
      asm volatile("s_waitcnt vmcnt(8)" ::: "memory");
    } else {
      asm volatile("s_waitcnt vmcnt(0)" ::: "memory");
    }
    __builtin_amdgcn_s_barrier();
    __builtin_amdgcn_sched_barrier(0);
    const unsigned short* As = SM + cur * 16384;
    const unsigned short* Bs = As + 8192;
    __builtin_amdgcn_s_setprio(1);
#pragma unroll
    for (int ks = 0; ks < 2; ++ks) {
      bf16x8 af[4], bfr[4];
#pragma unroll
      for (int ff = 0; ff < 4; ++ff) {
        int ra = wm * 64 + ff * 16 + fr_r;
        int rb = wn * 64 + ff * 16 + fr_r;
        int cha  = ((ks * 4 + chb) ^ (ra & 7)) * 8;
        int chbb = ((ks * 4 + chb) ^ (rb & 7)) * 8;
        af[ff]  = *(const bf16x8*)(As + ra * 64 + cha);
        bfr[ff] = *(const bf16x8*)(Bs + rb * 64 + chbb);
      }
#pragma unroll
      for (int fm = 0; fm < 4; ++fm)
#pragma unroll
        for (int fn = 0; fn < 4; ++fn)
          acc[fm][fn] = __builtin_amdgcn_mfma_f32_16x16x32_bf16(af[fm], bfr[fn],
                                                                acc[fm][fn], 0, 0, 0);
    }
    __builtin_amdgcn_s_setprio(0);
    __builtin_amdgcn_s_barrier();
    __builtin_amdgcn_sched_barrier(0);
    cur ^= 1;
  }
  int cr = (lane >> 4) * 4, cc = lane & 15;
#pragma unroll
  for (int fm = 0; fm < 4; ++fm)
#pragma unroll
    for (int fn = 0; fn < 4; ++fn) {
      int col = wn * 64 + fn * 16 + cc;
      float bias = BKV[j0 + col];
      int rb = (wm * 64 + fm * 16 + cr) * 128 + col;
#pragma unroll
      for (int i = 0; i < 4; ++i)
        SM[rb + i * 128] = f2bf(acc[fm][fn][i] + bias);
    }
  __syncthreads();
#pragma unroll
  for (int it = 0; it < 8; ++it) {
    int c = it * 256 + tid;
    int row = c >> 4, cg = c & 15;
    *(bf16x8*)(KB + (size_t)(m0 + row) * 768 + j0 + cg * 8) =
        *(const bf16x8*)(SM + row * 128 + cg * 8);
  }
}

// ------------------------- hop helpers --------------------------------------
__device__ __forceinline__ void load6(const unsigned short* p, float* o) {
  ushort2 a = *(const ushort2*)(p);
  ushort2 b = *(const ushort2*)(p + 2);
  ushort2 c = *(const ushort2*)(p + 4);
  o[0] = bf2f(a.x); o[1] = bf2f(a.y);
  o[2] = bf2f(b.x); o[3] = bf2f(b.y);
  o[4] = bf2f(c.x); o[5] = bf2f(c.y);
}

// hop pass s: q = 0.25*ACC[s]/L[s]; atomic-accumulate into slot s+1;
// block 0 zeroes slot s+2.
__global__ __launch_bounds__(256) void k_hop(const unsigned short* __restrict__ KB,
                                             float* __restrict__ ACCb,
                                             float* __restrict__ Lb,
                                             int s) {
  __shared__ float red[4][768];
  __shared__ float redl[4][128];
  int tid = threadIdx.x, blk = blockIdx.x;
  int w = tid >> 6, lane = tid & 63;
  int hb = w & 1, sub = w >> 1;
  const float* Ap  = ACCb + s * 1536;
  const float* Lp  = Lb + s * 32;
  float* An  = ACCb + (s + 1) * 1536;
  float* Ln_ = Lb + (s + 1) * 32;
  if (blk == 0) {                      // zero slot s+2 (used by next pass)
    for (int i = tid; i < 1536; i += 256) ACCb[(s + 2) * 1536 + i] = 0.f;
    if (tid < 32) Lb[(s + 2) * 32 + tid] = 0.f;
  }
  int h = hb * 8 + (lane >> 3), p = lane & 7;
  float rl0 = SCALING_ / Lp[h * 2 + 0];
  float rl1 = SCALING_ / Lp[h * 2 + 1];
  float qv0[6], qv1[6];
#pragma unroll
  for (int j = 0; j < 6; ++j) {
    qv0[j] = rl0 * Ap[(h * 2 + 0) * 48 + p * 6 + j];
    qv1[j] = rl1 * Ap[(h * 2 + 1) * 48 + p * 6 + j];
  }
  float l0 = 0.f, l1 = 0.f;
  float acc0[6] = {}, acc1[6] = {};
  int n0 = blk * CBLK + sub * 49;
  int nend = n0 + 49;
  if (nend > NMEM) nend = NMEM;
#pragma unroll 4
  for (int n = n0; n < nend; ++n) {
    const unsigned short* ks = KB + (size_t)n * 768 + hb * 384 + lane * 6;
    float kf[6]; load6(ks, kf);
    float sc0 = 0.f, sc1 = 0.f;
#pragma unroll
    for (int j = 0; j < 6; ++j) {
      sc0 = fmaf(kf[j], qv0[j], sc0);
      sc1 = fmaf(kf[j], qv1[j], sc1);
    }
#pragma unroll
    for (int o = 1; o < 8; o <<= 1) {
      sc0 += __shfl_xor(sc0, o);
      sc1 += __shfl_xor(sc1, o);
    }
    float e0 = __expf(sc0);
    float e1 = __expf(sc1);
    l0 += e0; l1 += e1;
#pragma unroll
    for (int j = 0; j < 6; ++j) {
      acc0[j] = fmaf(e0, kf[j], acc0[j]);
      acc1[j] = fmaf(e1, kf[j], acc1[j]);
    }
  }
#pragma unroll
  for (int j = 0; j < 6; ++j) {
    red[w][lane * 12 + j]     = acc0[j];
    red[w][lane * 12 + 6 + j] = acc1[j];
  }
  redl[w][lane * 2]     = l0;
  redl[w][lane * 2 + 1] = l1;
  __syncthreads();
  if (sub == 0) {
#pragma unroll
    for (int j = 0; j < 6; ++j) {
      acc0[j] += red[w + 2][lane * 12 + j];
      acc1[j] += red[w + 2][lane * 12 + 6 + j];
    }
    l0 += redl[w + 2][lane * 2];
    l1 += redl[w + 2][lane * 2 + 1];
#pragma unroll
    for (int j = 0; j < 6; ++j) {
      atomicAdd(&An[(h * 2 + 0) * 48 + p * 6 + j], acc0[j]);
      atomicAdd(&An[(h * 2 + 1) * 48 + p * 6 + j], acc1[j]);
    }
    if (p == 0) {
      atomicAdd(&Ln_[h * 2 + 0], l0);
      atomicAdd(&Ln_[h * 2 + 1], l1);
    }
  }
}

// final score pass: q from slot 5; writes raw S; atomicAdd l into LF (=L[6])
__global__ __launch_bounds__(256) void k_escore(const unsigned short* __restrict__ KB,
                                                const float* __restrict__ Ap,
                                                const float* __restrict__ Lp,
                                                float* __restrict__ S,
                                                float* __restrict__ LF) {
  __shared__ float redl[4][128];
  int tid = threadIdx.x, blk = blockIdx.x;
  int w = tid >> 6, lane = tid & 63;
  int hb = w & 1, sub = w >> 1;
  int h = hb * 8 + (lane >> 3), p = lane & 7;
  float rl0 = SCALING_ / Lp[h * 2 + 0];
  float rl1 = SCALING_ / Lp[h * 2 + 1];
  float qv0[6], qv1[6];
#pragma unroll
  for (int j = 0; j < 6; ++j) {
    qv0[j] = rl0 * Ap[(h * 2 + 0) * 48 + p * 6 + j];
    qv1[j] = rl1 * Ap[(h * 2 + 1) * 48 + p * 6 + j];
  }
  float l0 = 0.f, l1 = 0.f;
  int n0 = blk * CBLK + sub * 49;
  int nend = n0 + 49;
  if (nend > NMEM) nend = NMEM;
#pragma unroll 4
  for (int n = n0; n < nend; ++n) {
    const unsigned short* ks = KB + (size_t)n * 768 + hb * 384 + lane * 6;
    float kf[6]; load6(ks, kf);
    float sc0 = 0.f, sc1 = 0.f;
#pragma unroll
    for (int j = 0; j < 6; ++j) {
      sc0 = fmaf(kf[j], qv0[j], sc0);
      sc1 = fmaf(kf[j], qv1[j], sc1);
    }
#pragma unroll
    for (int o = 1; o < 8; o <<= 1) {
      sc0 += __shfl_xor(sc0, o);
      sc1 += __shfl_xor(sc1, o);
    }
    if (p == 0) {
      S[(size_t)n * 32 + h]      = sc0;
      S[(size_t)n * 32 + 16 + h] = sc1;
    }
    l0 += __expf(sc0);
    l1 += __expf(sc1);
  }
  redl[w][lane * 2]     = l0;
  redl[w][lane * 2 + 1] = l1;
  __syncthreads();
  if (sub == 0) {
    l0 += redl[w + 2][lane * 2];
    l1 += redl[w + 2][lane * 2 + 1];
    if (p == 0) {
      atomicAdd(&LF[h * 2 + 0], l0);
      atomicAdd(&LF[h * 2 + 1], l1);
    }
  }
}

// ------------------------- u-pass (w = exp(S)/L) ----------------------------
__global__ __launch_bounds__(256) void k_upass(const unsigned short* __restrict__ XH,
                                               const float* __restrict__ S,
                                               const float* __restrict__ LF,
                                               float* __restrict__ UP) {
  __shared__ float SW[64 * 32];
  __shared__ float cc[32];
  int kb = blockIdx.x, t = threadIdx.x;
  if (t < 32) cc[t] = 1.0f / LF[t];
  float a0[32], a1[32], a2[32];
#pragma unroll
  for (int i = 0; i < 32; ++i) { a0[i] = 0.f; a1[i] = 0.f; a2[i] = 0.f; }
  int n0 = kb * UROWS;
  int nend = n0 + UROWS; if (nend > NMEM) nend = NMEM;
  for (int ns = n0; ns < nend; ns += 64) {
    int sub = nend - ns; if (sub > 64) sub = 64;
    __syncthreads();
    for (int i = t; i < sub * 32; i += 256)
      SW[i] = __expf(S[(size_t)ns * 32 + i]) * cc[i & 31];
    __syncthreads();
    for (int r = 0; r < sub; ++r) {
      const unsigned short* xr = XH + (size_t)(ns + r) * 768;
      float x0 = bf2f(xr[t]), x1 = bf2f(xr[t + 256]), x2 = bf2f(xr[t + 512]);
      const float4* w4 = (const float4*)(SW + r * 32);
#pragma unroll
      for (int c = 0; c < 8; ++c) {
        float4 wv = w4[c];
        a0[c * 4 + 0] = fmaf(wv.x, x0, a0[c * 4 + 0]);
        a0[c * 4 + 1] = fmaf(wv.y, x0, a0[c * 4 + 1]);
        a0[c * 4 + 2] = fmaf(wv.z, x0, a0[c * 4 + 2]);
        a0[c * 4 + 3] = fmaf(wv.w, x0, a0[c * 4 + 3]);
        a1[c * 4 + 0] = fmaf(wv.x, x1, a1[c * 4 + 0]);
        a1[c * 4 + 1] = fmaf(wv.y, x1, a1[c * 4 + 1]);
        a1[c * 4 + 2] = fmaf(wv.z, x1, a1[c * 4 + 2]);
        a1[c * 4 + 3] = fmaf(wv.w, x1, a1[c * 4 + 3]);
        a2[c * 4 + 0] = fmaf(wv.x, x2, a2[c * 4 + 0]);
        a2[c * 4 + 1] = fmaf(wv.y, x2, a2[c * 4 + 1]);
        a2[c * 4 + 2] = fmaf(wv.z, x2, a2[c * 4 + 2]);
        a2[c * 4 + 3] = fmaf(wv.w, x2, a2[c * 4 + 3]);
      }
    }
  }
#pragma unroll
  for (int bh = 0; bh < 32; ++bh) {
    size_t base = ((size_t)kb * 32 + bh) * 768;
    UP[base + t]       = a0[bh];
    UP[base + 256 + t] = a1[bh];
    UP[base + 512 + t] = a2[bh];
  }
}

__global__ __launch_bounds__(256) void k_ured(const float* __restrict__ UP,
                                              float* __restrict__ U) {
  int o = blockIdx.x * 256 + threadIdx.x;
  float s0 = 0.f, s1 = 0.f, s2 = 0.f, s3 = 0.f;
#pragma unroll 4
  for (int kb = 0; kb < UKS; kb += 4) {
    s0 += UP[(size_t)(kb + 0) * 24576 + o];
    s1 += UP[(size_t)(kb + 1) * 24576 + o];
    s2 += UP[(size_t)(kb + 2) * 24576 + o];
    s3 += UP[(size_t)(kb + 3) * 24576 + o];
  }
  U[o] = (s0 + s1) + (s2 + s3);
}

__global__ __launch_bounds__(256) void k_outproj(const float* __restrict__ U,
                                                 const unsigned short* __restrict__ WT,
                                                 const float* __restrict__ BKV,
                                                 float* __restrict__ outa) {
  int gw = blockIdx.x * 4 + (threadIdx.x >> 6);
  int lane = threadIdx.x & 63;
  int b = gw >= 768;
  int j = gw - b * 768;
  int h = j / 48;
  const float* u = U + (size_t)(b * 16 + h) * 768;
  const unsigned short* wr = WT + (size_t)(768 + j) * 768;
  float a = 0.f;
  for (int d = lane; d < 768; d += 64) a = fmaf(u[d], bf2f(wr[d]), a);
#pragma unroll
  for (int o = 32; o >= 1; o >>= 1) a += __shfl_xor(a, o);
  if (lane == 0) outa[b * 768 + j] = a + BKV[768 + j];
}

// ------------------------- pooled / norm ------------------------------------
__global__ __launch_bounds__(256) void k_pooled(const float* __restrict__ outa,
                                                const float* __restrict__ Wo,
                                                const float* __restrict__ bo,
                                                float* __restrict__ dp) {
  __shared__ float xs[768];
  __shared__ float pr[256];
  int b = blockIdx.y, jc = blockIdx.x, t = threadIdx.x;
  xs[t]       = outa[b * 768 + t];
  xs[t + 256] = outa[b * 768 + 256 + t];
  xs[t + 512] = outa[b * 768 + 512 + t];
  __syncthreads();
  int w = t >> 6, lane = t & 63;
  int j = jc * 64 + lane;
  float a = 0.f;
  int d0 = w * 192;
  for (int d = d0; d < d0 + 192; ++d) a = fmaf(xs[d], Wo[(size_t)d * 768 + j], a);
  pr[t] = a;
  __syncthreads();
  if (t < 64) {
    float sv = pr[t] + pr[64 + t] + pr[128 + t] + pr[192 + t];
    int j2 = jc * 64 + t;
    dp[b * 768 + j2] = sv + bo[j2];
  }
}

__global__ __launch_bounds__(256) void k_pnorm(const float* __restrict__ dp,
                                               float* __restrict__ PN) {
  int b = blockIdx.x, t = threadIdx.x;
  __shared__ float sred[8];
  float x0 = dp[b * 768 + t], x1 = dp[b * 768 + 256 + t], x2 = dp[b * 768 + 512 + t];
  float s2 = x0 * x0 + x1 * x1 + x2 * x2;
#pragma unroll
  for (int o = 32; o >= 1; o >>= 1) s2 += __shfl_xor(s2, o);
  int lane = t & 63, w = t >> 6;
  if (lane == 0) sred[w] = s2;
  __syncthreads();
  float tot = sred[0] + sred[1] + sred[2] + sred[3];
  float rs = rsqrtf(tot);
  PN[b * 768 + t]       = x0 * rs;
  PN[b * 768 + 256 + t] = x1 * rs;
  PN[b * 768 + 512 + t] = x2 * rs;
}

// ------------------------- similarity + top-4 -------------------------------
__global__ __launch_bounds__(256) void k_sim(const float* __restrict__ mem,
                                             const float* __restrict__ PN,
                                             const float* __restrict__ rnorm,
                                             float* __restrict__ tval,
                                             int* __restrict__ tidx) {
  int gw = (blockIdx.x * 256 + threadIdx.x) >> 6;   // 8192 waves
  int lane = threadIdx.x & 63;
  const float4* pa = (const float4*)(PN);
  const float4* pb = (const float4*)(PN + 768);
  float4 qa0 = pa[lane], qa1 = pa[lane + 64], qa2 = pa[lane + 128];
  float4 qb0 = pb[lane], qb1 = pb[lane + 64], qb2 = pb[lane + 128];
  Top4 t0, t1; t0.init(); t1.init();
  int n0 = gw * 13;
  int nend = n0 + 13; if (nend > NMEM) nend = NMEM;
  for (int n = n0; n < nend; ++n) {
    const float4* r = (const float4*)(mem + (size_t)n * 768);
    float4 x0 = r[lane], x1 = r[lane + 64], x2 = r[lane + 128];
    float d0 = x0.x * qa0.x + x0.y * qa0.y + x0.z * qa0.z + x0.w * qa0.w +
               x1.x * qa1.x + x1.y * qa1.y + x1.z * qa1.z + x1.w * qa1.w +
               x2.x * qa2.x + x2.y * qa2.y + x2.z * qa2.z + x2.w * qa2.w;
    float d1 = x0.x * qb0.x + x0.y * qb0.y + x0.z * qb0.z + x0.w * qb0.w +
               x1.x * qb1.x + x1.y * qb1.y + x1.z * qb1.z + x1.w * qb1.w +
               x2.x * qb2.x + x2.y * qb2.y + x2.z * qb2.z + x2.w * qb2.w;
#pragma unroll
    for (int o = 32; o >= 1; o >>= 1) { d0 += __shfl_xor(d0, o); d1 += __shfl_xor(d1, o); }
    float rn = rnorm[n];
    t0.ins(d0 * rn, n);
    t1.ins(d1 * rn, n);
  }
  if (lane == 0) {
    int base = gw * 8;
    tval[base + 0] = t0.v0; tval[base + 1] = t0.v1; tval[base + 2] = t0.v2; tval[base + 3] = t0.v3;
    tval[base + 4] = t1.v0; tval[base + 5] = t1.v1; tval[base + 6] = t1.v2; tval[base + 7] = t1.v3;
    tidx[base + 0] = t0.i0; tidx[base + 1] = t0.i1; tidx[base + 2] = t0.i2; tidx[base + 3] = t0.i3;
    tidx[base + 4] = t1.i0; tidx[base + 5] = t1.i1; tidx[base + 6] = t1.i2; tidx[base + 7] = t1.i3;
  }
}

__global__ __launch_bounds__(256) void k_top1(const float* __restrict__ tval,
                                              const int* __restrict__ tidx,
                                              float* __restrict__ ptv,
                                              int* __restrict__ pti) {
  __shared__ float lv[4][8];
  __shared__ int   li[4][8];
  int z = blockIdx.x, t = threadIdx.x;
  int lane = t & 63, w = t >> 6;
  int wv = z * 256 + t;
  Top4 a, b; a.init(); b.init();
#pragma unroll
  for (int r = 0; r < 4; ++r) {
    a.ins(tval[wv * 8 + r],     tidx[wv * 8 + r]);
    b.ins(tval[wv * 8 + 4 + r], tidx[wv * 8 + 4 + r]);
  }
  bfly(a, 32);
  bfly(b, 32);
  if (lane == 0) {
    lv[w][0] = a.v0; lv[w][1] = a.v1; lv[w][2] = a.v2; lv[w][3] = a.v3;
    lv[w][4] = b.v0; lv[w][5] = b.v1; lv[w][6] = b.v2; lv[w][7] = b.v3;
    li[w][0] = a.i0; li[w][1] = a.i1; li[w][2] = a.i2; li[w][3] = a.i3;
    li[w][4] = b.i0; li[w][5] = b.i1; li[w][6] = b.i2; li[w][7] = b.i3;
  }
  __syncthreads();
  if (t < 2) {
    Top4 m_; m_.init();
#pragma unroll
    for (int w2 = 0; w2 < 4; ++w2)
#pragma unroll
      for (int r = 0; r < 4; ++r) m_.ins(lv[w2][t * 4 + r], li[w2][t * 4 + r]);
    int base = z * 8 + t * 4;
    ptv[base + 0] = m_.v0; ptv[base + 1] = m_.v1;
    ptv[base + 2] = m_.v2; ptv[base + 3] = m_.v3;
    pti[base + 0] = m_.i0; pti[base + 1] = m_.i1;
    pti[base + 2] = m_.i2; pti[base + 3] = m_.i3;
  }
}

__global__ __launch_bounds__(64) void k_top2(const float* __restrict__ ptv,
                                             const int* __restrict__ pti,
                                             float* __restrict__ dout) {
  int t = threadIdx.x;
  int half = t >> 5, e = t & 31;
  Top4 a; a.init();
#pragma unroll
  for (int r = 0; r < 4; ++r)
    a.ins(ptv[e * 8 + half * 4 + r], pti[e * 8 + half * 4 + r]);
  bfly(a, 16);
  if (e == 0) {
    dout[half * 4 + 0] = (float)a.i0;
    dout[half * 4 + 1] = (float)a.i1;
    dout[half * 4 + 2] = (float)a.i2;
    dout[half * 4 + 3] = (float)a.i3;
  }
}

// ---------------------------------------------------------------------------
extern "C" void kernel_launch(void* const* d_in, const int* in_sizes, int n_in,
                              void* d_out, int out_size, void* d_ws, size_t ws_size,
                              hipStream_t stream) {
  const float* qe     = (const float*)d_in[0];
  const float* mem    = (const float*)d_in[1];
  const float* ln_q_g = (const float*)d_in[2];
  const float* ln_q_b = (const float*)d_in[3];
  const float* ln_s_g = (const float*)d_in[4];
  const float* ln_s_b = (const float*)d_in[5];
  const float* ln_p_g = (const float*)d_in[6];
  const float* ln_p_b = (const float*)d_in[7];
  const float* Wq = (const float*)d_in[8];  const float* bq = (const float*)d_in[9];
  const float* Wk = (const float*)d_in[10]; const float* bk = (const float*)d_in[11];
  const float* Wv = (const float*)d_in[12]; const float* bv = (const float*)d_in[13];
  const float* Wo = (const float*)d_in[14]; const float* bo = (const float*)d_in[15];

  char* w = (char*)d_ws;
  size_t off = 0;
  auto alloc = [&](size_t bytes) {
    size_t o = off;
    off += (bytes + 255) & ~(size_t)255;
    return o;
  };
  unsigned short* WT   = (unsigned short*)(w + alloc((size_t)1536 * 768 * 2));
  float*          PB   = (float*)(w + alloc(8 * 1536 * 4));
  float*          BKV  = (float*)(w + alloc(1536 * 4));
  float*          ACCB = (float*)(w + alloc(7 * 1536 * 4));
  float*          LB   = (float*)(w + alloc(7 * 32 * 4));
  float*          OUTA = (float*)(w + alloc(1536 * 4));
  float*          PN   = (float*)(w + alloc(1536 * 4));
  float*          UBUF = (float*)(w + alloc((size_t)24576 * 4));
  float*          RNORM= (float*)(w + alloc((size_t)NPAD * 4));
  unsigned short* XH   = (unsigned short*)(w + alloc((size_t)NPAD * 768 * 2));
  unsigned short* KB   = (unsigned short*)(w + alloc((size_t)NPAD * 768 * 2));
  float*          SB   = (float*)(w + alloc((size_t)NMEM * 32 * 4));
  float*          UP   = (float*)(w + alloc((size_t)UKS * 24576 * 4));
  float*          TVAL = (float*)(w + alloc((size_t)8192 * 8 * 4));
  int*            TIDX = (int*)(w + alloc((size_t)8192 * 8 * 4));
  float*          PTV  = (float*)(w + alloc((size_t)32 * 8 * 4));
  int*            PTI  = (int*)(w + alloc((size_t)32 * 8 * 4));
  if (off > ws_size) {
    fprintf(stderr, "[hopfield] ws too small: need %zu have %zu\n", off, ws_size);
    return;
  }
  float* dout = (float*)d_out;

  k_fold_wt  <<<dim3(12, 12, 2), 256, 0, stream>>>(Wk, Wv, ln_s_g, ln_p_g, WT);
  k_fold_bias<<<dim3(6, 8), 256, 0, stream>>>(Wk, Wv, ln_s_b, ln_p_b, PB);
  k_bias_red <<<6, 256, 0, stream>>>(PB, bk, bv, BKV);
  k_q0       <<<dim3(12, 2), 256, 0, stream>>>(qe, ln_q_g, ln_q_b, Wq, bq, ACCB, LB);
  k_ln       <<<1024, 256, 0, stream>>>(mem, XH, RNORM);
  k_gemm     <<<98 * 6 * 8, 256, 0, stream>>>(XH, WT, BKV, KB);
  for (int s = 0; s < 5; ++s)
    k_hop    <<<HOPB, 256, 0, stream>>>(KB, ACCB, LB, s);
  k_escore   <<<HOPB, 256, 0, stream>>>(KB, ACCB + 5 * 1536, LB + 5 * 32, SB,
                                        LB + 6 * 32);
  k_upass    <<<UKS, 256, 0, stream>>>(XH, SB, LB + 6 * 32, UP);
  k_ured     <<<96, 256, 0, stream>>>(UP, UBUF);
  k_outproj  <<<384, 256, 0, stream>>>(UBUF, WT, BKV, OUTA);
  k_pooled   <<<dim3(12, 2), 256, 0, stream>>>(OUTA, Wo, bo, dout + 8);
  k_pnorm    <<<2, 256, 0, stream>>>(dout + 8, PN);
  k_sim      <<<2048, 256, 0, stream>>>(mem, PN, RNORM, TVAL, TIDX);
  k_top1     <<<32, 256, 0, stream>>>(TVAL, TIDX, PTV, PTI);
  k_top2     <<<1, 64, 0, stream>>>(PTV, PTI, dout);
}

// Round 13
// 851.002 us; speedup vs baseline: 1.7724x; 1.7724x over previous
//
#include <hip/hip_runtime.h>
#include <cstdio>
#include <cstdint>

// ---------------------------------------------------------------------------
// HopfieldPoolingRouter on MI355X — V-free formulation, fixed-base softmax,
// block-reduced hop partials, counted-vmcnt GEMM pipeline.  (Round-10 best.)
//   k: KB = LN(mem)@WTk^T + BKVk  (bf16 MFMA, BK=64, XOR-swizzled LDS,
//      2-buffer + counted vmcnt(8): prefetch stays in flight across barrier)
//   5x hop: q = 0.25 * softmax(q k^T) k  (m=0 softmax, branchless, |sc|<~15)
//   escore: S raw scores + l partials;  C = log(sum exp(S))
//   upass:  u[bh][:] = sum_n exp(S-C)[n][bh] * XH[n][:]
//   outproj: out = u@WTv^T + BKVv  (v eliminated: affine trick)
//   pooled = out@Wo + bo; normalize; sims + butterfly top-4
// ---------------------------------------------------------------------------

#define NMEM 100000
#define NPAD 100096          // 782 * 128
#define HOPB 1024            // hop-pass blocks; also partials per (b,h)
#define CBLK 98              // rows per hop block (1024*98 >= 100000)
#define UKS  512
#define UROWS 196
#define SCALING_ 0.25f

typedef __attribute__((ext_vector_type(8))) short bf16x8;
typedef __attribute__((ext_vector_type(4))) float f32x4;

__device__ __forceinline__ unsigned short f2bf(float f) {
  union { float f; unsigned u; } c; c.f = f;
  unsigned u = c.u + 0x7fffu + ((c.u >> 16) & 1u);   // RNE
  return (unsigned short)(u >> 16);
}
__device__ __forceinline__ float bf2f(unsigned short h) {
  union { unsigned u; float f; } c; c.u = ((unsigned)h) << 16;
  return c.f;
}
__device__ __forceinline__ void gl_lds16(const void* g, void* l) {
  __builtin_amdgcn_global_load_lds(
      (const __attribute__((address_space(1))) unsigned int*)g,
      (__attribute__((address_space(3))) unsigned int*)l, 16, 0, 0);
}

__device__ __forceinline__ bool bet(float s, int n, float v, int i) {
  return (s > v) || (s == v && n < i);
}
struct Top4 {
  float v0, v1, v2, v3;
  int   i0, i1, i2, i3;
  __device__ __forceinline__ void init() {
    v0 = v1 = v2 = v3 = -INFINITY;
    i0 = i1 = i2 = i3 = 0x7fffffff;
  }
  __device__ __forceinline__ void ins(float s, int n) {
    bool c0 = bet(s, n, v0, i0), c1 = bet(s, n, v1, i1);
    bool c2 = bet(s, n, v2, i2), c3 = bet(s, n, v3, i3);
    float w0 = c0 ? s : v0;             int j0 = c0 ? n : i0;
    float w1 = c0 ? v0 : (c1 ? s : v1); int j1 = c0 ? i0 : (c1 ? n : i1);
    float w2 = c1 ? v1 : (c2 ? s : v2); int j2 = c1 ? i1 : (c2 ? n : i2);
    float w3 = c2 ? v2 : (c3 ? s : v3); int j3 = c2 ? i2 : (c3 ? n : i3);
    v0 = w0; v1 = w1; v2 = w2; v3 = w3;
    i0 = j0; i1 = j1; i2 = j2; i3 = j3;
  }
};
__device__ __forceinline__ void bfly(Top4& a, int omax) {
  for (int o = omax; o >= 1; o >>= 1) {
    float w0 = __shfl_xor(a.v0, o), w1 = __shfl_xor(a.v1, o);
    float w2 = __shfl_xor(a.v2, o), w3 = __shfl_xor(a.v3, o);
    int   j0 = __shfl_xor(a.i0, o), j1 = __shfl_xor(a.i1, o);
    int   j2 = __shfl_xor(a.i2, o), j3 = __shfl_xor(a.i3, o);
    a.ins(w0, j0); a.ins(w1, j1); a.ins(w2, j2); a.ins(w3, j3);
  }
}

// ------------------------- weight folding ----------------------------------
__global__ __launch_bounds__(256) void k_fold_wt(const float* __restrict__ Wk,
                                                 const float* __restrict__ Wv,
                                                 const float* __restrict__ gs,
                                                 const float* __restrict__ gp,
                                                 unsigned short* __restrict__ WT) {
  __shared__ float ts[64][65];
  int d0 = blockIdx.x * 64, j0 = blockIdx.y * 64, z = blockIdx.z;
  const float* W = z ? Wv : Wk;
  const float* g = z ? gp : gs;
  int t = threadIdx.x, c = t & 63, r4 = t >> 6;
#pragma unroll
  for (int p = 0; p < 16; ++p) {
    int r = p * 4 + r4;
    ts[r][c] = g[d0 + r] * W[(size_t)(d0 + r) * 768 + j0 + c];
  }
  __syncthreads();
#pragma unroll
  for (int p = 0; p < 16; ++p) {
    int jr = p * 4 + r4;
    WT[(size_t)(z * 768 + j0 + jr) * 768 + d0 + c] = f2bf(ts[c][jr]);
  }
}

__global__ __launch_bounds__(256) void k_fold_bias(const float* __restrict__ Wk,
                                                   const float* __restrict__ Wv,
                                                   const float* __restrict__ bs,
                                                   const float* __restrict__ bp,
                                                   float* __restrict__ PB) {
  int jc = blockIdx.x, dz = blockIdx.y, t = threadIdx.x;
  int j = jc * 256 + t;
  const float* W  = (j < 768) ? Wk : Wv;
  const float* bb = (j < 768) ? bs : bp;
  int jj = (j < 768) ? j : j - 768;
  float a = 0.f;
  int dend = dz * 96 + 96;
  for (int d = dz * 96; d < dend; ++d) a = fmaf(bb[d], W[(size_t)d * 768 + jj], a);
  PB[dz * 1536 + j] = a;
}

__global__ __launch_bounds__(256) void k_bias_red(const float* __restrict__ PB,
                                                  const float* __restrict__ bk,
                                                  const float* __restrict__ bv,
                                                  float* __restrict__ BKV) {
  int j = blockIdx.x * 256 + threadIdx.x;
  float a = (j < 768) ? bk[j] : bv[j - 768];
#pragma unroll
  for (int dz = 0; dz < 8; ++dz) a += PB[dz * 1536 + j];
  BKV[j] = a;
}

// ------------------------- q0 ----------------------------------------------
__global__ __launch_bounds__(256) void k_q0(const float* __restrict__ qe,
                                            const float* __restrict__ gq,
                                            const float* __restrict__ bq_ln,
                                            const float* __restrict__ Wq,
                                            const float* __restrict__ bq,
                                            float* __restrict__ qbuf) {
  int b = blockIdx.y, jc = blockIdx.x, t = threadIdx.x;
  __shared__ float xs[768];
  __shared__ float sred[16];
  __shared__ float pr[256];
  float x0 = qe[b * 768 + t], x1 = qe[b * 768 + 256 + t], x2 = qe[b * 768 + 512 + t];
  float s = x0 + x1 + x2, s2 = x0 * x0 + x1 * x1 + x2 * x2;
#pragma unroll
  for (int o = 32; o >= 1; o >>= 1) { s += __shfl_xor(s, o); s2 += __shfl_xor(s2, o); }
  int lane = t & 63, w = t >> 6;
  if (lane == 0) { sred[w] = s; sred[8 + w] = s2; }
  __syncthreads();
  s  = sred[0] + sred[1] + sred[2] + sred[3];
  s2 = sred[8] + sred[9] + sred[10] + sred[11];
  float mean = s * (1.f / 768.f);
  float var  = s2 * (1.f / 768.f) - mean * mean;
  float rstd = rsqrtf(var + 1e-5f);
  xs[t]       = (x0 - mean) * rstd * gq[t]       + bq_ln[t];
  xs[t + 256] = (x1 - mean) * rstd * gq[t + 256] + bq_ln[t + 256];
  xs[t + 512] = (x2 - mean) * rstd * gq[t + 512] + bq_ln[t + 512];
  __syncthreads();
  int j = jc * 64 + lane;
  float a = 0.f;
  int d0 = w * 192;
  for (int d = d0; d < d0 + 192; ++d) a = fmaf(xs[d], Wq[(size_t)d * 768 + j], a);
  pr[t] = a;
  __syncthreads();
  if (t < 64) {
    float sv = pr[t] + pr[64 + t] + pr[128 + t] + pr[192 + t];
    int j2 = jc * 64 + t;
    qbuf[b * 768 + j2] = SCALING_ * (sv + bq[j2]);
  }
}

// ------------------------- memory LN + rnorm (contiguous wave chunks) ------
__global__ __launch_bounds__(256) void k_ln(const float* __restrict__ mem,
                                            unsigned short* __restrict__ XH,
                                            float* __restrict__ rnorm) {
  int gw = (blockIdx.x * 256 + threadIdx.x) >> 6;   // 4096 waves
  int lane = threadIdx.x & 63;
  int n0 = gw * 25;
  int nend = n0 + 25; if (nend > NPAD) nend = NPAD;
  for (int n = n0; n < nend; ++n) {
    ushort4* orow = (ushort4*)(XH + (size_t)n * 768);
    if (n >= NMEM) {
      ushort4 z; z.x = z.y = z.z = z.w = 0;
      orow[lane] = z; orow[lane + 64] = z; orow[lane + 128] = z;
      continue;
    }
    const float4* r = (const float4*)(mem + (size_t)n * 768);
    float4 x0 = r[lane], x1 = r[lane + 64], x2 = r[lane + 128];
    float s  = x0.x + x0.y + x0.z + x0.w + x1.x + x1.y + x1.z + x1.w +
               x2.x + x2.y + x2.z + x2.w;
    float s2 = x0.x * x0.x + x0.y * x0.y + x0.z * x0.z + x0.w * x0.w +
               x1.x * x1.x + x1.y * x1.y + x1.z * x1.z + x1.w * x1.w +
               x2.x * x2.x + x2.y * x2.y + x2.z * x2.z + x2.w * x2.w;
#pragma unroll
    for (int o = 32; o >= 1; o >>= 1) { s += __shfl_xor(s, o); s2 += __shfl_xor(s2, o); }
    float mean = s * (1.f / 768.f);
    float var  = s2 * (1.f / 768.f) - mean * mean;
    float rstd = rsqrtf(var + 1e-5f);
    if (lane == 0) rnorm[n] = rsqrtf(s2);
    ushort4 o0, o1, o2;
    o0.x = f2bf((x0.x - mean) * rstd); o0.y = f2bf((x0.y - mean) * rstd);
    o0.z = f2bf((x0.z - mean) * rstd); o0.w = f2bf((x0.w - mean) * rstd);
    o1.x = f2bf((x1.x - mean) * rstd); o1.y = f2bf((x1.y - mean) * rstd);
    o1.z = f2bf((x1.z - mean) * rstd); o1.w = f2bf((x1.w - mean) * rstd);
    o2.x = f2bf((x2.x - mean) * rstd); o2.y = f2bf((x2.y - mean) * rstd);
    o2.z = f2bf((x2.z - mean) * rstd); o2.w = f2bf((x2.w - mean) * rstd);
    orow[lane] = o0; orow[lane + 64] = o1; orow[lane + 128] = o2;
  }
}

// ------------------------- projection GEMM (counted-vmcnt pipeline) --------
// 2 LDS buffers; stage(kt+1) issued before compute(kt); raw s_barrier + manual
// s_waitcnt vmcnt(8) lets the prefetch's 8 loads/thread stay in flight across
// the barrier (no vmcnt(0) drain). Second barrier protects buf reuse.
__global__ __launch_bounds__(256) void k_gemm(const unsigned short* __restrict__ XH,
                                              const unsigned short* __restrict__ WT,
                                              const float* __restrict__ BKV,
                                              unsigned short* __restrict__ KB) {
  __shared__ __align__(16) unsigned short SM[32768];
  int f = blockIdx.x;
  int xcd = f & 7, s = f >> 3;
  int g = s / 6, jt = s - g * 6;
  int mt = g * 8 + xcd;
  if (mt >= 782) return;
  int m0 = mt * 128, j0 = jt * 128;
  int tid = threadIdx.x;
  int wave = tid >> 6, lane = tid & 63;
  int wm = wave >> 1, wn = wave & 1;
  int fr_r = lane & 15, chb = lane >> 4;
  f32x4 acc[4][4] = {};

  auto stage = [&](int kt, int bb) {   // 8 gl_lds per thread
    unsigned short* As = SM + bb * 16384;
    unsigned short* Bs = As + 8192;
    int k0 = kt * 64;
#pragma unroll
    for (int it = 0; it < 4; ++it) {
      int c = it * 256 + tid;
      int row = c >> 3, kk = c & 7;
      int src = (kk ^ (row & 7)) * 8;
      gl_lds16(XH + (size_t)(m0 + row) * 768 + k0 + src, As + c * 8);
      gl_lds16(WT + (size_t)(j0 + row) * 768 + k0 + src, Bs + c * 8);
    }
  };

  stage(0, 0);
  int cur = 0;
  for (int kt = 0; kt < 12; ++kt) {
    if (kt < 11) {
      stage(kt + 1, cur ^ 1);
      asm volatile("s_waitcnt vmcnt(8)" ::: "memory");  // buf[kt] loads done
    } else {
      asm volatile("s_waitcnt vmcnt(0)" ::: "memory");
    }
    __builtin_amdgcn_s_barrier();
    __builtin_amdgcn_sched_barrier(0);
    const unsigned short* As = SM + cur * 16384;
    const unsigned short* Bs = As + 8192;
    __builtin_amdgcn_s_setprio(1);
#pragma unroll
    for (int ks = 0; ks < 2; ++ks) {
      bf16x8 af[4], bfr[4];
#pragma unroll
      for (int ff = 0; ff < 4; ++ff) {
        int ra = wm * 64 + ff * 16 + fr_r;
        int rb = wn * 64 + ff * 16 + fr_r;
        int cha  = ((ks * 4 + chb) ^ (ra & 7)) * 8;
        int chbb = ((ks * 4 + chb) ^ (rb & 7)) * 8;
        af[ff]  = *(const bf16x8*)(As + ra * 64 + cha);
        bfr[ff] = *(const bf16x8*)(Bs + rb * 64 + chbb);
      }
#pragma unroll
      for (int fm = 0; fm < 4; ++fm)
#pragma unroll
        for (int fn = 0; fn < 4; ++fn)
          acc[fm][fn] = __builtin_amdgcn_mfma_f32_16x16x32_bf16(af[fm], bfr[fn],
                                                                acc[fm][fn], 0, 0, 0);
    }
    __builtin_amdgcn_s_setprio(0);
    __builtin_amdgcn_s_barrier();      // all waves done reading buf[cur]
    __builtin_amdgcn_sched_barrier(0);
    cur ^= 1;
  }
  // epilogue: acc -> LDS (bf16 128x128), then coalesced 16B stores
  int cr = (lane >> 4) * 4, cc = lane & 15;
#pragma unroll
  for (int fm = 0; fm < 4; ++fm)
#pragma unroll
    for (int fn = 0; fn < 4; ++fn) {
      int col = wn * 64 + fn * 16 + cc;
      float bias = BKV[j0 + col];
      int rb = (wm * 64 + fm * 16 + cr) * 128 + col;
#pragma unroll
      for (int i = 0; i < 4; ++i)
        SM[rb + i * 128] = f2bf(acc[fm][fn][i] + bias);
    }
  __syncthreads();
#pragma unroll
  for (int it = 0; it < 8; ++it) {
    int c = it * 256 + tid;
    int row = c >> 4, cg = c & 15;
    *(bf16x8*)(KB + (size_t)(m0 + row) * 768 + j0 + cg * 8) =
        *(const bf16x8*)(SM + row * 128 + cg * 8);
  }
}

// ------------------------- hop helpers -------------------------------------
__device__ __forceinline__ void load6(const unsigned short* p, float* o) {
  ushort2 a = *(const ushort2*)(p);
  ushort2 b = *(const ushort2*)(p + 2);
  ushort2 c = *(const ushort2*)(p + 4);
  o[0] = bf2f(a.x); o[1] = bf2f(a.y);
  o[2] = bf2f(b.x); o[3] = bf2f(b.y);
  o[4] = bf2f(c.x); o[5] = bf2f(c.y);
}

// hop pass: fixed-base (m=0) softmax, block-reduced partials.
__global__ __launch_bounds__(256) void k_hop(const unsigned short* __restrict__ KB,
                                             const float* __restrict__ qin,
                                             float* __restrict__ pa,
                                             float* __restrict__ pl) {
  __shared__ float red[4][768];
  __shared__ float redl[4][128];
  int tid = threadIdx.x, blk = blockIdx.x;
  int w = tid >> 6, lane = tid & 63;
  int hb = w & 1, sub = w >> 1;
  float qv0[6], qv1[6];
  const float* qb = qin + hb * 384 + lane * 6;
#pragma unroll
  for (int j = 0; j < 6; ++j) { qv0[j] = qb[j]; qv1[j] = qb[768 + j]; }
  float l0 = 0.f, l1 = 0.f;
  float acc0[6] = {}, acc1[6] = {};
  int n0 = blk * CBLK + sub * 49;
  int nend = n0 + 49;
  if (nend > NMEM) nend = NMEM;
#pragma unroll 4
  for (int n = n0; n < nend; ++n) {
    const unsigned short* ks = KB + (size_t)n * 768 + hb * 384 + lane * 6;
    float kf[6]; load6(ks, kf);
    float sc0 = 0.f, sc1 = 0.f;
#pragma unroll
    for (int j = 0; j < 6; ++j) {
      sc0 = fmaf(kf[j], qv0[j], sc0);
      sc1 = fmaf(kf[j], qv1[j], sc1);
    }
#pragma unroll
    for (int o = 1; o < 8; o <<= 1) {
      sc0 += __shfl_xor(sc0, o);
      sc1 += __shfl_xor(sc1, o);
    }
    float e0 = __expf(sc0);
    float e1 = __expf(sc1);
    l0 += e0; l1 += e1;
#pragma unroll
    for (int j = 0; j < 6; ++j) {
      acc0[j] = fmaf(e0, kf[j], acc0[j]);
      acc1[j] = fmaf(e1, kf[j], acc1[j]);
    }
  }
#pragma unroll
  for (int j = 0; j < 6; ++j) {
    red[w][lane * 12 + j]     = acc0[j];
    red[w][lane * 12 + 6 + j] = acc1[j];
  }
  redl[w][lane * 2]     = l0;
  redl[w][lane * 2 + 1] = l1;
  __syncthreads();
  if (sub == 0) {
#pragma unroll
    for (int j = 0; j < 6; ++j) {
      acc0[j] += red[w + 2][lane * 12 + j];
      acc1[j] += red[w + 2][lane * 12 + 6 + j];
    }
    l0 += redl[w + 2][lane * 2];
    l1 += redl[w + 2][lane * 2 + 1];
    int h = hb * 8 + (lane >> 3), p = lane & 7;
    size_t b0 = ((size_t)(h * 2 + 0) * HOPB + blk) * 48 + p * 6;
    size_t b1 = ((size_t)(h * 2 + 1) * HOPB + blk) * 48 + p * 6;
#pragma unroll
    for (int j = 0; j < 6; ++j) { pa[b0 + j] = acc0[j]; pa[b1 + j] = acc1[j]; }
    if (p == 0) {
      pl[(size_t)(h * 2 + 0) * HOPB + blk] = l0;
      pl[(size_t)(h * 2 + 1) * HOPB + blk] = l1;
    }
  }
}

// merge HOPB block-partials per (b,h) -> q
__global__ __launch_bounds__(256) void k_hred(const float* __restrict__ pa,
                                              const float* __restrict__ pl,
                                              float* __restrict__ qout) {
  int b = blockIdx.x & 1, h = blockIdx.x >> 1;
  __shared__ float sred[4];
  __shared__ float p3[256];
  int t = threadIdx.x, lane = t & 63, w = t >> 6;
  size_t mlb = (size_t)(h * 2 + b) * HOPB;
  float ll = 0.f;
  for (int i = t; i < HOPB; i += 256) ll += pl[mlb + i];
#pragma unroll
  for (int o = 32; o >= 1; o >>= 1) ll += __shfl_xor(ll, o);
  if (lane == 0) sred[w] = ll;
  __syncthreads();
  float ltot = sred[0] + sred[1] + sred[2] + sred[3];
  int d = t & 63, seg = t >> 6;
  float a = 0.f;
  if (d < 48) {
#pragma unroll 4
    for (int i = seg; i < HOPB; i += 4)
      a += pa[(mlb + i) * 48 + d];
  }
  p3[seg * 64 + d] = a;
  __syncthreads();
  if (t < 48) {
    float av = p3[t] + p3[64 + t] + p3[128 + t] + p3[192 + t];
    qout[b * 768 + h * 48 + t] = SCALING_ * (av / ltot);
  }
}

// final score pass: raw scores S + block-reduced l partials (m=0)
__global__ __launch_bounds__(256) void k_escore(const unsigned short* __restrict__ KB,
                                                const float* __restrict__ qin,
                                                float* __restrict__ S,
                                                float* __restrict__ pl) {
  __shared__ float redl[4][128];
  int tid = threadIdx.x, blk = blockIdx.x;
  int w = tid >> 6, lane = tid & 63;
  int hb = w & 1, sub = w >> 1;
  float qv0[6], qv1[6];
  const float* qb = qin + hb * 384 + lane * 6;
#pragma unroll
  for (int j = 0; j < 6; ++j) { qv0[j] = qb[j]; qv1[j] = qb[768 + j]; }
  float l0 = 0.f, l1 = 0.f;
  int hl = lane >> 3, p = lane & 7;
  int h = hb * 8 + hl;
  int n0 = blk * CBLK + sub * 49;
  int nend = n0 + 49;
  if (nend > NMEM) nend = NMEM;
#pragma unroll 4
  for (int n = n0; n < nend; ++n) {
    const unsigned short* ks = KB + (size_t)n * 768 + hb * 384 + lane * 6;
    float kf[6]; load6(ks, kf);
    float sc0 = 0.f, sc1 = 0.f;
#pragma unroll
    for (int j = 0; j < 6; ++j) {
      sc0 = fmaf(kf[j], qv0[j], sc0);
      sc1 = fmaf(kf[j], qv1[j], sc1);
    }
#pragma unroll
    for (int o = 1; o < 8; o <<= 1) {
      sc0 += __shfl_xor(sc0, o);
      sc1 += __shfl_xor(sc1, o);
    }
    if (p == 0) {
      S[(size_t)n * 32 + h]      = sc0;
      S[(size_t)n * 32 + 16 + h] = sc1;
    }
    l0 += __expf(sc0);
    l1 += __expf(sc1);
  }
  redl[w][lane * 2]     = l0;
  redl[w][lane * 2 + 1] = l1;
  __syncthreads();
  if (sub == 0) {
    l0 += redl[w + 2][lane * 2];
    l1 += redl[w + 2][lane * 2 + 1];
    if (p == 0) {
      pl[(size_t)(h * 2 + 0) * HOPB + blk] = l0;
      pl[(size_t)(h * 2 + 1) * HOPB + blk] = l1;
    }
  }
}

// merge -> C[bh] = log(sum l)
__global__ __launch_bounds__(256) void k_hredM(const float* __restrict__ pl,
                                               float* __restrict__ C) {
  int b = blockIdx.x & 1, h = blockIdx.x >> 1;
  __shared__ float sred[4];
  int t = threadIdx.x, lane = t & 63, w = t >> 6;
  size_t mlb = (size_t)(h * 2 + b) * HOPB;
  float ll = 0.f;
  for (int i = t; i < HOPB; i += 256) ll += pl[mlb + i];
#pragma unroll
  for (int o = 32; o >= 1; o >>= 1) ll += __shfl_xor(ll, o);
  if (lane == 0) sred[w] = ll;
  __syncthreads();
  if (t == 0) C[b * 16 + h] = logf(sred[0] + sred[1] + sred[2] + sred[3]);
}

// ------------------------- u-pass (fused wexp) ------------------------------
__global__ __launch_bounds__(256) void k_upass(const unsigned short* __restrict__ XH,
                                               const float* __restrict__ S,
                                               const float* __restrict__ C,
                                               float* __restrict__ UP) {
  __shared__ float SW[64 * 32];
  __shared__ float cc[32];
  int kb = blockIdx.x, t = threadIdx.x;
  if (t < 32) cc[t] = C[t];
  float a0[32], a1[32], a2[32];
#pragma unroll
  for (int i = 0; i < 32; ++i) { a0[i] = 0.f; a1[i] = 0.f; a2[i] = 0.f; }
  int n0 = kb * UROWS;
  int nend = n0 + UROWS; if (nend > NMEM) nend = NMEM;
  for (int ns = n0; ns < nend; ns += 64) {
    int sub = nend - ns; if (sub > 64) sub = 64;
    __syncthreads();
    for (int i = t; i < sub * 32; i += 256)
      SW[i] = __expf(S[(size_t)ns * 32 + i] - cc[i & 31]);
    __syncthreads();
    for (int r = 0; r < sub; ++r) {
      const unsigned short* xr = XH + (size_t)(ns + r) * 768;
      float x0 = bf2f(xr[t]), x1 = bf2f(xr[t + 256]), x2 = bf2f(xr[t + 512]);
      const float4* w4 = (const float4*)(SW + r * 32);
#pragma unroll
      for (int c = 0; c < 8; ++c) {
        float4 wv = w4[c];
        a0[c * 4 + 0] = fmaf(wv.x, x0, a0[c * 4 + 0]);
        a0[c * 4 + 1] = fmaf(wv.y, x0, a0[c * 4 + 1]);
        a0[c * 4 + 2] = fmaf(wv.z, x0, a0[c * 4 + 2]);
        a0[c * 4 + 3] = fmaf(wv.w, x0, a0[c * 4 + 3]);
        a1[c * 4 + 0] = fmaf(wv.x, x1, a1[c * 4 + 0]);
        a1[c * 4 + 1] = fmaf(wv.y, x1, a1[c * 4 + 1]);
        a1[c * 4 + 2] = fmaf(wv.z, x1, a1[c * 4 + 2]);
        a1[c * 4 + 3] = fmaf(wv.w, x1, a1[c * 4 + 3]);
        a2[c * 4 + 0] = fmaf(wv.x, x2, a2[c * 4 + 0]);
        a2[c * 4 + 1] = fmaf(wv.y, x2, a2[c * 4 + 1]);
        a2[c * 4 + 2] = fmaf(wv.z, x2, a2[c * 4 + 2]);
        a2[c * 4 + 3] = fmaf(wv.w, x2, a2[c * 4 + 3]);
      }
    }
  }
#pragma unroll
  for (int bh = 0; bh < 32; ++bh) {
    size_t base = ((size_t)kb * 32 + bh) * 768;
    UP[base + t]       = a0[bh];
    UP[base + 256 + t] = a1[bh];
    UP[base + 512 + t] = a2[bh];
  }
}

__global__ __launch_bounds__(256) void k_ured(const float* __restrict__ UP,
                                              float* __restrict__ U) {
  int o = blockIdx.x * 256 + threadIdx.x;
  float s0 = 0.f, s1 = 0.f, s2 = 0.f, s3 = 0.f;
#pragma unroll 4
  for (int kb = 0; kb < UKS; kb += 4) {
    s0 += UP[(size_t)(kb + 0) * 24576 + o];
    s1 += UP[(size_t)(kb + 1) * 24576 + o];
    s2 += UP[(size_t)(kb + 2) * 24576 + o];
    s3 += UP[(size_t)(kb + 3) * 24576 + o];
  }
  U[o] = (s0 + s1) + (s2 + s3);
}

__global__ __launch_bounds__(256) void k_outproj(const float* __restrict__ U,
                                                 const unsigned short* __restrict__ WT,
                                                 const float* __restrict__ BKV,
                                                 float* __restrict__ outa) {
  int gw = blockIdx.x * 4 + (threadIdx.x >> 6);
  int lane = threadIdx.x & 63;
  int b = gw >= 768;
  int j = gw - b * 768;
  int h = j / 48;
  const float* u = U + (size_t)(b * 16 + h) * 768;
  const unsigned short* wr = WT + (size_t)(768 + j) * 768;
  float a = 0.f;
  for (int d = lane; d < 768; d += 64) a = fmaf(u[d], bf2f(wr[d]), a);
#pragma unroll
  for (int o = 32; o >= 1; o >>= 1) a += __shfl_xor(a, o);
  if (lane == 0) outa[b * 768 + j] = a + BKV[768 + j];
}

// ------------------------- pooled / norm -----------------------------------
__global__ __launch_bounds__(256) void k_pooled(const float* __restrict__ outa,
                                                const float* __restrict__ Wo,
                                                const float* __restrict__ bo,
                                                float* __restrict__ dp) {
  __shared__ float xs[768];
  __shared__ float pr[256];
  int b = blockIdx.y, jc = blockIdx.x, t = threadIdx.x;
  xs[t]       = outa[b * 768 + t];
  xs[t + 256] = outa[b * 768 + 256 + t];
  xs[t + 512] = outa[b * 768 + 512 + t];
  __syncthreads();
  int w = t >> 6, lane = t & 63;
  int j = jc * 64 + lane;
  float a = 0.f;
  int d0 = w * 192;
  for (int d = d0; d < d0 + 192; ++d) a = fmaf(xs[d], Wo[(size_t)d * 768 + j], a);
  pr[t] = a;
  __syncthreads();
  if (t < 64) {
    float sv = pr[t] + pr[64 + t] + pr[128 + t] + pr[192 + t];
    int j2 = jc * 64 + t;
    dp[b * 768 + j2] = sv + bo[j2];
  }
}

__global__ __launch_bounds__(256) void k_pnorm(const float* __restrict__ dp,
                                               float* __restrict__ PN) {
  int b = blockIdx.x, t = threadIdx.x;
  __shared__ float sred[8];
  float x0 = dp[b * 768 + t], x1 = dp[b * 768 + 256 + t], x2 = dp[b * 768 + 512 + t];
  float s2 = x0 * x0 + x1 * x1 + x2 * x2;
#pragma unroll
  for (int o = 32; o >= 1; o >>= 1) s2 += __shfl_xor(s2, o);
  int lane = t & 63, w = t >> 6;
  if (lane == 0) sred[w] = s2;
  __syncthreads();
  float tot = sred[0] + sred[1] + sred[2] + sred[3];
  float rs = rsqrtf(tot);
  PN[b * 768 + t]       = x0 * rs;
  PN[b * 768 + 256 + t] = x1 * rs;
  PN[b * 768 + 512 + t] = x2 * rs;
}

// ------------------------- similarity + top-4 (contiguous chunks) ----------
__global__ __launch_bounds__(256) void k_sim(const float* __restrict__ mem,
                                             const float* __restrict__ PN,
                                             const float* __restrict__ rnorm,
                                             float* __restrict__ tval,
                                             int* __restrict__ tidx) {
  int gw = (blockIdx.x * 256 + threadIdx.x) >> 6;   // 8192 waves
  int lane = threadIdx.x & 63;
  const float4* pa = (const float4*)(PN);
  const float4* pb = (const float4*)(PN + 768);
  float4 qa0 = pa[lane], qa1 = pa[lane + 64], qa2 = pa[lane + 128];
  float4 qb0 = pb[lane], qb1 = pb[lane + 64], qb2 = pb[lane + 128];
  Top4 t0, t1; t0.init(); t1.init();
  int n0 = gw * 13;
  int nend = n0 + 13; if (nend > NMEM) nend = NMEM;
  for (int n = n0; n < nend; ++n) {
    const float4* r = (const float4*)(mem + (size_t)n * 768);
    float4 x0 = r[lane], x1 = r[lane + 64], x2 = r[lane + 128];
    float d0 = x0.x * qa0.x + x0.y * qa0.y + x0.z * qa0.z + x0.w * qa0.w +
               x1.x * qa1.x + x1.y * qa1.y + x1.z * qa1.z + x1.w * qa1.w +
               x2.x * qa2.x + x2.y * qa2.y + x2.z * qa2.z + x2.w * qa2.w;
    float d1 = x0.x * qb0.x + x0.y * qb0.y + x0.z * qb0.z + x0.w * qb0.w +
               x1.x * qb1.x + x1.y * qb1.y + x1.z * qb1.z + x1.w * qb1.w +
               x2.x * qb2.x + x2.y * qb2.y + x2.z * qb2.z + x2.w * qb2.w;
#pragma unroll
    for (int o = 32; o >= 1; o >>= 1) { d0 += __shfl_xor(d0, o); d1 += __shfl_xor(d1, o); }
    float rn = rnorm[n];
    t0.ins(d0 * rn, n);
    t1.ins(d1 * rn, n);
  }
  if (lane == 0) {
    int base = gw * 8;
    tval[base + 0] = t0.v0; tval[base + 1] = t0.v1; tval[base + 2] = t0.v2; tval[base + 3] = t0.v3;
    tval[base + 4] = t1.v0; tval[base + 5] = t1.v1; tval[base + 6] = t1.v2; tval[base + 7] = t1.v3;
    tidx[base + 0] = t0.i0; tidx[base + 1] = t0.i1; tidx[base + 2] = t0.i2; tidx[base + 3] = t0.i3;
    tidx[base + 4] = t1.i0; tidx[base + 5] = t1.i1; tidx[base + 6] = t1.i2; tidx[base + 7] = t1.i3;
  }
}

__global__ __launch_bounds__(256) void k_top1(const float* __restrict__ tval,
                                              const int* __restrict__ tidx,
                                              float* __restrict__ ptv,
                                              int* __restrict__ pti) {
  __shared__ float lv[4][8];
  __shared__ int   li[4][8];
  int z = blockIdx.x, t = threadIdx.x;
  int lane = t & 63, w = t >> 6;
  int wv = z * 256 + t;
  Top4 a, b; a.init(); b.init();
#pragma unroll
  for (int r = 0; r < 4; ++r) {
    a.ins(tval[wv * 8 + r],     tidx[wv * 8 + r]);
    b.ins(tval[wv * 8 + 4 + r], tidx[wv * 8 + 4 + r]);
  }
  bfly(a, 32);
  bfly(b, 32);
  if (lane == 0) {
    lv[w][0] = a.v0; lv[w][1] = a.v1; lv[w][2] = a.v2; lv[w][3] = a.v3;
    lv[w][4] = b.v0; lv[w][5] = b.v1; lv[w][6] = b.v2; lv[w][7] = b.v3;
    li[w][0] = a.i0; li[w][1] = a.i1; li[w][2] = a.i2; li[w][3] = a.i3;
    li[w][4] = b.i0; li[w][5] = b.i1; li[w][6] = b.i2; li[w][7] = b.i3;
  }
  __syncthreads();
  if (t < 2) {
    Top4 m_; m_.init();
#pragma unroll
    for (int w2 = 0; w2 < 4; ++w2)
#pragma unroll
      for (int r = 0; r < 4; ++r) m_.ins(lv[w2][t * 4 + r], li[w2][t * 4 + r]);
    int base = z * 8 + t * 4;
    ptv[base + 0] = m_.v0; ptv[base + 1] = m_.v1;
    ptv[base + 2] = m_.v2; ptv[base + 3] = m_.v3;
    pti[base + 0] = m_.i0; pti[base + 1] = m_.i1;
    pti[base + 2] = m_.i2; pti[base + 3] = m_.i3;
  }
}

__global__ __launch_bounds__(64) void k_top2(const float* __restrict__ ptv,
                                             const int* __restrict__ pti,
                                             float* __restrict__ dout) {
  int t = threadIdx.x;
  int half = t >> 5, e = t & 31;
  Top4 a; a.init();
#pragma unroll
  for (int r = 0; r < 4; ++r)
    a.ins(ptv[e * 8 + half * 4 + r], pti[e * 8 + half * 4 + r]);
  bfly(a, 16);
  if (e == 0) {
    dout[half * 4 + 0] = (float)a.i0;
    dout[half * 4 + 1] = (float)a.i1;
    dout[half * 4 + 2] = (float)a.i2;
    dout[half * 4 + 3] = (float)a.i3;
  }
}

// ---------------------------------------------------------------------------
extern "C" void kernel_launch(void* const* d_in, const int* in_sizes, int n_in,
                              void* d_out, int out_size, void* d_ws, size_t ws_size,
                              hipStream_t stream) {
  const float* qe     = (const float*)d_in[0];
  const float* mem    = (const float*)d_in[1];
  const float* ln_q_g = (const float*)d_in[2];
  const float* ln_q_b = (const float*)d_in[3];
  const float* ln_s_g = (const float*)d_in[4];
  const float* ln_s_b = (const float*)d_in[5];
  const float* ln_p_g = (const float*)d_in[6];
  const float* ln_p_b = (const float*)d_in[7];
  const float* Wq = (const float*)d_in[8];  const float* bq = (const float*)d_in[9];
  const float* Wk = (const float*)d_in[10]; const float* bk = (const float*)d_in[11];
  const float* Wv = (const float*)d_in[12]; const float* bv = (const float*)d_in[13];
  const float* Wo = (const float*)d_in[14]; const float* bo = (const float*)d_in[15];

  char* w = (char*)d_ws;
  size_t off = 0;
  auto alloc = [&](size_t bytes) {
    size_t o = off;
    off += (bytes + 255) & ~(size_t)255;
    return o;
  };
  unsigned short* WT   = (unsigned short*)(w + alloc((size_t)1536 * 768 * 2));
  float*          PB   = (float*)(w + alloc(8 * 1536 * 4));
  float*          BKV  = (float*)(w + alloc(1536 * 4));
  float*          QBUF = (float*)(w + alloc(1536 * 4));
  float*          OUTA = (float*)(w + alloc(1536 * 4));
  float*          PN   = (float*)(w + alloc(1536 * 4));
  float*          CML  = (float*)(w + alloc(32 * 4));
  float*          UBUF = (float*)(w + alloc((size_t)24576 * 4));
  float*          RNORM= (float*)(w + alloc((size_t)NPAD * 4));
  unsigned short* XH   = (unsigned short*)(w + alloc((size_t)NPAD * 768 * 2));
  unsigned short* KB   = (unsigned short*)(w + alloc((size_t)NPAD * 768 * 2));
  float*          PA   = (float*)(w + alloc((size_t)32 * HOPB * 48 * 4));
  float*          PL   = (float*)(w + alloc((size_t)32 * HOPB * 4));
  float*          SB   = (float*)(w + alloc((size_t)NMEM * 32 * 4));
  float*          UP   = (float*)(w + alloc((size_t)UKS * 24576 * 4));
  float*          TVAL = (float*)(w + alloc((size_t)8192 * 8 * 4));
  int*            TIDX = (int*)(w + alloc((size_t)8192 * 8 * 4));
  float*          PTV  = (float*)(w + alloc((size_t)32 * 8 * 4));
  int*            PTI  = (int*)(w + alloc((size_t)32 * 8 * 4));
  if (off > ws_size) {
    fprintf(stderr, "[hopfield] ws too small: need %zu have %zu\n", off, ws_size);
    return;
  }
  float* dout = (float*)d_out;

  k_fold_wt  <<<dim3(12, 12, 2), 256, 0, stream>>>(Wk, Wv, ln_s_g, ln_p_g, WT);
  k_fold_bias<<<dim3(6, 8), 256, 0, stream>>>(Wk, Wv, ln_s_b, ln_p_b, PB);
  k_bias_red <<<6, 256, 0, stream>>>(PB, bk, bv, BKV);
  k_q0       <<<dim3(12, 2), 256, 0, stream>>>(qe, ln_q_g, ln_q_b, Wq, bq, QBUF);
  k_ln       <<<1024, 256, 0, stream>>>(mem, XH, RNORM);
  k_gemm     <<<98 * 6 * 8, 256, 0, stream>>>(XH, WT, BKV, KB);
  for (int step = 0; step < 5; ++step) {
    k_hop    <<<HOPB, 256, 0, stream>>>(KB, QBUF, PA, PL);
    k_hred   <<<32, 256, 0, stream>>>(PA, PL, QBUF);
  }
  k_escore   <<<HOPB, 256, 0, stream>>>(KB, QBUF, SB, PL);
  k_hredM    <<<32, 256, 0, stream>>>(PL, CML);
  k_upass    <<<UKS, 256, 0, stream>>>(XH, SB, CML, UP);
  k_ured     <<<96, 256, 0, stream>>>(UP, UBUF);
  k_outproj  <<<384, 256, 0, stream>>>(UBUF, WT, BKV, OUTA);
  k_pooled   <<<dim3(12, 2), 256, 0, stream>>>(OUTA, Wo, bo, dout + 8);
  k_pnorm    <<<2, 256, 0, stream>>>(dout + 8, PN);
  k_sim      <<<2048, 256, 0, stream>>>(mem, PN, RNORM, TVAL, TIDX);
  k_top1     <<<32, 256, 0, stream>>>(TVAL, TIDX, PTV, PTI);
  k_top2     <<<1, 64, 0, stream>>>(PTV, PTI, dout);
}

// Round 14
// 776.135 us; speedup vs baseline: 1.9434x; 1.0965x over previous
//
#include <hip/hip_runtime.h>
#include <cstdio>
#include <cstdint>

// ---------------------------------------------------------------------------
// HopfieldPoolingRouter on MI355X — V-free, fixed-base softmax, block-partial
// hops + 256-block split merges (8-way atomics), q recomputed on the fly.
//   k: KB = LN(mem)@WTk^T + BKVk  (bf16 MFMA, BK=64, swizzled, vmcnt(8))
//   slots: QN[7][32][48], LT[7][32]. slot0 = q0 (LT=1), zeroed ahead of use.
//   hop s: q = 0.25*QN[s]/LT[s]; stream KB; block-reduce -> PA/PL partials;
//          block 0 zeroes slot s+2.
//   hred s (256 blocks): sum 128-partial slice -> 48 atomicAdds into QN[s+1].
//   escore: q from slot5; writes S; PL partials -> hredM -> C = log L.
//   upass: w = exp(S-C); u = sum w*XH;  outproj (V eliminated); pooled; top4.
// ---------------------------------------------------------------------------

#define NMEM 100000
#define NPAD 100096          // 782 * 128
#define HOPB 1024            // hop-pass blocks; partials per (b,h)
#define CBLK 98              // rows per hop block (1024*98 >= 100000)
#define UKS  512
#define UROWS 196
#define SCALING_ 0.25f

typedef __attribute__((ext_vector_type(8))) short bf16x8;
typedef __attribute__((ext_vector_type(4))) float f32x4;

__device__ __forceinline__ unsigned short f2bf(float f) {
  union { float f; unsigned u; } c; c.f = f;
  unsigned u = c.u + 0x7fffu + ((c.u >> 16) & 1u);   // RNE
  return (unsigned short)(u >> 16);
}
__device__ __forceinline__ float bf2f(unsigned short h) {
  union { unsigned u; float f; } c; c.u = ((unsigned)h) << 16;
  return c.f;
}
__device__ __forceinline__ void gl_lds16(const void* g, void* l) {
  __builtin_amdgcn_global_load_lds(
      (const __attribute__((address_space(1))) unsigned int*)g,
      (__attribute__((address_space(3))) unsigned int*)l, 16, 0, 0);
}

__device__ __forceinline__ bool bet(float s, int n, float v, int i) {
  return (s > v) || (s == v && n < i);
}
struct Top4 {
  float v0, v1, v2, v3;
  int   i0, i1, i2, i3;
  __device__ __forceinline__ void init() {
    v0 = v1 = v2 = v3 = -INFINITY;
    i0 = i1 = i2 = i3 = 0x7fffffff;
  }
  __device__ __forceinline__ void ins(float s, int n) {
    bool c0 = bet(s, n, v0, i0), c1 = bet(s, n, v1, i1);
    bool c2 = bet(s, n, v2, i2), c3 = bet(s, n, v3, i3);
    float w0 = c0 ? s : v0;             int j0 = c0 ? n : i0;
    float w1 = c0 ? v0 : (c1 ? s : v1); int j1 = c0 ? i0 : (c1 ? n : i1);
    float w2 = c1 ? v1 : (c2 ? s : v2); int j2 = c1 ? i1 : (c2 ? n : i2);
    float w3 = c2 ? v2 : (c3 ? s : v3); int j3 = c2 ? i2 : (c3 ? n : i3);
    v0 = w0; v1 = w1; v2 = w2; v3 = w3;
    i0 = j0; i1 = j1; i2 = j2; i3 = j3;
  }
};
__device__ __forceinline__ void bfly(Top4& a, int omax) {
  for (int o = omax; o >= 1; o >>= 1) {
    float w0 = __shfl_xor(a.v0, o), w1 = __shfl_xor(a.v1, o);
    float w2 = __shfl_xor(a.v2, o), w3 = __shfl_xor(a.v3, o);
    int   j0 = __shfl_xor(a.i0, o), j1 = __shfl_xor(a.i1, o);
    int   j2 = __shfl_xor(a.i2, o), j3 = __shfl_xor(a.i3, o);
    a.ins(w0, j0); a.ins(w1, j1); a.ins(w2, j2); a.ins(w3, j3);
  }
}

// ------------------------- weight folding ----------------------------------
__global__ __launch_bounds__(256) void k_fold_wt(const float* __restrict__ Wk,
                                                 const float* __restrict__ Wv,
                                                 const float* __restrict__ gs,
                                                 const float* __restrict__ gp,
                                                 unsigned short* __restrict__ WT) {
  __shared__ float ts[64][65];
  int d0 = blockIdx.x * 64, j0 = blockIdx.y * 64, z = blockIdx.z;
  const float* W = z ? Wv : Wk;
  const float* g = z ? gp : gs;
  int t = threadIdx.x, c = t & 63, r4 = t >> 6;
#pragma unroll
  for (int p = 0; p < 16; ++p) {
    int r = p * 4 + r4;
    ts[r][c] = g[d0 + r] * W[(size_t)(d0 + r) * 768 + j0 + c];
  }
  __syncthreads();
#pragma unroll
  for (int p = 0; p < 16; ++p) {
    int jr = p * 4 + r4;
    WT[(size_t)(z * 768 + j0 + jr) * 768 + d0 + c] = f2bf(ts[c][jr]);
  }
}

__global__ __launch_bounds__(256) void k_fold_bias(const float* __restrict__ Wk,
                                                   const float* __restrict__ Wv,
                                                   const float* __restrict__ bs,
                                                   const float* __restrict__ bp,
                                                   float* __restrict__ PB) {
  int jc = blockIdx.x, dz = blockIdx.y, t = threadIdx.x;
  int j = jc * 256 + t;
  const float* W  = (j < 768) ? Wk : Wv;
  const float* bb = (j < 768) ? bs : bp;
  int jj = (j < 768) ? j : j - 768;
  float a = 0.f;
  int dend = dz * 96 + 96;
  for (int d = dz * 96; d < dend; ++d) a = fmaf(bb[d], W[(size_t)d * 768 + jj], a);
  PB[dz * 1536 + j] = a;
}

__global__ __launch_bounds__(256) void k_bias_red(const float* __restrict__ PB,
                                                  const float* __restrict__ bk,
                                                  const float* __restrict__ bv,
                                                  float* __restrict__ BKV) {
  int j = blockIdx.x * 256 + threadIdx.x;
  float a = (j < 768) ? bk[j] : bv[j - 768];
#pragma unroll
  for (int dz = 0; dz < 8; ++dz) a += PB[dz * 1536 + j];
  BKV[j] = a;
}

// ------------------------- q0 -> QN slot 0 (LT=1), zero slot 1 --------------
__global__ __launch_bounds__(256) void k_q0(const float* __restrict__ qe,
                                            const float* __restrict__ gq,
                                            const float* __restrict__ bq_ln,
                                            const float* __restrict__ Wq,
                                            const float* __restrict__ bq,
                                            float* __restrict__ QN,
                                            float* __restrict__ LT) {
  int b = blockIdx.y, jc = blockIdx.x, t = threadIdx.x;
  __shared__ float xs[768];
  __shared__ float sred[16];
  __shared__ float pr[256];
  if (jc == 0 && b == 0) {
    for (int i = t; i < 1536; i += 256) QN[1536 + i] = 0.f;
    if (t < 32) { LT[t] = 1.0f; LT[32 + t] = 0.f; }
  }
  float x0 = qe[b * 768 + t], x1 = qe[b * 768 + 256 + t], x2 = qe[b * 768 + 512 + t];
  float s = x0 + x1 + x2, s2 = x0 * x0 + x1 * x1 + x2 * x2;
#pragma unroll
  for (int o = 32; o >= 1; o >>= 1) { s += __shfl_xor(s, o); s2 += __shfl_xor(s2, o); }
  int lane = t & 63, w = t >> 6;
  if (lane == 0) { sred[w] = s; sred[8 + w] = s2; }
  __syncthreads();
  s  = sred[0] + sred[1] + sred[2] + sred[3];
  s2 = sred[8] + sred[9] + sred[10] + sred[11];
  float mean = s * (1.f / 768.f);
  float var  = s2 * (1.f / 768.f) - mean * mean;
  float rstd = rsqrtf(var + 1e-5f);
  xs[t]       = (x0 - mean) * rstd * gq[t]       + bq_ln[t];
  xs[t + 256] = (x1 - mean) * rstd * gq[t + 256] + bq_ln[t + 256];
  xs[t + 512] = (x2 - mean) * rstd * gq[t + 512] + bq_ln[t + 512];
  __syncthreads();
  int j = jc * 64 + lane;
  float a = 0.f;
  int d0 = w * 192;
  for (int d = d0; d < d0 + 192; ++d) a = fmaf(xs[d], Wq[(size_t)d * 768 + j], a);
  pr[t] = a;
  __syncthreads();
  if (t < 64) {
    float sv = pr[t] + pr[64 + t] + pr[128 + t] + pr[192 + t];
    int j2 = jc * 64 + t;
    int h = j2 / 48, dh = j2 - h * 48;
    QN[(h * 2 + b) * 48 + dh] = sv + bq[j2];   // slot 0, unscaled; LT0 = 1
  }
}

// ------------------------- memory LN + rnorm --------------------------------
__global__ __launch_bounds__(256) void k_ln(const float* __restrict__ mem,
                                            unsigned short* __restrict__ XH,
                                            float* __restrict__ rnorm) {
  int gw = (blockIdx.x * 256 + threadIdx.x) >> 6;   // 4096 waves
  int lane = threadIdx.x & 63;
  int n0 = gw * 25;
  int nend = n0 + 25; if (nend > NPAD) nend = NPAD;
  for (int n = n0; n < nend; ++n) {
    ushort4* orow = (ushort4*)(XH + (size_t)n * 768);
    if (n >= NMEM) {
      ushort4 z; z.x = z.y = z.z = z.w = 0;
      orow[lane] = z; orow[lane + 64] = z; orow[lane + 128] = z;
      continue;
    }
    const float4* r = (const float4*)(mem + (size_t)n * 768);
    float4 x0 = r[lane], x1 = r[lane + 64], x2 = r[lane + 128];
    float s  = x0.x + x0.y + x0.z + x0.w + x1.x + x1.y + x1.z + x1.w +
               x2.x + x2.y + x2.z + x2.w;
    float s2 = x0.x * x0.x + x0.y * x0.y + x0.z * x0.z + x0.w * x0.w +
               x1.x * x1.x + x1.y * x1.y + x1.z * x1.z + x1.w * x1.w +
               x2.x * x2.x + x2.y * x2.y + x2.z * x2.z + x2.w * x2.w;
#pragma unroll
    for (int o = 32; o >= 1; o >>= 1) { s += __shfl_xor(s, o); s2 += __shfl_xor(s2, o); }
    float mean = s * (1.f / 768.f);
    float var  = s2 * (1.f / 768.f) - mean * mean;
    float rstd = rsqrtf(var + 1e-5f);
    if (lane == 0) rnorm[n] = rsqrtf(s2);
    ushort4 o0, o1, o2;
    o0.x = f2bf((x0.x - mean) * rstd); o0.y = f2bf((x0.y - mean) * rstd);
    o0.z = f2bf((x0.z - mean) * rstd); o0.w = f2bf((x0.w - mean) * rstd);
    o1.x = f2bf((x1.x - mean) * rstd); o1.y = f2bf((x1.y - mean) * rstd);
    o1.z = f2bf((x1.z - mean) * rstd); o1.w = f2bf((x1.w - mean) * rstd);
    o2.x = f2bf((x2.x - mean) * rstd); o2.y = f2bf((x2.y - mean) * rstd);
    o2.z = f2bf((x2.z - mean) * rstd); o2.w = f2bf((x2.w - mean) * rstd);
    orow[lane] = o0; orow[lane + 64] = o1; orow[lane + 128] = o2;
  }
}

// ------------------------- projection GEMM (BK=64, swizzle, vmcnt8) ---------
__global__ __launch_bounds__(256) void k_gemm(const unsigned short* __restrict__ XH,
                                              const unsigned short* __restrict__ WT,
                                              const float* __restrict__ BKV,
                                              unsigned short* __restrict__ KB) {
  __shared__ __align__(16) unsigned short SM[32768];
  int f = blockIdx.x;
  int xcd = f & 7, s = f >> 3;
  int g = s / 6, jt = s - g * 6;
  int mt = g * 8 + xcd;
  if (mt >= 782) return;
  int m0 = mt * 128, j0 = jt * 128;
  int tid = threadIdx.x;
  int wave = tid >> 6, lane = tid & 63;
  int wm = wave >> 1, wn = wave & 1;
  int fr_r = lane & 15, chb = lane >> 4;
  f32x4 acc[4][4] = {};

  auto stage = [&](int kt, int bb) {
    unsigned short* As = SM + bb * 16384;
    unsigned short* Bs = As + 8192;
    int k0 = kt * 64;
#pragma unroll
    for (int it = 0; it < 4; ++it) {
      int c = it * 256 + tid;
      int row = c >> 3, kk = c & 7;
      int src = (kk ^ (row & 7)) * 8;
      gl_lds16(XH + (size_t)(m0 + row) * 768 + k0 + src, As + c * 8);
      gl_lds16(WT + (size_t)(j0 + row) * 768 + k0 + src, Bs + c * 8);
    }
  };

  stage(0, 0);
  int cur = 0;
  for (int kt = 0; kt < 12; ++kt) {
    if (kt < 11) {
      stage(kt + 1, cur ^ 1);
      asm volatile("s_waitcnt vmcnt(8)" ::: "memory");
    } else {
      asm volatile("s_waitcnt vmcnt(0)" ::: "memory");
    }
    __builtin_amdgcn_s_barrier();
    __builtin_amdgcn_sched_barrier(0);
    const unsigned short* As = SM + cur * 16384;
    const unsigned short* Bs = As + 8192;
    __builtin_amdgcn_s_setprio(1);
#pragma unroll
    for (int ks = 0; ks < 2; ++ks) {
      bf16x8 af[4], bfr[4];
#pragma unroll
      for (int ff = 0; ff < 4; ++ff) {
        int ra = wm * 64 + ff * 16 + fr_r;
        int rb = wn * 64 + ff * 16 + fr_r;
        int cha  = ((ks * 4 + chb) ^ (ra & 7)) * 8;
        int chbb = ((ks * 4 + chb) ^ (rb & 7)) * 8;
        af[ff]  = *(const bf16x8*)(As + ra * 64 + cha);
        bfr[ff] = *(const bf16x8*)(Bs + rb * 64 + chbb);
      }
#pragma unroll
      for (int fm = 0; fm < 4; ++fm)
#pragma unroll
        for (int fn = 0; fn < 4; ++fn)
          acc[fm][fn] = __builtin_amdgcn_mfma_f32_16x16x32_bf16(af[fm], bfr[fn],
                                                                acc[fm][fn], 0, 0, 0);
    }
    __builtin_amdgcn_s_setprio(0);
    __builtin_amdgcn_s_barrier();
    __builtin_amdgcn_sched_barrier(0);
    cur ^= 1;
  }
  int cr = (lane >> 4) * 4, cc = lane & 15;
#pragma unroll
  for (int fm = 0; fm < 4; ++fm)
#pragma unroll
    for (int fn = 0; fn < 4; ++fn) {
      int col = wn * 64 + fn * 16 + cc;
      float bias = BKV[j0 + col];
      int rb = (wm * 64 + fm * 16 + cr) * 128 + col;
#pragma unroll
      for (int i = 0; i < 4; ++i)
        SM[rb + i * 128] = f2bf(acc[fm][fn][i] + bias);
    }
  __syncthreads();
#pragma unroll
  for (int it = 0; it < 8; ++it) {
    int c = it * 256 + tid;
    int row = c >> 4, cg = c & 15;
    *(bf16x8*)(KB + (size_t)(m0 + row) * 768 + j0 + cg * 8) =
        *(const bf16x8*)(SM + row * 128 + cg * 8);
  }
}

// ------------------------- hop helpers --------------------------------------
__device__ __forceinline__ void load6(const unsigned short* p, float* o) {
  ushort2 a = *(const ushort2*)(p);
  ushort2 b = *(const ushort2*)(p + 2);
  ushort2 c = *(const ushort2*)(p + 4);
  o[0] = bf2f(a.x); o[1] = bf2f(a.y);
  o[2] = bf2f(b.x); o[3] = bf2f(b.y);
  o[4] = bf2f(c.x); o[5] = bf2f(c.y);
}

// hop pass s: q = 0.25*QN[s]/LT[s]; PA/PL block partials; blk0 zeroes slot s+2
__global__ __launch_bounds__(256) void k_hop(const unsigned short* __restrict__ KB,
                                             const float* __restrict__ QN,
                                             const float* __restrict__ LT,
                                             float* __restrict__ QNz,
                                             float* __restrict__ LTz,
                                             float* __restrict__ pa,
                                             float* __restrict__ pl,
                                             int s) {
  __shared__ float red[4][768];
  __shared__ float redl[4][128];
  int tid = threadIdx.x, blk = blockIdx.x;
  int w = tid >> 6, lane = tid & 63;
  int hb = w & 1, sub = w >> 1;
  if (blk == 0) {                      // zero slot s+2 for hred_{s+1}
    for (int i = tid; i < 1536; i += 256) QNz[(s + 2) * 1536 + i] = 0.f;
    if (tid < 32) LTz[(s + 2) * 32 + tid] = 0.f;
  }
  int h = hb * 8 + (lane >> 3), p = lane & 7;
  const float* Ap = QN + s * 1536;
  const float* Lp = LT + s * 32;
  float rl0 = SCALING_ / Lp[h * 2 + 0];
  float rl1 = SCALING_ / Lp[h * 2 + 1];
  float qv0[6], qv1[6];
#pragma unroll
  for (int j = 0; j < 6; ++j) {
    qv0[j] = rl0 * Ap[(h * 2 + 0) * 48 + p * 6 + j];
    qv1[j] = rl1 * Ap[(h * 2 + 1) * 48 + p * 6 + j];
  }
  float l0 = 0.f, l1 = 0.f;
  float acc0[6] = {}, acc1[6] = {};
  int n0 = blk * CBLK + sub * 49;
  int nend = n0 + 49;
  if (nend > NMEM) nend = NMEM;
#pragma unroll 4
  for (int n = n0; n < nend; ++n) {
    const unsigned short* ks = KB + (size_t)n * 768 + hb * 384 + lane * 6;
    float kf[6]; load6(ks, kf);
    float sc0 = 0.f, sc1 = 0.f;
#pragma unroll
    for (int j = 0; j < 6; ++j) {
      sc0 = fmaf(kf[j], qv0[j], sc0);
      sc1 = fmaf(kf[j], qv1[j], sc1);
    }
#pragma unroll
    for (int o = 1; o < 8; o <<= 1) {
      sc0 += __shfl_xor(sc0, o);
      sc1 += __shfl_xor(sc1, o);
    }
    float e0 = __expf(sc0);
    float e1 = __expf(sc1);
    l0 += e0; l1 += e1;
#pragma unroll
    for (int j = 0; j < 6; ++j) {
      acc0[j] = fmaf(e0, kf[j], acc0[j]);
      acc1[j] = fmaf(e1, kf[j], acc1[j]);
    }
  }
#pragma unroll
  for (int j = 0; j < 6; ++j) {
    red[w][lane * 12 + j]     = acc0[j];
    red[w][lane * 12 + 6 + j] = acc1[j];
  }
  redl[w][lane * 2]     = l0;
  redl[w][lane * 2 + 1] = l1;
  __syncthreads();
  if (sub == 0) {
#pragma unroll
    for (int j = 0; j < 6; ++j) {
      acc0[j] += red[w + 2][lane * 12 + j];
      acc1[j] += red[w + 2][lane * 12 + 6 + j];
    }
    l0 += redl[w + 2][lane * 2];
    l1 += redl[w + 2][lane * 2 + 1];
    size_t b0 = ((size_t)(h * 2 + 0) * HOPB + blk) * 48 + p * 6;
    size_t b1 = ((size_t)(h * 2 + 1) * HOPB + blk) * 48 + p * 6;
#pragma unroll
    for (int j = 0; j < 6; ++j) { pa[b0 + j] = acc0[j]; pa[b1 + j] = acc1[j]; }
    if (p == 0) {
      pl[(size_t)(h * 2 + 0) * HOPB + blk] = l0;
      pl[(size_t)(h * 2 + 1) * HOPB + blk] = l1;
    }
  }
}

// split merge: 256 blocks (8 slices per (b,h)); 48 atomicAdds/block (8-way)
__global__ __launch_bounds__(256) void k_hred(const float* __restrict__ pa,
                                              const float* __restrict__ pl,
                                              float* __restrict__ QNn,
                                              float* __restrict__ LTn) {
  __shared__ float p3[256];
  __shared__ float sl[4];
  int blk = blockIdx.x;
  int g = blk >> 3, part = blk & 7;
  int b = g & 1, h = g >> 1;
  int t = threadIdx.x, lane = t & 63, w = t >> 6;
  size_t mlb = (size_t)(h * 2 + b) * HOPB;
  int i0 = part * 128;
  float ll = (t < 128) ? pl[mlb + i0 + t] : 0.f;
#pragma unroll
  for (int o = 32; o >= 1; o >>= 1) ll += __shfl_xor(ll, o);
  if (lane == 0) sl[w] = ll;
  int d = t & 63, seg = t >> 6;
  float a = 0.f;
  if (d < 48) {
#pragma unroll 8
    for (int i = i0 + seg; i < i0 + 128; i += 4)
      a += pa[(mlb + i) * 48 + d];
  }
  p3[seg * 64 + d] = a;
  __syncthreads();
  if (t < 48) {
    float av = p3[t] + p3[64 + t] + p3[128 + t] + p3[192 + t];
    atomicAdd(&QNn[(h * 2 + b) * 48 + t], av);
  }
  if (t == 0) atomicAdd(&LTn[h * 2 + b], sl[0] + sl[1] + sl[2] + sl[3]);
}

// final score pass: q from slot 5 on the fly; writes S + PL partials
__global__ __launch_bounds__(256) void k_escore(const unsigned short* __restrict__ KB,
                                                const float* __restrict__ Ap,
                                                const float* __restrict__ Lp,
                                                float* __restrict__ S,
                                                float* __restrict__ pl) {
  __shared__ float redl[4][128];
  int tid = threadIdx.x, blk = blockIdx.x;
  int w = tid >> 6, lane = tid & 63;
  int hb = w & 1, sub = w >> 1;
  int h = hb * 8 + (lane >> 3), p = lane & 7;
  float rl0 = SCALING_ / Lp[h * 2 + 0];
  float rl1 = SCALING_ / Lp[h * 2 + 1];
  float qv0[6], qv1[6];
#pragma unroll
  for (int j = 0; j < 6; ++j) {
    qv0[j] = rl0 * Ap[(h * 2 + 0) * 48 + p * 6 + j];
    qv1[j] = rl1 * Ap[(h * 2 + 1) * 48 + p * 6 + j];
  }
  float l0 = 0.f, l1 = 0.f;
  int n0 = blk * CBLK + sub * 49;
  int nend = n0 + 49;
  if (nend > NMEM) nend = NMEM;
#pragma unroll 4
  for (int n = n0; n < nend; ++n) {
    const unsigned short* ks = KB + (size_t)n * 768 + hb * 384 + lane * 6;
    float kf[6]; load6(ks, kf);
    float sc0 = 0.f, sc1 = 0.f;
#pragma unroll
    for (int j = 0; j < 6; ++j) {
      sc0 = fmaf(kf[j], qv0[j], sc0);
      sc1 = fmaf(kf[j], qv1[j], sc1);
    }
#pragma unroll
    for (int o = 1; o < 8; o <<= 1) {
      sc0 += __shfl_xor(sc0, o);
      sc1 += __shfl_xor(sc1, o);
    }
    if (p == 0) {
      S[(size_t)n * 32 + h]      = sc0;
      S[(size_t)n * 32 + 16 + h] = sc1;
    }
    l0 += __expf(sc0);
    l1 += __expf(sc1);
  }
  redl[w][lane * 2]     = l0;
  redl[w][lane * 2 + 1] = l1;
  __syncthreads();
  if (sub == 0) {
    l0 += redl[w + 2][lane * 2];
    l1 += redl[w + 2][lane * 2 + 1];
    if (p == 0) {
      pl[(size_t)(h * 2 + 0) * HOPB + blk] = l0;
      pl[(size_t)(h * 2 + 1) * HOPB + blk] = l1;
    }
  }
}

// merge -> C[bh] = log(sum l)
__global__ __launch_bounds__(256) void k_hredM(const float* __restrict__ pl,
                                               float* __restrict__ C) {
  int b = blockIdx.x & 1, h = blockIdx.x >> 1;
  __shared__ float sred[4];
  int t = threadIdx.x, lane = t & 63, w = t >> 6;
  size_t mlb = (size_t)(h * 2 + b) * HOPB;
  float ll = 0.f;
  for (int i = t; i < HOPB; i += 256) ll += pl[mlb + i];
#pragma unroll
  for (int o = 32; o >= 1; o >>= 1) ll += __shfl_xor(ll, o);
  if (lane == 0) sred[w] = ll;
  __syncthreads();
  if (t == 0) C[b * 16 + h] = logf(sred[0] + sred[1] + sred[2] + sred[3]);
}

// ------------------------- u-pass (fused wexp) ------------------------------
__global__ __launch_bounds__(256) void k_upass(const unsigned short* __restrict__ XH,
                                               const float* __restrict__ S,
                                               const float* __restrict__ C,
                                               float* __restrict__ UP) {
  __shared__ float SW[64 * 32];
  __shared__ float cc[32];
  int kb = blockIdx.x, t = threadIdx.x;
  if (t < 32) cc[t] = C[t];
  float a0[32], a1[32], a2[32];
#pragma unroll
  for (int i = 0; i < 32; ++i) { a0[i] = 0.f; a1[i] = 0.f; a2[i] = 0.f; }
  int n0 = kb * UROWS;
  int nend = n0 + UROWS; if (nend > NMEM) nend = NMEM;
  for (int ns = n0; ns < nend; ns += 64) {
    int sub = nend - ns; if (sub > 64) sub = 64;
    __syncthreads();
    for (int i = t; i < sub * 32; i += 256)
      SW[i] = __expf(S[(size_t)ns * 32 + i] - cc[i & 31]);
    __syncthreads();
    for (int r = 0; r < sub; ++r) {
      const unsigned short* xr = XH + (size_t)(ns + r) * 768;
      float x0 = bf2f(xr[t]), x1 = bf2f(xr[t + 256]), x2 = bf2f(xr[t + 512]);
      const float4* w4 = (const float4*)(SW + r * 32);
#pragma unroll
      for (int c = 0; c < 8; ++c) {
        float4 wv = w4[c];
        a0[c * 4 + 0] = fmaf(wv.x, x0, a0[c * 4 + 0]);
        a0[c * 4 + 1] = fmaf(wv.y, x0, a0[c * 4 + 1]);
        a0[c * 4 + 2] = fmaf(wv.z, x0, a0[c * 4 + 2]);
        a0[c * 4 + 3] = fmaf(wv.w, x0, a0[c * 4 + 3]);
        a1[c * 4 + 0] = fmaf(wv.x, x1, a1[c * 4 + 0]);
        a1[c * 4 + 1] = fmaf(wv.y, x1, a1[c * 4 + 1]);
        a1[c * 4 + 2] = fmaf(wv.z, x1, a1[c * 4 + 2]);
        a1[c * 4 + 3] = fmaf(wv.w, x1, a1[c * 4 + 3]);
        a2[c * 4 + 0] = fmaf(wv.x, x2, a2[c * 4 + 0]);
        a2[c * 4 + 1] = fmaf(wv.y, x2, a2[c * 4 + 1]);
        a2[c * 4 + 2] = fmaf(wv.z, x2, a2[c * 4 + 2]);
        a2[c * 4 + 3] = fmaf(wv.w, x2, a2[c * 4 + 3]);
      }
    }
  }
#pragma unroll
  for (int bh = 0; bh < 32; ++bh) {
    size_t base = ((size_t)kb * 32 + bh) * 768;
    UP[base + t]       = a0[bh];
    UP[base + 256 + t] = a1[bh];
    UP[base + 512 + t] = a2[bh];
  }
}

__global__ __launch_bounds__(256) void k_ured(const float* __restrict__ UP,
                                              float* __restrict__ U) {
  int o = blockIdx.x * 256 + threadIdx.x;
  float s0 = 0.f, s1 = 0.f, s2 = 0.f, s3 = 0.f;
#pragma unroll 4
  for (int kb = 0; kb < UKS; kb += 4) {
    s0 += UP[(size_t)(kb + 0) * 24576 + o];
    s1 += UP[(size_t)(kb + 1) * 24576 + o];
    s2 += UP[(size_t)(kb + 2) * 24576 + o];
    s3 += UP[(size_t)(kb + 3) * 24576 + o];
  }
  U[o] = (s0 + s1) + (s2 + s3);
}

__global__ __launch_bounds__(256) void k_outproj(const float* __restrict__ U,
                                                 const unsigned short* __restrict__ WT,
                                                 const float* __restrict__ BKV,
                                                 float* __restrict__ outa) {
  int gw = blockIdx.x * 4 + (threadIdx.x >> 6);
  int lane = threadIdx.x & 63;
  int b = gw >= 768;
  int j = gw - b * 768;
  int h = j / 48;
  const float* u = U + (size_t)(b * 16 + h) * 768;
  const unsigned short* wr = WT + (size_t)(768 + j) * 768;
  float a = 0.f;
  for (int d = lane; d < 768; d += 64) a = fmaf(u[d], bf2f(wr[d]), a);
#pragma unroll
  for (int o = 32; o >= 1; o >>= 1) a += __shfl_xor(a, o);
  if (lane == 0) outa[b * 768 + j] = a + BKV[768 + j];
}

// ------------------------- pooled / norm ------------------------------------
__global__ __launch_bounds__(256) void k_pooled(const float* __restrict__ outa,
                                                const float* __restrict__ Wo,
                                                const float* __restrict__ bo,
                                                float* __restrict__ dp) {
  __shared__ float xs[768];
  __shared__ float pr[256];
  int b = blockIdx.y, jc = blockIdx.x, t = threadIdx.x;
  xs[t]       = outa[b * 768 + t];
  xs[t + 256] = outa[b * 768 + 256 + t];
  xs[t + 512] = outa[b * 768 + 512 + t];
  __syncthreads();
  int w = t >> 6, lane = t & 63;
  int j = jc * 64 + lane;
  float a = 0.f;
  int d0 = w * 192;
  for (int d = d0; d < d0 + 192; ++d) a = fmaf(xs[d], Wo[(size_t)d * 768 + j], a);
  pr[t] = a;
  __syncthreads();
  if (t < 64) {
    float sv = pr[t] + pr[64 + t] + pr[128 + t] + pr[192 + t];
    int j2 = jc * 64 + t;
    dp[b * 768 + j2] = sv + bo[j2];
  }
}

__global__ __launch_bounds__(256) void k_pnorm(const float* __restrict__ dp,
                                               float* __restrict__ PN) {
  int b = blockIdx.x, t = threadIdx.x;
  __shared__ float sred[8];
  float x0 = dp[b * 768 + t], x1 = dp[b * 768 + 256 + t], x2 = dp[b * 768 + 512 + t];
  float s2 = x0 * x0 + x1 * x1 + x2 * x2;
#pragma unroll
  for (int o = 32; o >= 1; o >>= 1) s2 += __shfl_xor(s2, o);
  int lane = t & 63, w = t >> 6;
  if (lane == 0) sred[w] = s2;
  __syncthreads();
  float tot = sred[0] + sred[1] + sred[2] + sred[3];
  float rs = rsqrtf(tot);
  PN[b * 768 + t]       = x0 * rs;
  PN[b * 768 + 256 + t] = x1 * rs;
  PN[b * 768 + 512 + t] = x2 * rs;
}

// ------------------------- similarity + top-4 -------------------------------
__global__ __launch_bounds__(256) void k_sim(const float* __restrict__ mem,
                                             const float* __restrict__ PN,
                                             const float* __restrict__ rnorm,
                                             float* __restrict__ tval,
                                             int* __restrict__ tidx) {
  int gw = (blockIdx.x * 256 + threadIdx.x) >> 6;   // 8192 waves
  int lane = threadIdx.x & 63;
  const float4* pa = (const float4*)(PN);
  const float4* pb = (const float4*)(PN + 768);
  float4 qa0 = pa[lane], qa1 = pa[lane + 64], qa2 = pa[lane + 128];
  float4 qb0 = pb[lane], qb1 = pb[lane + 64], qb2 = pb[lane + 128];
  Top4 t0, t1; t0.init(); t1.init();
  int n0 = gw * 13;
  int nend = n0 + 13; if (nend > NMEM) nend = NMEM;
  for (int n = n0; n < nend; ++n) {
    const float4* r = (const float4*)(mem + (size_t)n * 768);
    float4 x0 = r[lane], x1 = r[lane + 64], x2 = r[lane + 128];
    float d0 = x0.x * qa0.x + x0.y * qa0.y + x0.z * qa0.z + x0.w * qa0.w +
               x1.x * qa1.x + x1.y * qa1.y + x1.z * qa1.z + x1.w * qa1.w +
               x2.x * qa2.x + x2.y * qa2.y + x2.z * qa2.z + x2.w * qa2.w;
    float d1 = x0.x * qb0.x + x0.y * qb0.y + x0.z * qb0.z + x0.w * qb0.w +
               x1.x * qb1.x + x1.y * qb1.y + x1.z * qb1.z + x1.w * qb1.w +
               x2.x * qb2.x + x2.y * qb2.y + x2.z * qb2.z + x2.w * qb2.w;
#pragma unroll
    for (int o = 32; o >= 1; o >>= 1) { d0 += __shfl_xor(d0, o); d1 += __shfl_xor(d1, o); }
    float rn = rnorm[n];
    t0.ins(d0 * rn, n);
    t1.ins(d1 * rn, n);
  }
  if (lane == 0) {
    int base = gw * 8;
    tval[base + 0] = t0.v0; tval[base + 1] = t0.v1; tval[base + 2] = t0.v2; tval[base + 3] = t0.v3;
    tval[base + 4] = t1.v0; tval[base + 5] = t1.v1; tval[base + 6] = t1.v2; tval[base + 7] = t1.v3;
    tidx[base + 0] = t0.i0; tidx[base + 1] = t0.i1; tidx[base + 2] = t0.i2; tidx[base + 3] = t0.i3;
    tidx[base + 4] = t1.i0; tidx[base + 5] = t1.i1; tidx[base + 6] = t1.i2; tidx[base + 7] = t1.i3;
  }
}

__global__ __launch_bounds__(256) void k_top1(const float* __restrict__ tval,
                                              const int* __restrict__ tidx,
                                              float* __restrict__ ptv,
                                              int* __restrict__ pti) {
  __shared__ float lv[4][8];
  __shared__ int   li[4][8];
  int z = blockIdx.x, t = threadIdx.x;
  int lane = t & 63, w = t >> 6;
  int wv = z * 256 + t;
  Top4 a, b; a.init(); b.init();
#pragma unroll
  for (int r = 0; r < 4; ++r) {
    a.ins(tval[wv * 8 + r],     tidx[wv * 8 + r]);
    b.ins(tval[wv * 8 + 4 + r], tidx[wv * 8 + 4 + r]);
  }
  bfly(a, 32);
  bfly(b, 32);
  if (lane == 0) {
    lv[w][0] = a.v0; lv[w][1] = a.v1; lv[w][2] = a.v2; lv[w][3] = a.v3;
    lv[w][4] = b.v0; lv[w][5] = b.v1; lv[w][6] = b.v2; lv[w][7] = b.v3;
    li[w][0] = a.i0; li[w][1] = a.i1; li[w][2] = a.i2; li[w][3] = a.i3;
    li[w][4] = b.i0; li[w][5] = b.i1; li[w][6] = b.i2; li[w][7] = b.i3;
  }
  __syncthreads();
  if (t < 2) {
    Top4 m_; m_.init();
#pragma unroll
    for (int w2 = 0; w2 < 4; ++w2)
#pragma unroll
      for (int r = 0; r < 4; ++r) m_.ins(lv[w2][t * 4 + r], li[w2][t * 4 + r]);
    int base = z * 8 + t * 4;
    ptv[base + 0] = m_.v0; ptv[base + 1] = m_.v1;
    ptv[base + 2] = m_.v2; ptv[base + 3] = m_.v3;
    pti[base + 0] = m_.i0; pti[base + 1] = m_.i1;
    pti[base + 2] = m_.i2; pti[base + 3] = m_.i3;
  }
}

__global__ __launch_bounds__(64) void k_top2(const float* __restrict__ ptv,
                                             const int* __restrict__ pti,
                                             float* __restrict__ dout) {
  int t = threadIdx.x;
  int half = t >> 5, e = t & 31;
  Top4 a; a.init();
#pragma unroll
  for (int r = 0; r < 4; ++r)
    a.ins(ptv[e * 8 + half * 4 + r], pti[e * 8 + half * 4 + r]);
  bfly(a, 16);
  if (e == 0) {
    dout[half * 4 + 0] = (float)a.i0;
    dout[half * 4 + 1] = (float)a.i1;
    dout[half * 4 + 2] = (float)a.i2;
    dout[half * 4 + 3] = (float)a.i3;
  }
}

// ---------------------------------------------------------------------------
extern "C" void kernel_launch(void* const* d_in, const int* in_sizes, int n_in,
                              void* d_out, int out_size, void* d_ws, size_t ws_size,
                              hipStream_t stream) {
  const float* qe     = (const float*)d_in[0];
  const float* mem    = (const float*)d_in[1];
  const float* ln_q_g = (const float*)d_in[2];
  const float* ln_q_b = (const float*)d_in[3];
  const float* ln_s_g = (const float*)d_in[4];
  const float* ln_s_b = (const float*)d_in[5];
  const float* ln_p_g = (const float*)d_in[6];
  const float* ln_p_b = (const float*)d_in[7];
  const float* Wq = (const float*)d_in[8];  const float* bq = (const float*)d_in[9];
  const float* Wk = (const float*)d_in[10]; const float* bk = (const float*)d_in[11];
  const float* Wv = (const float*)d_in[12]; const float* bv = (const float*)d_in[13];
  const float* Wo = (const float*)d_in[14]; const float* bo = (const float*)d_in[15];

  char* w = (char*)d_ws;
  size_t off = 0;
  auto alloc = [&](size_t bytes) {
    size_t o = off;
    off += (bytes + 255) & ~(size_t)255;
    return o;
  };
  unsigned short* WT   = (unsigned short*)(w + alloc((size_t)1536 * 768 * 2));
  float*          PB   = (float*)(w + alloc(8 * 1536 * 4));
  float*          BKV  = (float*)(w + alloc(1536 * 4));
  float*          QN   = (float*)(w + alloc(7 * 1536 * 4));
  float*          LT   = (float*)(w + alloc(7 * 32 * 4));
  float*          OUTA = (float*)(w + alloc(1536 * 4));
  float*          PN   = (float*)(w + alloc(1536 * 4));
  float*          CML  = (float*)(w + alloc(32 * 4));
  float*          UBUF = (float*)(w + alloc((size_t)24576 * 4));
  float*          RNORM= (float*)(w + alloc((size_t)NPAD * 4));
  unsigned short* XH   = (unsigned short*)(w + alloc((size_t)NPAD * 768 * 2));
  unsigned short* KB   = (unsigned short*)(w + alloc((size_t)NPAD * 768 * 2));
  float*          PA   = (float*)(w + alloc((size_t)32 * HOPB * 48 * 4));
  float*          PL   = (float*)(w + alloc((size_t)32 * HOPB * 4));
  float*          SB   = (float*)(w + alloc((size_t)NMEM * 32 * 4));
  float*          UP   = (float*)(w + alloc((size_t)UKS * 24576 * 4));
  float*          TVAL = (float*)(w + alloc((size_t)8192 * 8 * 4));
  int*            TIDX = (int*)(w + alloc((size_t)8192 * 8 * 4));
  float*          PTV  = (float*)(w + alloc((size_t)32 * 8 * 4));
  int*            PTI  = (int*)(w + alloc((size_t)32 * 8 * 4));
  if (off > ws_size) {
    fprintf(stderr, "[hopfield] ws too small: need %zu have %zu\n", off, ws_size);
    return;
  }
  float* dout = (float*)d_out;

  k_fold_wt  <<<dim3(12, 12, 2), 256, 0, stream>>>(Wk, Wv, ln_s_g, ln_p_g, WT);
  k_fold_bias<<<dim3(6, 8), 256, 0, stream>>>(Wk, Wv, ln_s_b, ln_p_b, PB);
  k_bias_red <<<6, 256, 0, stream>>>(PB, bk, bv, BKV);
  k_q0       <<<dim3(12, 2), 256, 0, stream>>>(qe, ln_q_g, ln_q_b, Wq, bq, QN, LT);
  k_ln       <<<1024, 256, 0, stream>>>(mem, XH, RNORM);
  k_gemm     <<<98 * 6 * 8, 256, 0, stream>>>(XH, WT, BKV, KB);
  for (int s = 0; s < 5; ++s) {
    k_hop    <<<HOPB, 256, 0, stream>>>(KB, QN, LT, QN, LT, PA, PL, s);
    k_hred   <<<256, 256, 0, stream>>>(PA, PL, QN + (s + 1) * 1536,
                                       LT + (s + 1) * 32);
  }
  k_escore   <<<HOPB, 256, 0, stream>>>(KB, QN + 5 * 1536, LT + 5 * 32, SB, PL);
  k_hredM    <<<32, 256, 0, stream>>>(PL, CML);
  k_upass    <<<UKS, 256, 0, stream>>>(XH, SB, CML, UP);
  k_ured     <<<96, 256, 0, stream>>>(UP, UBUF);
  k_outproj  <<<384, 256, 0, stream>>>(UBUF, WT, BKV, OUTA);
  k_pooled   <<<dim3(12, 2), 256, 0, stream>>>(OUTA, Wo, bo, dout + 8);
  k_pnorm    <<<2, 256, 0, stream>>>(dout + 8, PN);
  k_sim      <<<2048, 256, 0, stream>>>(mem, PN, RNORM, TVAL, TIDX);
  k_top1     <<<32, 256, 0, stream>>>(TVAL, TIDX, PTV, PTI);
  k_top2     <<<1, 64, 0, stream>>>(PTV, PTI, dout);
}

// Round 15
// 766.212 us; speedup vs baseline: 1.9685x; 1.0129x over previous
//
#include <hip/hip_runtime.h>
#include <cstdio>
#include <cstdint>

// ---------------------------------------------------------------------------
// HopfieldPoolingRouter on MI355X — V-free, fixed-base softmax, block-partial
// hops + 256-block split merges (8-way atomics), q recomputed on the fly.
// GEMM: 512-thread blocks (8 waves, 32x64 wave tiles) for 16 waves/CU latency
// hiding at unchanged 64KB LDS; BK=64, XOR swizzle, counted vmcnt(4).
// ---------------------------------------------------------------------------

#define NMEM 100000
#define NPAD 100096          // 782 * 128
#define HOPB 1024            // hop-pass blocks; partials per (b,h)
#define CBLK 98              // rows per hop block (1024*98 >= 100000)
#define UKS  512
#define UROWS 196
#define SCALING_ 0.25f

typedef __attribute__((ext_vector_type(8))) short bf16x8;
typedef __attribute__((ext_vector_type(4))) float f32x4;

__device__ __forceinline__ unsigned short f2bf(float f) {
  union { float f; unsigned u; } c; c.f = f;
  unsigned u = c.u + 0x7fffu + ((c.u >> 16) & 1u);   // RNE
  return (unsigned short)(u >> 16);
}
__device__ __forceinline__ float bf2f(unsigned short h) {
  union { unsigned u; float f; } c; c.u = ((unsigned)h) << 16;
  return c.f;
}
__device__ __forceinline__ void gl_lds16(const void* g, void* l) {
  __builtin_amdgcn_global_load_lds(
      (const __attribute__((address_space(1))) unsigned int*)g,
      (__attribute__((address_space(3))) unsigned int*)l, 16, 0, 0);
}

__device__ __forceinline__ bool bet(float s, int n, float v, int i) {
  return (s > v) || (s == v && n < i);
}
struct Top4 {
  float v0, v1, v2, v3;
  int   i0, i1, i2, i3;
  __device__ __forceinline__ void init() {
    v0 = v1 = v2 = v3 = -INFINITY;
    i0 = i1 = i2 = i3 = 0x7fffffff;
  }
  __device__ __forceinline__ void ins(float s, int n) {
    bool c0 = bet(s, n, v0, i0), c1 = bet(s, n, v1, i1);
    bool c2 = bet(s, n, v2, i2), c3 = bet(s, n, v3, i3);
    float w0 = c0 ? s : v0;             int j0 = c0 ? n : i0;
    float w1 = c0 ? v0 : (c1 ? s : v1); int j1 = c0 ? i0 : (c1 ? n : i1);
    float w2 = c1 ? v1 : (c2 ? s : v2); int j2 = c1 ? i1 : (c2 ? n : i2);
    float w3 = c2 ? v2 : (c3 ? s : v3); int j3 = c2 ? i2 : (c3 ? n : i3);
    v0 = w0; v1 = w1; v2 = w2; v3 = w3;
    i0 = j0; i1 = j1; i2 = j2; i3 = j3;
  }
};
__device__ __forceinline__ void bfly(Top4& a, int omax) {
  for (int o = omax; o >= 1; o >>= 1) {
    float w0 = __shfl_xor(a.v0, o), w1 = __shfl_xor(a.v1, o);
    float w2 = __shfl_xor(a.v2, o), w3 = __shfl_xor(a.v3, o);
    int   j0 = __shfl_xor(a.i0, o), j1 = __shfl_xor(a.i1, o);
    int   j2 = __shfl_xor(a.i2, o), j3 = __shfl_xor(a.i3, o);
    a.ins(w0, j0); a.ins(w1, j1); a.ins(w2, j2); a.ins(w3, j3);
  }
}

// ------------------------- weight folding ----------------------------------
__global__ __launch_bounds__(256) void k_fold_wt(const float* __restrict__ Wk,
                                                 const float* __restrict__ Wv,
                                                 const float* __restrict__ gs,
                                                 const float* __restrict__ gp,
                                                 unsigned short* __restrict__ WT) {
  __shared__ float ts[64][65];
  int d0 = blockIdx.x * 64, j0 = blockIdx.y * 64, z = blockIdx.z;
  const float* W = z ? Wv : Wk;
  const float* g = z ? gp : gs;
  int t = threadIdx.x, c = t & 63, r4 = t >> 6;
#pragma unroll
  for (int p = 0; p < 16; ++p) {
    int r = p * 4 + r4;
    ts[r][c] = g[d0 + r] * W[(size_t)(d0 + r) * 768 + j0 + c];
  }
  __syncthreads();
#pragma unroll
  for (int p = 0; p < 16; ++p) {
    int jr = p * 4 + r4;
    WT[(size_t)(z * 768 + j0 + jr) * 768 + d0 + c] = f2bf(ts[c][jr]);
  }
}

__global__ __launch_bounds__(256) void k_fold_bias(const float* __restrict__ Wk,
                                                   const float* __restrict__ Wv,
                                                   const float* __restrict__ bs,
                                                   const float* __restrict__ bp,
                                                   float* __restrict__ PB) {
  int jc = blockIdx.x, dz = blockIdx.y, t = threadIdx.x;
  int j = jc * 256 + t;
  const float* W  = (j < 768) ? Wk : Wv;
  const float* bb = (j < 768) ? bs : bp;
  int jj = (j < 768) ? j : j - 768;
  float a = 0.f;
  int dend = dz * 96 + 96;
  for (int d = dz * 96; d < dend; ++d) a = fmaf(bb[d], W[(size_t)d * 768 + jj], a);
  PB[dz * 1536 + j] = a;
}

__global__ __launch_bounds__(256) void k_bias_red(const float* __restrict__ PB,
                                                  const float* __restrict__ bk,
                                                  const float* __restrict__ bv,
                                                  float* __restrict__ BKV) {
  int j = blockIdx.x * 256 + threadIdx.x;
  float a = (j < 768) ? bk[j] : bv[j - 768];
#pragma unroll
  for (int dz = 0; dz < 8; ++dz) a += PB[dz * 1536 + j];
  BKV[j] = a;
}

// ------------------------- q0 -> QN slot 0 (LT=1), zero slot 1 --------------
__global__ __launch_bounds__(256) void k_q0(const float* __restrict__ qe,
                                            const float* __restrict__ gq,
                                            const float* __restrict__ bq_ln,
                                            const float* __restrict__ Wq,
                                            const float* __restrict__ bq,
                                            float* __restrict__ QN,
                                            float* __restrict__ LT) {
  int b = blockIdx.y, jc = blockIdx.x, t = threadIdx.x;
  __shared__ float xs[768];
  __shared__ float sred[16];
  __shared__ float pr[256];
  if (jc == 0 && b == 0) {
    for (int i = t; i < 1536; i += 256) QN[1536 + i] = 0.f;
    if (t < 32) { LT[t] = 1.0f; LT[32 + t] = 0.f; }
  }
  float x0 = qe[b * 768 + t], x1 = qe[b * 768 + 256 + t], x2 = qe[b * 768 + 512 + t];
  float s = x0 + x1 + x2, s2 = x0 * x0 + x1 * x1 + x2 * x2;
#pragma unroll
  for (int o = 32; o >= 1; o >>= 1) { s += __shfl_xor(s, o); s2 += __shfl_xor(s2, o); }
  int lane = t & 63, w = t >> 6;
  if (lane == 0) { sred[w] = s; sred[8 + w] = s2; }
  __syncthreads();
  s  = sred[0] + sred[1] + sred[2] + sred[3];
  s2 = sred[8] + sred[9] + sred[10] + sred[11];
  float mean = s * (1.f / 768.f);
  float var  = s2 * (1.f / 768.f) - mean * mean;
  float rstd = rsqrtf(var + 1e-5f);
  xs[t]       = (x0 - mean) * rstd * gq[t]       + bq_ln[t];
  xs[t + 256] = (x1 - mean) * rstd * gq[t + 256] + bq_ln[t + 256];
  xs[t + 512] = (x2 - mean) * rstd * gq[t + 512] + bq_ln[t + 512];
  __syncthreads();
  int j = jc * 64 + lane;
  float a = 0.f;
  int d0 = w * 192;
  for (int d = d0; d < d0 + 192; ++d) a = fmaf(xs[d], Wq[(size_t)d * 768 + j], a);
  pr[t] = a;
  __syncthreads();
  if (t < 64) {
    float sv = pr[t] + pr[64 + t] + pr[128 + t] + pr[192 + t];
    int j2 = jc * 64 + t;
    int h = j2 / 48, dh = j2 - h * 48;
    QN[(h * 2 + b) * 48 + dh] = sv + bq[j2];   // slot 0, unscaled; LT0 = 1
  }
}

// ------------------------- memory LN + rnorm --------------------------------
__global__ __launch_bounds__(256) void k_ln(const float* __restrict__ mem,
                                            unsigned short* __restrict__ XH,
                                            float* __restrict__ rnorm) {
  int gw = (blockIdx.x * 256 + threadIdx.x) >> 6;   // 4096 waves
  int lane = threadIdx.x & 63;
  int n0 = gw * 25;
  int nend = n0 + 25; if (nend > NPAD) nend = NPAD;
  for (int n = n0; n < nend; ++n) {
    ushort4* orow = (ushort4*)(XH + (size_t)n * 768);
    if (n >= NMEM) {
      ushort4 z; z.x = z.y = z.z = z.w = 0;
      orow[lane] = z; orow[lane + 64] = z; orow[lane + 128] = z;
      continue;
    }
    const float4* r = (const float4*)(mem + (size_t)n * 768);
    float4 x0 = r[lane], x1 = r[lane + 64], x2 = r[lane + 128];
    float s  = x0.x + x0.y + x0.z + x0.w + x1.x + x1.y + x1.z + x1.w +
               x2.x + x2.y + x2.z + x2.w;
    float s2 = x0.x * x0.x + x0.y * x0.y + x0.z * x0.z + x0.w * x0.w +
               x1.x * x1.x + x1.y * x1.y + x1.z * x1.z + x1.w * x1.w +
               x2.x * x2.x + x2.y * x2.y + x2.z * x2.z + x2.w * x2.w;
#pragma unroll
    for (int o = 32; o >= 1; o >>= 1) { s += __shfl_xor(s, o); s2 += __shfl_xor(s2, o); }
    float mean = s * (1.f / 768.f);
    float var  = s2 * (1.f / 768.f) - mean * mean;
    float rstd = rsqrtf(var + 1e-5f);
    if (lane == 0) rnorm[n] = rsqrtf(s2);
    ushort4 o0, o1, o2;
    o0.x = f2bf((x0.x - mean) * rstd); o0.y = f2bf((x0.y - mean) * rstd);
    o0.z = f2bf((x0.z - mean) * rstd); o0.w = f2bf((x0.w - mean) * rstd);
    o1.x = f2bf((x1.x - mean) * rstd); o1.y = f2bf((x1.y - mean) * rstd);
    o1.z = f2bf((x1.z - mean) * rstd); o1.w = f2bf((x1.w - mean) * rstd);
    o2.x = f2bf((x2.x - mean) * rstd); o2.y = f2bf((x2.y - mean) * rstd);
    o2.z = f2bf((x2.z - mean) * rstd); o2.w = f2bf((x2.w - mean) * rstd);
    orow[lane] = o0; orow[lane + 64] = o1; orow[lane + 128] = o2;
  }
}

// ------------------------- projection GEMM (8 waves, 32x64 wave tiles) ------
// 512 threads = 8 waves; wave (wm,wn) owns 32x64 sub-tile -> 16 waves/CU at
// 64KB LDS. BK=64, XOR swizzle, counted vmcnt(4) (4 gl_lds per thread/tile).
__global__ __launch_bounds__(512) void k_gemm(const unsigned short* __restrict__ XH,
                                              const unsigned short* __restrict__ WT,
                                              const float* __restrict__ BKV,
                                              unsigned short* __restrict__ KB) {
  __shared__ __align__(16) unsigned short SM[32768];   // 2 x (A 16KB | B 16KB)
  int f = blockIdx.x;
  int xcd = f & 7, s = f >> 3;
  int g = s / 6, jt = s - g * 6;
  int mt = g * 8 + xcd;
  if (mt >= 782) return;
  int m0 = mt * 128, j0 = jt * 128;
  int tid = threadIdx.x;
  int wave = tid >> 6, lane = tid & 63;
  int wm = wave >> 1, wn = wave & 1;       // wm 0..3 (32-row strips), wn 0..1
  int fr_r = lane & 15, chb = lane >> 4;
  f32x4 acc[2][4] = {};

  auto stage = [&](int kt, int bb) {       // 4 gl_lds per thread
    unsigned short* As = SM + bb * 16384;
    unsigned short* Bs = As + 8192;
    int k0 = kt * 64;
#pragma unroll
    for (int it = 0; it < 2; ++it) {
      int c = it * 512 + tid;              // 1024 chunks of 16B per matrix
      int row = c >> 3, kk = c & 7;
      int src = (kk ^ (row & 7)) * 8;
      gl_lds16(XH + (size_t)(m0 + row) * 768 + k0 + src, As + c * 8);
      gl_lds16(WT + (size_t)(j0 + row) * 768 + k0 + src, Bs + c * 8);
    }
  };

  stage(0, 0);
  int cur = 0;
  for (int kt = 0; kt < 12; ++kt) {
    if (kt < 11) {
      stage(kt + 1, cur ^ 1);
      asm volatile("s_waitcnt vmcnt(4)" ::: "memory");  // buf[kt] loads done
    } else {
      asm volatile("s_waitcnt vmcnt(0)" ::: "memory");
    }
    __builtin_amdgcn_s_barrier();
    __builtin_amdgcn_sched_barrier(0);
    const unsigned short* As = SM + cur * 16384;
    const unsigned short* Bs = As + 8192;
    __builtin_amdgcn_s_setprio(1);
#pragma unroll
    for (int ks = 0; ks < 2; ++ks) {
      bf16x8 af[2], bfr[4];
#pragma unroll
      for (int ff = 0; ff < 2; ++ff) {
        int ra = wm * 32 + ff * 16 + fr_r;
        int cha = ((ks * 4 + chb) ^ (ra & 7)) * 8;
        af[ff] = *(const bf16x8*)(As + ra * 64 + cha);
      }
#pragma unroll
      for (int ff = 0; ff < 4; ++ff) {
        int rb = wn * 64 + ff * 16 + fr_r;
        int chbb = ((ks * 4 + chb) ^ (rb & 7)) * 8;
        bfr[ff] = *(const bf16x8*)(Bs + rb * 64 + chbb);
      }
#pragma unroll
      for (int fm = 0; fm < 2; ++fm)
#pragma unroll
        for (int fn = 0; fn < 4; ++fn)
          acc[fm][fn] = __builtin_amdgcn_mfma_f32_16x16x32_bf16(af[fm], bfr[fn],
                                                                acc[fm][fn], 0, 0, 0);
    }
    __builtin_amdgcn_s_setprio(0);
    __builtin_amdgcn_s_barrier();      // all waves done reading buf[cur]
    __builtin_amdgcn_sched_barrier(0);
    cur ^= 1;
  }
  // epilogue: acc -> LDS (bf16 128x128 = 32KB), then coalesced 16B stores
  int cr = (lane >> 4) * 4, cc = lane & 15;
#pragma unroll
  for (int fm = 0; fm < 2; ++fm)
#pragma unroll
    for (int fn = 0; fn < 4; ++fn) {
      int col = wn * 64 + fn * 16 + cc;
      float bias = BKV[j0 + col];
      int rb = (wm * 32 + fm * 16 + cr) * 128 + col;
#pragma unroll
      for (int i = 0; i < 4; ++i)
        SM[rb + i * 128] = f2bf(acc[fm][fn][i] + bias);
    }
  __syncthreads();
#pragma unroll
  for (int it = 0; it < 4; ++it) {
    int c = it * 512 + tid;              // 2048 chunks of 16B
    int row = c >> 4, cg = c & 15;
    *(bf16x8*)(KB + (size_t)(m0 + row) * 768 + j0 + cg * 8) =
        *(const bf16x8*)(SM + row * 128 + cg * 8);
  }
}

// ------------------------- hop helpers --------------------------------------
__device__ __forceinline__ void load6(const unsigned short* p, float* o) {
  ushort2 a = *(const ushort2*)(p);
  ushort2 b = *(const ushort2*)(p + 2);
  ushort2 c = *(const ushort2*)(p + 4);
  o[0] = bf2f(a.x); o[1] = bf2f(a.y);
  o[2] = bf2f(b.x); o[3] = bf2f(b.y);
  o[4] = bf2f(c.x); o[5] = bf2f(c.y);
}

// hop pass s: q = 0.25*QN[s]/LT[s]; PA/PL block partials; blk0 zeroes slot s+2
__global__ __launch_bounds__(256) void k_hop(const unsigned short* __restrict__ KB,
                                             const float* __restrict__ QN,
                                             const float* __restrict__ LT,
                                             float* __restrict__ QNz,
                                             float* __restrict__ LTz,
                                             float* __restrict__ pa,
                                             float* __restrict__ pl,
                                             int s) {
  __shared__ float red[4][768];
  __shared__ float redl[4][128];
  int tid = threadIdx.x, blk = blockIdx.x;
  int w = tid >> 6, lane = tid & 63;
  int hb = w & 1, sub = w >> 1;
  if (blk == 0) {                      // zero slot s+2 for hred_{s+1}
    for (int i = tid; i < 1536; i += 256) QNz[(s + 2) * 1536 + i] = 0.f;
    if (tid < 32) LTz[(s + 2) * 32 + tid] = 0.f;
  }
  int h = hb * 8 + (lane >> 3), p = lane & 7;
  const float* Ap = QN + s * 1536;
  const float* Lp = LT + s * 32;
  float rl0 = SCALING_ / Lp[h * 2 + 0];
  float rl1 = SCALING_ / Lp[h * 2 + 1];
  float qv0[6], qv1[6];
#pragma unroll
  for (int j = 0; j < 6; ++j) {
    qv0[j] = rl0 * Ap[(h * 2 + 0) * 48 + p * 6 + j];
    qv1[j] = rl1 * Ap[(h * 2 + 1) * 48 + p * 6 + j];
  }
  float l0 = 0.f, l1 = 0.f;
  float acc0[6] = {}, acc1[6] = {};
  int n0 = blk * CBLK + sub * 49;
  int nend = n0 + 49;
  if (nend > NMEM) nend = NMEM;
#pragma unroll 4
  for (int n = n0; n < nend; ++n) {
    const unsigned short* ks = KB + (size_t)n * 768 + hb * 384 + lane * 6;
    float kf[6]; load6(ks, kf);
    float sc0 = 0.f, sc1 = 0.f;
#pragma unroll
    for (int j = 0; j < 6; ++j) {
      sc0 = fmaf(kf[j], qv0[j], sc0);
      sc1 = fmaf(kf[j], qv1[j], sc1);
    }
#pragma unroll
    for (int o = 1; o < 8; o <<= 1) {
      sc0 += __shfl_xor(sc0, o);
      sc1 += __shfl_xor(sc1, o);
    }
    float e0 = __expf(sc0);
    float e1 = __expf(sc1);
    l0 += e0; l1 += e1;
#pragma unroll
    for (int j = 0; j < 6; ++j) {
      acc0[j] = fmaf(e0, kf[j], acc0[j]);
      acc1[j] = fmaf(e1, kf[j], acc1[j]);
    }
  }
#pragma unroll
  for (int j = 0; j < 6; ++j) {
    red[w][lane * 12 + j]     = acc0[j];
    red[w][lane * 12 + 6 + j] = acc1[j];
  }
  redl[w][lane * 2]     = l0;
  redl[w][lane * 2 + 1] = l1;
  __syncthreads();
  if (sub == 0) {
#pragma unroll
    for (int j = 0; j < 6; ++j) {
      acc0[j] += red[w + 2][lane * 12 + j];
      acc1[j] += red[w + 2][lane * 12 + 6 + j];
    }
    l0 += redl[w + 2][lane * 2];
    l1 += redl[w + 2][lane * 2 + 1];
    size_t b0 = ((size_t)(h * 2 + 0) * HOPB + blk) * 48 + p * 6;
    size_t b1 = ((size_t)(h * 2 + 1) * HOPB + blk) * 48 + p * 6;
#pragma unroll
    for (int j = 0; j < 6; ++j) { pa[b0 + j] = acc0[j]; pa[b1 + j] = acc1[j]; }
    if (p == 0) {
      pl[(size_t)(h * 2 + 0) * HOPB + blk] = l0;
      pl[(size_t)(h * 2 + 1) * HOPB + blk] = l1;
    }
  }
}

// split merge: 256 blocks (8 slices per (b,h)); 48 atomicAdds/block (8-way)
__global__ __launch_bounds__(256) void k_hred(const float* __restrict__ pa,
                                              const float* __restrict__ pl,
                                              float* __restrict__ QNn,
                                              float* __restrict__ LTn) {
  __shared__ float p3[256];
  __shared__ float sl[4];
  int blk = blockIdx.x;
  int g = blk >> 3, part = blk & 7;
  int b = g & 1, h = g >> 1;
  int t = threadIdx.x, lane = t & 63, w = t >> 6;
  size_t mlb = (size_t)(h * 2 + b) * HOPB;
  int i0 = part * 128;
  float ll = (t < 128) ? pl[mlb + i0 + t] : 0.f;
#pragma unroll
  for (int o = 32; o >= 1; o >>= 1) ll += __shfl_xor(ll, o);
  if (lane == 0) sl[w] = ll;
  int d = t & 63, seg = t >> 6;
  float a = 0.f;
  if (d < 48) {
#pragma unroll 8
    for (int i = i0 + seg; i < i0 + 128; i += 4)
      a += pa[(mlb + i) * 48 + d];
  }
  p3[seg * 64 + d] = a;
  __syncthreads();
  if (t < 48) {
    float av = p3[t] + p3[64 + t] + p3[128 + t] + p3[192 + t];
    atomicAdd(&QNn[(h * 2 + b) * 48 + t], av);
  }
  if (t == 0) atomicAdd(&LTn[h * 2 + b], sl[0] + sl[1] + sl[2] + sl[3]);
}

// final score pass: q from slot 5 on the fly; writes S + PL partials
__global__ __launch_bounds__(256) void k_escore(const unsigned short* __restrict__ KB,
                                                const float* __restrict__ Ap,
                                                const float* __restrict__ Lp,
                                                float* __restrict__ S,
                                                float* __restrict__ pl) {
  __shared__ float redl[4][128];
  int tid = threadIdx.x, blk = blockIdx.x;
  int w = tid >> 6, lane = tid & 63;
  int hb = w & 1, sub = w >> 1;
  int h = hb * 8 + (lane >> 3), p = lane & 7;
  float rl0 = SCALING_ / Lp[h * 2 + 0];
  float rl1 = SCALING_ / Lp[h * 2 + 1];
  float qv0[6], qv1[6];
#pragma unroll
  for (int j = 0; j < 6; ++j) {
    qv0[j] = rl0 * Ap[(h * 2 + 0) * 48 + p * 6 + j];
    qv1[j] = rl1 * Ap[(h * 2 + 1) * 48 + p * 6 + j];
  }
  float l0 = 0.f, l1 = 0.f;
  int n0 = blk * CBLK + sub * 49;
  int nend = n0 + 49;
  if (nend > NMEM) nend = NMEM;
#pragma unroll 4
  for (int n = n0; n < nend; ++n) {
    const unsigned short* ks = KB + (size_t)n * 768 + hb * 384 + lane * 6;
    float kf[6]; load6(ks, kf);
    float sc0 = 0.f, sc1 = 0.f;
#pragma unroll
    for (int j = 0; j < 6; ++j) {
      sc0 = fmaf(kf[j], qv0[j], sc0);
      sc1 = fmaf(kf[j], qv1[j], sc1);
    }
#pragma unroll
    for (int o = 1; o < 8; o <<= 1) {
      sc0 += __shfl_xor(sc0, o);
      sc1 += __shfl_xor(sc1, o);
    }
    if (p == 0) {
      S[(size_t)n * 32 + h]      = sc0;
      S[(size_t)n * 32 + 16 + h] = sc1;
    }
    l0 += __expf(sc0);
    l1 += __expf(sc1);
  }
  redl[w][lane * 2]     = l0;
  redl[w][lane * 2 + 1] = l1;
  __syncthreads();
  if (sub == 0) {
    l0 += redl[w + 2][lane * 2];
    l1 += redl[w + 2][lane * 2 + 1];
    if (p == 0) {
      pl[(size_t)(h * 2 + 0) * HOPB + blk] = l0;
      pl[(size_t)(h * 2 + 1) * HOPB + blk] = l1;
    }
  }
}

// merge -> C[bh] = log(sum l)
__global__ __launch_bounds__(256) void k_hredM(const float* __restrict__ pl,
                                               float* __restrict__ C) {
  int b = blockIdx.x & 1, h = blockIdx.x >> 1;
  __shared__ float sred[4];
  int t = threadIdx.x, lane = t & 63, w = t >> 6;
  size_t mlb = (size_t)(h * 2 + b) * HOPB;
  float ll = 0.f;
  for (int i = t; i < HOPB; i += 256) ll += pl[mlb + i];
#pragma unroll
  for (int o = 32; o >= 1; o >>= 1) ll += __shfl_xor(ll, o);
  if (lane == 0) sred[w] = ll;
  __syncthreads();
  if (t == 0) C[b * 16 + h] = logf(sred[0] + sred[1] + sred[2] + sred[3]);
}

// ------------------------- u-pass (fused wexp) ------------------------------
__global__ __launch_bounds__(256) void k_upass(const unsigned short* __restrict__ XH,
                                               const float* __restrict__ S,
                                               const float* __restrict__ C,
                                               float* __restrict__ UP) {
  __shared__ float SW[64 * 32];
  __shared__ float cc[32];
  int kb = blockIdx.x, t = threadIdx.x;
  if (t < 32) cc[t] = C[t];
  float a0[32], a1[32], a2[32];
#pragma unroll
  for (int i = 0; i < 32; ++i) { a0[i] = 0.f; a1[i] = 0.f; a2[i] = 0.f; }
  int n0 = kb * UROWS;
  int nend = n0 + UROWS; if (nend > NMEM) nend = NMEM;
  for (int ns = n0; ns < nend; ns += 64) {
    int sub = nend - ns; if (sub > 64) sub = 64;
    __syncthreads();
    for (int i = t; i < sub * 32; i += 256)
      SW[i] = __expf(S[(size_t)ns * 32 + i] - cc[i & 31]);
    __syncthreads();
    for (int r = 0; r < sub; ++r) {
      const unsigned short* xr = XH + (size_t)(ns + r) * 768;
      float x0 = bf2f(xr[t]), x1 = bf2f(xr[t + 256]), x2 = bf2f(xr[t + 512]);
      const float4* w4 = (const float4*)(SW + r * 32);
#pragma unroll
      for (int c = 0; c < 8; ++c) {
        float4 wv = w4[c];
        a0[c * 4 + 0] = fmaf(wv.x, x0, a0[c * 4 + 0]);
        a0[c * 4 + 1] = fmaf(wv.y, x0, a0[c * 4 + 1]);
        a0[c * 4 + 2] = fmaf(wv.z, x0, a0[c * 4 + 2]);
        a0[c * 4 + 3] = fmaf(wv.w, x0, a0[c * 4 + 3]);
        a1[c * 4 + 0] = fmaf(wv.x, x1, a1[c * 4 + 0]);
        a1[c * 4 + 1] = fmaf(wv.y, x1, a1[c * 4 + 1]);
        a1[c * 4 + 2] = fmaf(wv.z, x1, a1[c * 4 + 2]);
        a1[c * 4 + 3] = fmaf(wv.w, x1, a1[c * 4 + 3]);
        a2[c * 4 + 0] = fmaf(wv.x, x2, a2[c * 4 + 0]);
        a2[c * 4 + 1] = fmaf(wv.y, x2, a2[c * 4 + 1]);
        a2[c * 4 + 2] = fmaf(wv.z, x2, a2[c * 4 + 2]);
        a2[c * 4 + 3] = fmaf(wv.w, x2, a2[c * 4 + 3]);
      }
    }
  }
#pragma unroll
  for (int bh = 0; bh < 32; ++bh) {
    size_t base = ((size_t)kb * 32 + bh) * 768;
    UP[base + t]       = a0[bh];
    UP[base + 256 + t] = a1[bh];
    UP[base + 512 + t] = a2[bh];
  }
}

__global__ __launch_bounds__(256) void k_ured(const float* __restrict__ UP,
                                              float* __restrict__ U) {
  int o = blockIdx.x * 256 + threadIdx.x;
  float s0 = 0.f, s1 = 0.f, s2 = 0.f, s3 = 0.f;
#pragma unroll 4
  for (int kb = 0; kb < UKS; kb += 4) {
    s0 += UP[(size_t)(kb + 0) * 24576 + o];
    s1 += UP[(size_t)(kb + 1) * 24576 + o];
    s2 += UP[(size_t)(kb + 2) * 24576 + o];
    s3 += UP[(size_t)(kb + 3) * 24576 + o];
  }
  U[o] = (s0 + s1) + (s2 + s3);
}

__global__ __launch_bounds__(256) void k_outproj(const float* __restrict__ U,
                                                 const unsigned short* __restrict__ WT,
                                                 const float* __restrict__ BKV,
                                                 float* __restrict__ outa) {
  int gw = blockIdx.x * 4 + (threadIdx.x >> 6);
  int lane = threadIdx.x & 63;
  int b = gw >= 768;
  int j = gw - b * 768;
  int h = j / 48;
  const float* u = U + (size_t)(b * 16 + h) * 768;
  const unsigned short* wr = WT + (size_t)(768 + j) * 768;
  float a = 0.f;
  for (int d = lane; d < 768; d += 64) a = fmaf(u[d], bf2f(wr[d]), a);
#pragma unroll
  for (int o = 32; o >= 1; o >>= 1) a += __shfl_xor(a, o);
  if (lane == 0) outa[b * 768 + j] = a + BKV[768 + j];
}

// ------------------------- pooled / norm ------------------------------------
__global__ __launch_bounds__(256) void k_pooled(const float* __restrict__ outa,
                                                const float* __restrict__ Wo,
                                                const float* __restrict__ bo,
                                                float* __restrict__ dp) {
  __shared__ float xs[768];
  __shared__ float pr[256];
  int b = blockIdx.y, jc = blockIdx.x, t = threadIdx.x;
  xs[t]       = outa[b * 768 + t];
  xs[t + 256] = outa[b * 768 + 256 + t];
  xs[t + 512] = outa[b * 768 + 512 + t];
  __syncthreads();
  int w = t >> 6, lane = t & 63;
  int j = jc * 64 + lane;
  float a = 0.f;
  int d0 = w * 192;
  for (int d = d0; d < d0 + 192; ++d) a = fmaf(xs[d], Wo[(size_t)d * 768 + j], a);
  pr[t] = a;
  __syncthreads();
  if (t < 64) {
    float sv = pr[t] + pr[64 + t] + pr[128 + t] + pr[192 + t];
    int j2 = jc * 64 + t;
    dp[b * 768 + j2] = sv + bo[j2];
  }
}

__global__ __launch_bounds__(256) void k_pnorm(const float* __restrict__ dp,
                                               float* __restrict__ PN) {
  int b = blockIdx.x, t = threadIdx.x;
  __shared__ float sred[8];
  float x0 = dp[b * 768 + t], x1 = dp[b * 768 + 256 + t], x2 = dp[b * 768 + 512 + t];
  float s2 = x0 * x0 + x1 * x1 + x2 * x2;
#pragma unroll
  for (int o = 32; o >= 1; o >>= 1) s2 += __shfl_xor(s2, o);
  int lane = t & 63, w = t >> 6;
  if (lane == 0) sred[w] = s2;
  __syncthreads();
  float tot = sred[0] + sred[1] + sred[2] + sred[3];
  float rs = rsqrtf(tot);
  PN[b * 768 + t]       = x0 * rs;
  PN[b * 768 + 256 + t] = x1 * rs;
  PN[b * 768 + 512 + t] = x2 * rs;
}

// ------------------------- similarity + top-4 -------------------------------
__global__ __launch_bounds__(256) void k_sim(const float* __restrict__ mem,
                                             const float* __restrict__ PN,
                                             const float* __restrict__ rnorm,
                                             float* __restrict__ tval,
                                             int* __restrict__ tidx) {
  int gw = (blockIdx.x * 256 + threadIdx.x) >> 6;   // 8192 waves
  int lane = threadIdx.x & 63;
  const float4* pa = (const float4*)(PN);
  const float4* pb = (const float4*)(PN + 768);
  float4 qa0 = pa[lane], qa1 = pa[lane + 64], qa2 = pa[lane + 128];
  float4 qb0 = pb[lane], qb1 = pb[lane + 64], qb2 = pb[lane + 128];
  Top4 t0, t1; t0.init(); t1.init();
  int n0 = gw * 13;
  int nend = n0 + 13; if (nend > NMEM) nend = NMEM;
  for (int n = n0; n < nend; ++n) {
    const float4* r = (const float4*)(mem + (size_t)n * 768);
    float4 x0 = r[lane], x1 = r[lane + 64], x2 = r[lane + 128];
    float d0 = x0.x * qa0.x + x0.y * qa0.y + x0.z * qa0.z + x0.w * qa0.w +
               x1.x * qa1.x + x1.y * qa1.y + x1.z * qa1.z + x1.w * qa1.w +
               x2.x * qa2.x + x2.y * qa2.y + x2.z * qa2.z + x2.w * qa2.w;
    float d1 = x0.x * qb0.x + x0.y * qb0.y + x0.z * qb0.z + x0.w * qb0.w +
               x1.x * qb1.x + x1.y * qb1.y + x1.z * qb1.z + x1.w * qb1.w +
               x2.x * qb2.x + x2.y * qb2.y + x2.z * qb2.z + x2.w * qb2.w;
#pragma unroll
    for (int o = 32; o >= 1; o >>= 1) { d0 += __shfl_xor(d0, o); d1 += __shfl_xor(d1, o); }
    float rn = rnorm[n];
    t0.ins(d0 * rn, n);
    t1.ins(d1 * rn, n);
  }
  if (lane == 0) {
    int base = gw * 8;
    tval[base + 0] = t0.v0; tval[base + 1] = t0.v1; tval[base + 2] = t0.v2; tval[base + 3] = t0.v3;
    tval[base + 4] = t1.v0; tval[base + 5] = t1.v1; tval[base + 6] = t1.v2; tval[base + 7] = t1.v3;
    tidx[base + 0] = t0.i0; tidx[base + 1] = t0.i1; tidx[base + 2] = t0.i2; tidx[base + 3] = t0.i3;
    tidx[base + 4] = t1.i0; tidx[base + 5] = t1.i1; tidx[base + 6] = t1.i2; tidx[base + 7] = t1.i3;
  }
}

__global__ __launch_bounds__(256) void k_top1(const float* __restrict__ tval,
                                              const int* __restrict__ tidx,
                                              float* __restrict__ ptv,
                                              int* __restrict__ pti) {
  __shared__ float lv[4][8];
  __shared__ int   li[4][8];
  int z = blockIdx.x, t = threadIdx.x;
  int lane = t & 63, w = t >> 6;
  int wv = z * 256 + t;
  Top4 a, b; a.init(); b.init();
#pragma unroll
  for (int r = 0; r < 4; ++r) {
    a.ins(tval[wv * 8 + r],     tidx[wv * 8 + r]);
    b.ins(tval[wv * 8 + 4 + r], tidx[wv * 8 + 4 + r]);
  }
  bfly(a, 32);
  bfly(b, 32);
  if (lane == 0) {
    lv[w][0] = a.v0; lv[w][1] = a.v1; lv[w][2] = a.v2; lv[w][3] = a.v3;
    lv[w][4] = b.v0; lv[w][5] = b.v1; lv[w][6] = b.v2; lv[w][7] = b.v3;
    li[w][0] = a.i0; li[w][1] = a.i1; li[w][2] = a.i2; li[w][3] = a.i3;
    li[w][4] = b.i0; li[w][5] = b.i1; li[w][6] = b.i2; li[w][7] = b.i3;
  }
  __syncthreads();
  if (t < 2) {
    Top4 m_; m_.init();
#pragma unroll
    for (int w2 = 0; w2 < 4; ++w2)
#pragma unroll
      for (int r = 0; r < 4; ++r) m_.ins(lv[w2][t * 4 + r], li[w2][t * 4 + r]);
    int base = z * 8 + t * 4;
    ptv[base + 0] = m_.v0; ptv[base + 1] = m_.v1;
    ptv[base + 2] = m_.v2; ptv[base + 3] = m_.v3;
    pti[base + 0] = m_.i0; pti[base + 1] = m_.i1;
    pti[base + 2] = m_.i2; pti[base + 3] = m_.i3;
  }
}

__global__ __launch_bounds__(64) void k_top2(const float* __restrict__ ptv,
                                             const int* __restrict__ pti,
                                             float* __restrict__ dout) {
  int t = threadIdx.x;
  int half = t >> 5, e = t & 31;
  Top4 a; a.init();
#pragma unroll
  for (int r = 0; r < 4; ++r)
    a.ins(ptv[e * 8 + half * 4 + r], pti[e * 8 + half * 4 + r]);
  bfly(a, 16);
  if (e == 0) {
    dout[half * 4 + 0] = (float)a.i0;
    dout[half * 4 + 1] = (float)a.i1;
    dout[half * 4 + 2] = (float)a.i2;
    dout[half * 4 + 3] = (float)a.i3;
  }
}

// ---------------------------------------------------------------------------
extern "C" void kernel_launch(void* const* d_in, const int* in_sizes, int n_in,
                              void* d_out, int out_size, void* d_ws, size_t ws_size,
                              hipStream_t stream) {
  const float* qe     = (const float*)d_in[0];
  const float* mem    = (const float*)d_in[1];
  const float* ln_q_g = (const float*)d_in[2];
  const float* ln_q_b = (const float*)d_in[3];
  const float* ln_s_g = (const float*)d_in[4];
  const float* ln_s_b = (const float*)d_in[5];
  const float* ln_p_g = (const float*)d_in[6];
  const float* ln_p_b = (const float*)d_in[7];
  const float* Wq = (const float*)d_in[8];  const float* bq = (const float*)d_in[9];
  const float* Wk = (const float*)d_in[10]; const float* bk = (const float*)d_in[11];
  const float* Wv = (const float*)d_in[12]; const float* bv = (const float*)d_in[13];
  const float* Wo = (const float*)d_in[14]; const float* bo = (const float*)d_in[15];

  char* w = (char*)d_ws;
  size_t off = 0;
  auto alloc = [&](size_t bytes) {
    size_t o = off;
    off += (bytes + 255) & ~(size_t)255;
    return o;
  };
  unsigned short* WT   = (unsigned short*)(w + alloc((size_t)1536 * 768 * 2));
  float*          PB   = (float*)(w + alloc(8 * 1536 * 4));
  float*          BKV  = (float*)(w + alloc(1536 * 4));
  float*          QN   = (float*)(w + alloc(7 * 1536 * 4));
  float*          LT   = (float*)(w + alloc(7 * 32 * 4));
  float*          OUTA = (float*)(w + alloc(1536 * 4));
  float*          PN   = (float*)(w + alloc(1536 * 4));
  float*          CML  = (float*)(w + alloc(32 * 4));
  float*          UBUF = (float*)(w + alloc((size_t)24576 * 4));
  float*          RNORM= (float*)(w + alloc((size_t)NPAD * 4));
  unsigned short* XH   = (unsigned short*)(w + alloc((size_t)NPAD * 768 * 2));
  unsigned short* KB   = (unsigned short*)(w + alloc((size_t)NPAD * 768 * 2));
  float*          PA   = (float*)(w + alloc((size_t)32 * HOPB * 48 * 4));
  float*          PL   = (float*)(w + alloc((size_t)32 * HOPB * 4));
  float*          SB   = (float*)(w + alloc((size_t)NMEM * 32 * 4));
  float*          UP   = (float*)(w + alloc((size_t)UKS * 24576 * 4));
  float*          TVAL = (float*)(w + alloc((size_t)8192 * 8 * 4));
  int*            TIDX = (int*)(w + alloc((size_t)8192 * 8 * 4));
  float*          PTV  = (float*)(w + alloc((size_t)32 * 8 * 4));
  int*            PTI  = (int*)(w + alloc((size_t)32 * 8 * 4));
  if (off > ws_size) {
    fprintf(stderr, "[hopfield] ws too small: need %zu have %zu\n", off, ws_size);
    return;
  }
  float* dout = (float*)d_out;

  k_fold_wt  <<<dim3(12, 12, 2), 256, 0, stream>>>(Wk, Wv, ln_s_g, ln_p_g, WT);
  k_fold_bias<<<dim3(6, 8), 256, 0, stream>>>(Wk, Wv, ln_s_b, ln_p_b, PB);
  k_bias_red <<<6, 256, 0, stream>>>(PB, bk, bv, BKV);
  k_q0       <<<dim3(12, 2), 256, 0, stream>>>(qe, ln_q_g, ln_q_b, Wq, bq, QN, LT);
  k_ln       <<<1024, 256, 0, stream>>>(mem, XH, RNORM);
  k_gemm     <<<98 * 6 * 8, 512, 0, stream>>>(XH, WT, BKV, KB);
  for (int s = 0; s < 5; ++s) {
    k_hop    <<<HOPB, 256, 0, stream>>>(KB, QN, LT, QN, LT, PA, PL, s);
    k_hred   <<<256, 256, 0, stream>>>(PA, PL, QN + (s + 1) * 1536,
                                       LT + (s + 1) * 32);
  }
  k_escore   <<<HOPB, 256, 0, stream>>>(KB, QN + 5 * 1536, LT + 5 * 32, SB, PL);
  k_hredM    <<<32, 256, 0, stream>>>(PL, CML);
  k_upass    <<<UKS, 256, 0, stream>>>(XH, SB, CML, UP);
  k_ured     <<<96, 256, 0, stream>>>(UP, UBUF);
  k_outproj  <<<384, 256, 0, stream>>>(UBUF, WT, BKV, OUTA);
  k_pooled   <<<dim3(12, 2), 256, 0, stream>>>(OUTA, Wo, bo, dout + 8);
  k_pnorm    <<<2, 256, 0, stream>>>(dout + 8, PN);
  k_sim      <<<2048, 256, 0, stream>>>(mem, PN, RNORM, TVAL, TIDX);
  k_top1     <<<32, 256, 0, stream>>>(TVAL, TIDX, PTV, PTI);
  k_top2     <<<1, 64, 0, stream>>>(PTV, PTI, dout);
}

// Round 16
// 744.763 us; speedup vs baseline: 2.0252x; 1.0288x over previous
//
#include <hip/hip_runtime.h>
#include <cstdio>
#include <cstdint>

// ---------------------------------------------------------------------------
// HopfieldPoolingRouter on MI355X — V-free, fixed-base softmax, block-partial
// hops (2048 blocks, 8/CU) + 512-block split merges (16-way atomics),
// q recomputed on the fly. GEMM: 512-thread, 32x64 wave tiles, BK=64,
// XOR swizzle, counted vmcnt(4).
// ---------------------------------------------------------------------------

#define NMEM 100000
#define NPAD 100096          // 782 * 128
#define HOPB 2048            // hop-pass blocks; partials per (b,h)
#define CBLK 49              // rows per hop block (2048*49 >= 100000)
#define UKS  512
#define UROWS 196
#define SCALING_ 0.25f

typedef __attribute__((ext_vector_type(8))) short bf16x8;
typedef __attribute__((ext_vector_type(4))) float f32x4;

__device__ __forceinline__ unsigned short f2bf(float f) {
  union { float f; unsigned u; } c; c.f = f;
  unsigned u = c.u + 0x7fffu + ((c.u >> 16) & 1u);   // RNE
  return (unsigned short)(u >> 16);
}
__device__ __forceinline__ float bf2f(unsigned short h) {
  union { unsigned u; float f; } c; c.u = ((unsigned)h) << 16;
  return c.f;
}
__device__ __forceinline__ void gl_lds16(const void* g, void* l) {
  __builtin_amdgcn_global_load_lds(
      (const __attribute__((address_space(1))) unsigned int*)g,
      (__attribute__((address_space(3))) unsigned int*)l, 16, 0, 0);
}

__device__ __forceinline__ bool bet(float s, int n, float v, int i) {
  return (s > v) || (s == v && n < i);
}
struct Top4 {
  float v0, v1, v2, v3;
  int   i0, i1, i2, i3;
  __device__ __forceinline__ void init() {
    v0 = v1 = v2 = v3 = -INFINITY;
    i0 = i1 = i2 = i3 = 0x7fffffff;
  }
  __device__ __forceinline__ void ins(float s, int n) {
    bool c0 = bet(s, n, v0, i0), c1 = bet(s, n, v1, i1);
    bool c2 = bet(s, n, v2, i2), c3 = bet(s, n, v3, i3);
    float w0 = c0 ? s : v0;             int j0 = c0 ? n : i0;
    float w1 = c0 ? v0 : (c1 ? s : v1); int j1 = c0 ? i0 : (c1 ? n : i1);
    float w2 = c1 ? v1 : (c2 ? s : v2); int j2 = c1 ? i1 : (c2 ? n : i2);
    float w3 = c2 ? v2 : (c3 ? s : v3); int j3 = c2 ? i2 : (c3 ? n : i3);
    v0 = w0; v1 = w1; v2 = w2; v3 = w3;
    i0 = j0; i1 = j1; i2 = j2; i3 = j3;
  }
};
__device__ __forceinline__ void bfly(Top4& a, int omax) {
  for (int o = omax; o >= 1; o >>= 1) {
    float w0 = __shfl_xor(a.v0, o), w1 = __shfl_xor(a.v1, o);
    float w2 = __shfl_xor(a.v2, o), w3 = __shfl_xor(a.v3, o);
    int   j0 = __shfl_xor(a.i0, o), j1 = __shfl_xor(a.i1, o);
    int   j2 = __shfl_xor(a.i2, o), j3 = __shfl_xor(a.i3, o);
    a.ins(w0, j0); a.ins(w1, j1); a.ins(w2, j2); a.ins(w3, j3);
  }
}

// ------------------------- weight folding ----------------------------------
__global__ __launch_bounds__(256) void k_fold_wt(const float* __restrict__ Wk,
                                                 const float* __restrict__ Wv,
                                                 const float* __restrict__ gs,
                                                 const float* __restrict__ gp,
                                                 unsigned short* __restrict__ WT) {
  __shared__ float ts[64][65];
  int d0 = blockIdx.x * 64, j0 = blockIdx.y * 64, z = blockIdx.z;
  const float* W = z ? Wv : Wk;
  const float* g = z ? gp : gs;
  int t = threadIdx.x, c = t & 63, r4 = t >> 6;
#pragma unroll
  for (int p = 0; p < 16; ++p) {
    int r = p * 4 + r4;
    ts[r][c] = g[d0 + r] * W[(size_t)(d0 + r) * 768 + j0 + c];
  }
  __syncthreads();
#pragma unroll
  for (int p = 0; p < 16; ++p) {
    int jr = p * 4 + r4;
    WT[(size_t)(z * 768 + j0 + jr) * 768 + d0 + c] = f2bf(ts[c][jr]);
  }
}

__global__ __launch_bounds__(256) void k_fold_bias(const float* __restrict__ Wk,
                                                   const float* __restrict__ Wv,
                                                   const float* __restrict__ bs,
                                                   const float* __restrict__ bp,
                                                   float* __restrict__ PB) {
  int jc = blockIdx.x, dz = blockIdx.y, t = threadIdx.x;
  int j = jc * 256 + t;
  const float* W  = (j < 768) ? Wk : Wv;
  const float* bb = (j < 768) ? bs : bp;
  int jj = (j < 768) ? j : j - 768;
  float a = 0.f;
  int dend = dz * 96 + 96;
  for (int d = dz * 96; d < dend; ++d) a = fmaf(bb[d], W[(size_t)d * 768 + jj], a);
  PB[dz * 1536 + j] = a;
}

__global__ __launch_bounds__(256) void k_bias_red(const float* __restrict__ PB,
                                                  const float* __restrict__ bk,
                                                  const float* __restrict__ bv,
                                                  float* __restrict__ BKV) {
  int j = blockIdx.x * 256 + threadIdx.x;
  float a = (j < 768) ? bk[j] : bv[j - 768];
#pragma unroll
  for (int dz = 0; dz < 8; ++dz) a += PB[dz * 1536 + j];
  BKV[j] = a;
}

// ------------------------- q0 -> QN slot 0 (LT=1), zero slot 1 --------------
__global__ __launch_bounds__(256) void k_q0(const float* __restrict__ qe,
                                            const float* __restrict__ gq,
                                            const float* __restrict__ bq_ln,
                                            const float* __restrict__ Wq,
                                            const float* __restrict__ bq,
                                            float* __restrict__ QN,
                                            float* __restrict__ LT) {
  int b = blockIdx.y, jc = blockIdx.x, t = threadIdx.x;
  __shared__ float xs[768];
  __shared__ float sred[16];
  __shared__ float pr[256];
  if (jc == 0 && b == 0) {
    for (int i = t; i < 1536; i += 256) QN[1536 + i] = 0.f;
    if (t < 32) { LT[t] = 1.0f; LT[32 + t] = 0.f; }
  }
  float x0 = qe[b * 768 + t], x1 = qe[b * 768 + 256 + t], x2 = qe[b * 768 + 512 + t];
  float s = x0 + x1 + x2, s2 = x0 * x0 + x1 * x1 + x2 * x2;
#pragma unroll
  for (int o = 32; o >= 1; o >>= 1) { s += __shfl_xor(s, o); s2 += __shfl_xor(s2, o); }
  int lane = t & 63, w = t >> 6;
  if (lane == 0) { sred[w] = s; sred[8 + w] = s2; }
  __syncthreads();
  s  = sred[0] + sred[1] + sred[2] + sred[3];
  s2 = sred[8] + sred[9] + sred[10] + sred[11];
  float mean = s * (1.f / 768.f);
  float var  = s2 * (1.f / 768.f) - mean * mean;
  float rstd = rsqrtf(var + 1e-5f);
  xs[t]       = (x0 - mean) * rstd * gq[t]       + bq_ln[t];
  xs[t + 256] = (x1 - mean) * rstd * gq[t + 256] + bq_ln[t + 256];
  xs[t + 512] = (x2 - mean) * rstd * gq[t + 512] + bq_ln[t + 512];
  __syncthreads();
  int j = jc * 64 + lane;
  float a = 0.f;
  int d0 = w * 192;
  for (int d = d0; d < d0 + 192; ++d) a = fmaf(xs[d], Wq[(size_t)d * 768 + j], a);
  pr[t] = a;
  __syncthreads();
  if (t < 64) {
    float sv = pr[t] + pr[64 + t] + pr[128 + t] + pr[192 + t];
    int j2 = jc * 64 + t;
    int h = j2 / 48, dh = j2 - h * 48;
    QN[(h * 2 + b) * 48 + dh] = sv + bq[j2];   // slot 0, unscaled; LT0 = 1
  }
}

// ------------------------- memory LN + rnorm --------------------------------
__global__ __launch_bounds__(256) void k_ln(const float* __restrict__ mem,
                                            unsigned short* __restrict__ XH,
                                            float* __restrict__ rnorm) {
  int gw = (blockIdx.x * 256 + threadIdx.x) >> 6;   // 4096 waves
  int lane = threadIdx.x & 63;
  int n0 = gw * 25;
  int nend = n0 + 25; if (nend > NPAD) nend = NPAD;
  for (int n = n0; n < nend; ++n) {
    ushort4* orow = (ushort4*)(XH + (size_t)n * 768);
    if (n >= NMEM) {
      ushort4 z; z.x = z.y = z.z = z.w = 0;
      orow[lane] = z; orow[lane + 64] = z; orow[lane + 128] = z;
      continue;
    }
    const float4* r = (const float4*)(mem + (size_t)n * 768);
    float4 x0 = r[lane], x1 = r[lane + 64], x2 = r[lane + 128];
    float s  = x0.x + x0.y + x0.z + x0.w + x1.x + x1.y + x1.z + x1.w +
               x2.x + x2.y + x2.z + x2.w;
    float s2 = x0.x * x0.x + x0.y * x0.y + x0.z * x0.z + x0.w * x0.w +
               x1.x * x1.x + x1.y * x1.y + x1.z * x1.z + x1.w * x1.w +
               x2.x * x2.x + x2.y * x2.y + x2.z * x2.z + x2.w * x2.w;
#pragma unroll
    for (int o = 32; o >= 1; o >>= 1) { s += __shfl_xor(s, o); s2 += __shfl_xor(s2, o); }
    float mean = s * (1.f / 768.f);
    float var  = s2 * (1.f / 768.f) - mean * mean;
    float rstd = rsqrtf(var + 1e-5f);
    if (lane == 0) rnorm[n] = rsqrtf(s2);
    ushort4 o0, o1, o2;
    o0.x = f2bf((x0.x - mean) * rstd); o0.y = f2bf((x0.y - mean) * rstd);
    o0.z = f2bf((x0.z - mean) * rstd); o0.w = f2bf((x0.w - mean) * rstd);
    o1.x = f2bf((x1.x - mean) * rstd); o1.y = f2bf((x1.y - mean) * rstd);
    o1.z = f2bf((x1.z - mean) * rstd); o1.w = f2bf((x1.w - mean) * rstd);
    o2.x = f2bf((x2.x - mean) * rstd); o2.y = f2bf((x2.y - mean) * rstd);
    o2.z = f2bf((x2.z - mean) * rstd); o2.w = f2bf((x2.w - mean) * rstd);
    orow[lane] = o0; orow[lane + 64] = o1; orow[lane + 128] = o2;
  }
}

// ------------------------- projection GEMM (8 waves, 32x64 wave tiles) ------
__global__ __launch_bounds__(512) void k_gemm(const unsigned short* __restrict__ XH,
                                              const unsigned short* __restrict__ WT,
                                              const float* __restrict__ BKV,
                                              unsigned short* __restrict__ KB) {
  __shared__ __align__(16) unsigned short SM[32768];   // 2 x (A 16KB | B 16KB)
  int f = blockIdx.x;
  int xcd = f & 7, s = f >> 3;
  int g = s / 6, jt = s - g * 6;
  int mt = g * 8 + xcd;
  if (mt >= 782) return;
  int m0 = mt * 128, j0 = jt * 128;
  int tid = threadIdx.x;
  int wave = tid >> 6, lane = tid & 63;
  int wm = wave >> 1, wn = wave & 1;
  int fr_r = lane & 15, chb = lane >> 4;
  f32x4 acc[2][4] = {};

  auto stage = [&](int kt, int bb) {       // 4 gl_lds per thread
    unsigned short* As = SM + bb * 16384;
    unsigned short* Bs = As + 8192;
    int k0 = kt * 64;
#pragma unroll
    for (int it = 0; it < 2; ++it) {
      int c = it * 512 + tid;
      int row = c >> 3, kk = c & 7;
      int src = (kk ^ (row & 7)) * 8;
      gl_lds16(XH + (size_t)(m0 + row) * 768 + k0 + src, As + c * 8);
      gl_lds16(WT + (size_t)(j0 + row) * 768 + k0 + src, Bs + c * 8);
    }
  };

  stage(0, 0);
  int cur = 0;
  for (int kt = 0; kt < 12; ++kt) {
    if (kt < 11) {
      stage(kt + 1, cur ^ 1);
      asm volatile("s_waitcnt vmcnt(4)" ::: "memory");
    } else {
      asm volatile("s_waitcnt vmcnt(0)" ::: "memory");
    }
    __builtin_amdgcn_s_barrier();
    __builtin_amdgcn_sched_barrier(0);
    const unsigned short* As = SM + cur * 16384;
    const unsigned short* Bs = As + 8192;
    __builtin_amdgcn_s_setprio(1);
#pragma unroll
    for (int ks = 0; ks < 2; ++ks) {
      bf16x8 af[2], bfr[4];
#pragma unroll
      for (int ff = 0; ff < 2; ++ff) {
        int ra = wm * 32 + ff * 16 + fr_r;
        int cha = ((ks * 4 + chb) ^ (ra & 7)) * 8;
        af[ff] = *(const bf16x8*)(As + ra * 64 + cha);
      }
#pragma unroll
      for (int ff = 0; ff < 4; ++ff) {
        int rb = wn * 64 + ff * 16 + fr_r;
        int chbb = ((ks * 4 + chb) ^ (rb & 7)) * 8;
        bfr[ff] = *(const bf16x8*)(Bs + rb * 64 + chbb);
      }
#pragma unroll
      for (int fm = 0; fm < 2; ++fm)
#pragma unroll
        for (int fn = 0; fn < 4; ++fn)
          acc[fm][fn] = __builtin_amdgcn_mfma_f32_16x16x32_bf16(af[fm], bfr[fn],
                                                                acc[fm][fn], 0, 0, 0);
    }
    __builtin_amdgcn_s_setprio(0);
    __builtin_amdgcn_s_barrier();
    __builtin_amdgcn_sched_barrier(0);
    cur ^= 1;
  }
  int cr = (lane >> 4) * 4, cc = lane & 15;
#pragma unroll
  for (int fm = 0; fm < 2; ++fm)
#pragma unroll
    for (int fn = 0; fn < 4; ++fn) {
      int col = wn * 64 + fn * 16 + cc;
      float bias = BKV[j0 + col];
      int rb = (wm * 32 + fm * 16 + cr) * 128 + col;
#pragma unroll
      for (int i = 0; i < 4; ++i)
        SM[rb + i * 128] = f2bf(acc[fm][fn][i] + bias);
    }
  __syncthreads();
#pragma unroll
  for (int it = 0; it < 4; ++it) {
    int c = it * 512 + tid;
    int row = c >> 4, cg = c & 15;
    *(bf16x8*)(KB + (size_t)(m0 + row) * 768 + j0 + cg * 8) =
        *(const bf16x8*)(SM + row * 128 + cg * 8);
  }
}

// ------------------------- hop helpers --------------------------------------
__device__ __forceinline__ void load6(const unsigned short* p, float* o) {
  ushort2 a = *(const ushort2*)(p);
  ushort2 b = *(const ushort2*)(p + 2);
  ushort2 c = *(const ushort2*)(p + 4);
  o[0] = bf2f(a.x); o[1] = bf2f(a.y);
  o[2] = bf2f(b.x); o[3] = bf2f(b.y);
  o[4] = bf2f(c.x); o[5] = bf2f(c.y);
}

// hop pass s: q = 0.25*QN[s]/LT[s]; PA/PL block partials; blk0 zeroes slot s+2
// Block covers 49 rows: sub 0 -> 25 rows, sub 1 -> 24 rows.
__global__ __launch_bounds__(256) void k_hop(const unsigned short* __restrict__ KB,
                                             const float* __restrict__ QN,
                                             const float* __restrict__ LT,
                                             float* __restrict__ QNz,
                                             float* __restrict__ LTz,
                                             float* __restrict__ pa,
                                             float* __restrict__ pl,
                                             int s) {
  __shared__ float red[4][768];
  __shared__ float redl[4][128];
  int tid = threadIdx.x, blk = blockIdx.x;
  int w = tid >> 6, lane = tid & 63;
  int hb = w & 1, sub = w >> 1;
  if (blk == 0) {                      // zero slot s+2 for hred_{s+1}
    for (int i = tid; i < 1536; i += 256) QNz[(s + 2) * 1536 + i] = 0.f;
    if (tid < 32) LTz[(s + 2) * 32 + tid] = 0.f;
  }
  int h = hb * 8 + (lane >> 3), p = lane & 7;
  const float* Ap = QN + s * 1536;
  const float* Lp = LT + s * 32;
  float rl0 = SCALING_ / Lp[h * 2 + 0];
  float rl1 = SCALING_ / Lp[h * 2 + 1];
  float qv0[6], qv1[6];
#pragma unroll
  for (int j = 0; j < 6; ++j) {
    qv0[j] = rl0 * Ap[(h * 2 + 0) * 48 + p * 6 + j];
    qv1[j] = rl1 * Ap[(h * 2 + 1) * 48 + p * 6 + j];
  }
  float l0 = 0.f, l1 = 0.f;
  float acc0[6] = {}, acc1[6] = {};
  int n0 = blk * CBLK + sub * 25;
  int nend = n0 + (25 - sub);          // sub0: 25 rows, sub1: 24 rows
  if (nend > NMEM) nend = NMEM;
#pragma unroll 4
  for (int n = n0; n < nend; ++n) {
    const unsigned short* ks = KB + (size_t)n * 768 + hb * 384 + lane * 6;
    float kf[6]; load6(ks, kf);
    float sc0 = 0.f, sc1 = 0.f;
#pragma unroll
    for (int j = 0; j < 6; ++j) {
      sc0 = fmaf(kf[j], qv0[j], sc0);
      sc1 = fmaf(kf[j], qv1[j], sc1);
    }
#pragma unroll
    for (int o = 1; o < 8; o <<= 1) {
      sc0 += __shfl_xor(sc0, o);
      sc1 += __shfl_xor(sc1, o);
    }
    float e0 = __expf(sc0);
    float e1 = __expf(sc1);
    l0 += e0; l1 += e1;
#pragma unroll
    for (int j = 0; j < 6; ++j) {
      acc0[j] = fmaf(e0, kf[j], acc0[j]);
      acc1[j] = fmaf(e1, kf[j], acc1[j]);
    }
  }
#pragma unroll
  for (int j = 0; j < 6; ++j) {
    red[w][lane * 12 + j]     = acc0[j];
    red[w][lane * 12 + 6 + j] = acc1[j];
  }
  redl[w][lane * 2]     = l0;
  redl[w][lane * 2 + 1] = l1;
  __syncthreads();
  if (sub == 0) {
#pragma unroll
    for (int j = 0; j < 6; ++j) {
      acc0[j] += red[w + 2][lane * 12 + j];
      acc1[j] += red[w + 2][lane * 12 + 6 + j];
    }
    l0 += redl[w + 2][lane * 2];
    l1 += redl[w + 2][lane * 2 + 1];
    size_t b0 = ((size_t)(h * 2 + 0) * HOPB + blk) * 48 + p * 6;
    size_t b1 = ((size_t)(h * 2 + 1) * HOPB + blk) * 48 + p * 6;
#pragma unroll
    for (int j = 0; j < 6; ++j) { pa[b0 + j] = acc0[j]; pa[b1 + j] = acc1[j]; }
    if (p == 0) {
      pl[(size_t)(h * 2 + 0) * HOPB + blk] = l0;
      pl[(size_t)(h * 2 + 1) * HOPB + blk] = l1;
    }
  }
}

// split merge: 512 blocks (16 slices per (b,h)); 48 atomicAdds/block (16-way)
__global__ __launch_bounds__(256) void k_hred(const float* __restrict__ pa,
                                              const float* __restrict__ pl,
                                              float* __restrict__ QNn,
                                              float* __restrict__ LTn) {
  __shared__ float p3[256];
  __shared__ float sl[4];
  int blk = blockIdx.x;
  int g = blk >> 4, part = blk & 15;
  int b = g & 1, h = g >> 1;
  int t = threadIdx.x, lane = t & 63, w = t >> 6;
  size_t mlb = (size_t)(h * 2 + b) * HOPB;
  int i0 = part * 128;
  float ll = (t < 128) ? pl[mlb + i0 + t] : 0.f;
#pragma unroll
  for (int o = 32; o >= 1; o >>= 1) ll += __shfl_xor(ll, o);
  if (lane == 0) sl[w] = ll;
  int d = t & 63, seg = t >> 6;
  float a = 0.f;
  if (d < 48) {
#pragma unroll 8
    for (int i = i0 + seg; i < i0 + 128; i += 4)
      a += pa[(mlb + i) * 48 + d];
  }
  p3[seg * 64 + d] = a;
  __syncthreads();
  if (t < 48) {
    float av = p3[t] + p3[64 + t] + p3[128 + t] + p3[192 + t];
    atomicAdd(&QNn[(h * 2 + b) * 48 + t], av);
  }
  if (t == 0) atomicAdd(&LTn[h * 2 + b], sl[0] + sl[1] + sl[2] + sl[3]);
}

// final score pass: q from slot 5 on the fly; writes S + PL partials
__global__ __launch_bounds__(256) void k_escore(const unsigned short* __restrict__ KB,
                                                const float* __restrict__ Ap,
                                                const float* __restrict__ Lp,
                                                float* __restrict__ S,
                                                float* __restrict__ pl) {
  __shared__ float redl[4][128];
  int tid = threadIdx.x, blk = blockIdx.x;
  int w = tid >> 6, lane = tid & 63;
  int hb = w & 1, sub = w >> 1;
  int h = hb * 8 + (lane >> 3), p = lane & 7;
  float rl0 = SCALING_ / Lp[h * 2 + 0];
  float rl1 = SCALING_ / Lp[h * 2 + 1];
  float qv0[6], qv1[6];
#pragma unroll
  for (int j = 0; j < 6; ++j) {
    qv0[j] = rl0 * Ap[(h * 2 + 0) * 48 + p * 6 + j];
    qv1[j] = rl1 * Ap[(h * 2 + 1) * 48 + p * 6 + j];
  }
  float l0 = 0.f, l1 = 0.f;
  int n0 = blk * CBLK + sub * 25;
  int nend = n0 + (25 - sub);
  if (nend > NMEM) nend = NMEM;
#pragma unroll 4
  for (int n = n0; n < nend; ++n) {
    const unsigned short* ks = KB + (size_t)n * 768 + hb * 384 + lane * 6;
    float kf[6]; load6(ks, kf);
    float sc0 = 0.f, sc1 = 0.f;
#pragma unroll
    for (int j = 0; j < 6; ++j) {
      sc0 = fmaf(kf[j], qv0[j], sc0);
      sc1 = fmaf(kf[j], qv1[j], sc1);
    }
#pragma unroll
    for (int o = 1; o < 8; o <<= 1) {
      sc0 += __shfl_xor(sc0, o);
      sc1 += __shfl_xor(sc1, o);
    }
    if (p == 0) {
      S[(size_t)n * 32 + h]      = sc0;
      S[(size_t)n * 32 + 16 + h] = sc1;
    }
    l0 += __expf(sc0);
    l1 += __expf(sc1);
  }
  redl[w][lane * 2]     = l0;
  redl[w][lane * 2 + 1] = l1;
  __syncthreads();
  if (sub == 0) {
    l0 += redl[w + 2][lane * 2];
    l1 += redl[w + 2][lane * 2 + 1];
    if (p == 0) {
      pl[(size_t)(h * 2 + 0) * HOPB + blk] = l0;
      pl[(size_t)(h * 2 + 1) * HOPB + blk] = l1;
    }
  }
}

// merge -> C[bh] = log(sum l)
__global__ __launch_bounds__(256) void k_hredM(const float* __restrict__ pl,
                                               float* __restrict__ C) {
  int b = blockIdx.x & 1, h = blockIdx.x >> 1;
  __shared__ float sred[4];
  int t = threadIdx.x, lane = t & 63, w = t >> 6;
  size_t mlb = (size_t)(h * 2 + b) * HOPB;
  float ll = 0.f;
  for (int i = t; i < HOPB; i += 256) ll += pl[mlb + i];
#pragma unroll
  for (int o = 32; o >= 1; o >>= 1) ll += __shfl_xor(ll, o);
  if (lane == 0) sred[w] = ll;
  __syncthreads();
  if (t == 0) C[b * 16 + h] = logf(sred[0] + sred[1] + sred[2] + sred[3]);
}

// ------------------------- u-pass (fused wexp) ------------------------------
__global__ __launch_bounds__(256) void k_upass(const unsigned short* __restrict__ XH,
                                               const float* __restrict__ S,
                                               const float* __restrict__ C,
                                               float* __restrict__ UP) {
  __shared__ float SW[64 * 32];
  __shared__ float cc[32];
  int kb = blockIdx.x, t = threadIdx.x;
  if (t < 32) cc[t] = C[t];
  float a0[32], a1[32], a2[32];
#pragma unroll
  for (int i = 0; i < 32; ++i) { a0[i] = 0.f; a1[i] = 0.f; a2[i] = 0.f; }
  int n0 = kb * UROWS;
  int nend = n0 + UROWS; if (nend > NMEM) nend = NMEM;
  for (int ns = n0; ns < nend; ns += 64) {
    int sub = nend - ns; if (sub > 64) sub = 64;
    __syncthreads();
    for (int i = t; i < sub * 32; i += 256)
      SW[i] = __expf(S[(size_t)ns * 32 + i] - cc[i & 31]);
    __syncthreads();
    for (int r = 0; r < sub; ++r) {
      const unsigned short* xr = XH + (size_t)(ns + r) * 768;
      float x0 = bf2f(xr[t]), x1 = bf2f(xr[t + 256]), x2 = bf2f(xr[t + 512]);
      const float4* w4 = (const float4*)(SW + r * 32);
#pragma unroll
      for (int c = 0; c < 8; ++c) {
        float4 wv = w4[c];
        a0[c * 4 + 0] = fmaf(wv.x, x0, a0[c * 4 + 0]);
        a0[c * 4 + 1] = fmaf(wv.y, x0, a0[c * 4 + 1]);
        a0[c * 4 + 2] = fmaf(wv.z, x0, a0[c * 4 + 2]);
        a0[c * 4 + 3] = fmaf(wv.w, x0, a0[c * 4 + 3]);
        a1[c * 4 + 0] = fmaf(wv.x, x1, a1[c * 4 + 0]);
        a1[c * 4 + 1] = fmaf(wv.y, x1, a1[c * 4 + 1]);
        a1[c * 4 + 2] = fmaf(wv.z, x1, a1[c * 4 + 2]);
        a1[c * 4 + 3] = fmaf(wv.w, x1, a1[c * 4 + 3]);
        a2[c * 4 + 0] = fmaf(wv.x, x2, a2[c * 4 + 0]);
        a2[c * 4 + 1] = fmaf(wv.y, x2, a2[c * 4 + 1]);
        a2[c * 4 + 2] = fmaf(wv.z, x2, a2[c * 4 + 2]);
        a2[c * 4 + 3] = fmaf(wv.w, x2, a2[c * 4 + 3]);
      }
    }
  }
#pragma unroll
  for (int bh = 0; bh < 32; ++bh) {
    size_t base = ((size_t)kb * 32 + bh) * 768;
    UP[base + t]       = a0[bh];
    UP[base + 256 + t] = a1[bh];
    UP[base + 512 + t] = a2[bh];
  }
}

__global__ __launch_bounds__(256) void k_ured(const float* __restrict__ UP,
                                              float* __restrict__ U) {
  int o = blockIdx.x * 256 + threadIdx.x;
  float s0 = 0.f, s1 = 0.f, s2 = 0.f, s3 = 0.f;
#pragma unroll 4
  for (int kb = 0; kb < UKS; kb += 4) {
    s0 += UP[(size_t)(kb + 0) * 24576 + o];
    s1 += UP[(size_t)(kb + 1) * 24576 + o];
    s2 += UP[(size_t)(kb + 2) * 24576 + o];
    s3 += UP[(size_t)(kb + 3) * 24576 + o];
  }
  U[o] = (s0 + s1) + (s2 + s3);
}

__global__ __launch_bounds__(256) void k_outproj(const float* __restrict__ U,
                                                 const unsigned short* __restrict__ WT,
                                                 const float* __restrict__ BKV,
                                                 float* __restrict__ outa) {
  int gw = blockIdx.x * 4 + (threadIdx.x >> 6);
  int lane = threadIdx.x & 63;
  int b = gw >= 768;
  int j = gw - b * 768;
  int h = j / 48;
  const float* u = U + (size_t)(b * 16 + h) * 768;
  const unsigned short* wr = WT + (size_t)(768 + j) * 768;
  float a = 0.f;
  for (int d = lane; d < 768; d += 64) a = fmaf(u[d], bf2f(wr[d]), a);
#pragma unroll
  for (int o = 32; o >= 1; o >>= 1) a += __shfl_xor(a, o);
  if (lane == 0) outa[b * 768 + j] = a + BKV[768 + j];
}

// ------------------------- pooled / norm ------------------------------------
__global__ __launch_bounds__(256) void k_pooled(const float* __restrict__ outa,
                                                const float* __restrict__ Wo,
                                                const float* __restrict__ bo,
                                                float* __restrict__ dp) {
  __shared__ float xs[768];
  __shared__ float pr[256];
  int b = blockIdx.y, jc = blockIdx.x, t = threadIdx.x;
  xs[t]       = outa[b * 768 + t];
  xs[t + 256] = outa[b * 768 + 256 + t];
  xs[t + 512] = outa[b * 768 + 512 + t];
  __syncthreads();
  int w = t >> 6, lane = t & 63;
  int j = jc * 64 + lane;
  float a = 0.f;
  int d0 = w * 192;
  for (int d = d0; d < d0 + 192; ++d) a = fmaf(xs[d], Wo[(size_t)d * 768 + j], a);
  pr[t] = a;
  __syncthreads();
  if (t < 64) {
    float sv = pr[t] + pr[64 + t] + pr[128 + t] + pr[192 + t];
    int j2 = jc * 64 + t;
    dp[b * 768 + j2] = sv + bo[j2];
  }
}

__global__ __launch_bounds__(256) void k_pnorm(const float* __restrict__ dp,
                                               float* __restrict__ PN) {
  int b = blockIdx.x, t = threadIdx.x;
  __shared__ float sred[8];
  float x0 = dp[b * 768 + t], x1 = dp[b * 768 + 256 + t], x2 = dp[b * 768 + 512 + t];
  float s2 = x0 * x0 + x1 * x1 + x2 * x2;
#pragma unroll
  for (int o = 32; o >= 1; o >>= 1) s2 += __shfl_xor(s2, o);
  int lane = t & 63, w = t >> 6;
  if (lane == 0) sred[w] = s2;
  __syncthreads();
  float tot = sred[0] + sred[1] + sred[2] + sred[3];
  float rs = rsqrtf(tot);
  PN[b * 768 + t]       = x0 * rs;
  PN[b * 768 + 256 + t] = x1 * rs;
  PN[b * 768 + 512 + t] = x2 * rs;
}

// ------------------------- similarity + top-4 -------------------------------
__global__ __launch_bounds__(256) void k_sim(const float* __restrict__ mem,
                                             const float* __restrict__ PN,
                                             const float* __restrict__ rnorm,
                                             float* __restrict__ tval,
                                             int* __restrict__ tidx) {
  int gw = (blockIdx.x * 256 + threadIdx.x) >> 6;   // 8192 waves
  int lane = threadIdx.x & 63;
  const float4* pa = (const float4*)(PN);
  const float4* pb = (const float4*)(PN + 768);
  float4 qa0 = pa[lane], qa1 = pa[lane + 64], qa2 = pa[lane + 128];
  float4 qb0 = pb[lane], qb1 = pb[lane + 64], qb2 = pb[lane + 128];
  Top4 t0, t1; t0.init(); t1.init();
  int n0 = gw * 13;
  int nend = n0 + 13; if (nend > NMEM) nend = NMEM;
  for (int n = n0; n < nend; ++n) {
    const float4* r = (const float4*)(mem + (size_t)n * 768);
    float4 x0 = r[lane], x1 = r[lane + 64], x2 = r[lane + 128];
    float d0 = x0.x * qa0.x + x0.y * qa0.y + x0.z * qa0.z + x0.w * qa0.w +
               x1.x * qa1.x + x1.y * qa1.y + x1.z * qa1.z + x1.w * qa1.w +
               x2.x * qa2.x + x2.y * qa2.y + x2.z * qa2.z + x2.w * qa2.w;
    float d1 = x0.x * qb0.x + x0.y * qb0.y + x0.z * qb0.z + x0.w * qb0.w +
               x1.x * qb1.x + x1.y * qb1.y + x1.z * qb1.z + x1.w * qb1.w +
               x2.x * qb2.x + x2.y * qb2.y + x2.z * qb2.z + x2.w * qb2.w;
#pragma unroll
    for (int o = 32; o >= 1; o >>= 1) { d0 += __shfl_xor(d0, o); d1 += __shfl_xor(d1, o); }
    float rn = rnorm[n];
    t0.ins(d0 * rn, n);
    t1.ins(d1 * rn, n);
  }
  if (lane == 0) {
    int base = gw * 8;
    tval[base + 0] = t0.v0; tval[base + 1] = t0.v1; tval[base + 2] = t0.v2; tval[base + 3] = t0.v3;
    tval[base + 4] = t1.v0; tval[base + 5] = t1.v1; tval[base + 6] = t1.v2; tval[base + 7] = t1.v3;
    tidx[base + 0] = t0.i0; tidx[base + 1] = t0.i1; tidx[base + 2] = t0.i2; tidx[base + 3] = t0.i3;
    tidx[base + 4] = t1.i0; tidx[base + 5] = t1.i1; tidx[base + 6] = t1.i2; tidx[base + 7] = t1.i3;
  }
}

__global__ __launch_bounds__(256) void k_top1(const float* __restrict__ tval,
                                              const int* __restrict__ tidx,
                                              float* __restrict__ ptv,
                                              int* __restrict__ pti) {
  __shared__ float lv[4][8];
  __shared__ int   li[4][8];
  int z = blockIdx.x, t = threadIdx.x;
  int lane = t & 63, w = t >> 6;
  int wv = z * 256 + t;
  Top4 a, b; a.init(); b.init();
#pragma unroll
  for (int r = 0; r < 4; ++r) {
    a.ins(tval[wv * 8 + r],     tidx[wv * 8 + r]);
    b.ins(tval[wv * 8 + 4 + r], tidx[wv * 8 + 4 + r]);
  }
  bfly(a, 32);
  bfly(b, 32);
  if (lane == 0) {
    lv[w][0] = a.v0; lv[w][1] = a.v1; lv[w][2] = a.v2; lv[w][3] = a.v3;
    lv[w][4] = b.v0; lv[w][5] = b.v1; lv[w][6] = b.v2; lv[w][7] = b.v3;
    li[w][0] = a.i0; li[w][1] = a.i1; li[w][2] = a.i2; li[w][3] = a.i3;
    li[w][4] = b.i0; li[w][5] = b.i1; li[w][6] = b.i2; li[w][7] = b.i3;
  }
  __syncthreads();
  if (t < 2) {
    Top4 m_; m_.init();
#pragma unroll
    for (int w2 = 0; w2 < 4; ++w2)
#pragma unroll
      for (int r = 0; r < 4; ++r) m_.ins(lv[w2][t * 4 + r], li[w2][t * 4 + r]);
    int base = z * 8 + t * 4;
    ptv[base + 0] = m_.v0; ptv[base + 1] = m_.v1;
    ptv[base + 2] = m_.v2; ptv[base + 3] = m_.v3;
    pti[base + 0] = m_.i0; pti[base + 1] = m_.i1;
    pti[base + 2] = m_.i2; pti[base + 3] = m_.i3;
  }
}

__global__ __launch_bounds__(64) void k_top2(const float* __restrict__ ptv,
                                             const int* __restrict__ pti,
                                             float* __restrict__ dout) {
  int t = threadIdx.x;
  int half = t >> 5, e = t & 31;
  Top4 a; a.init();
#pragma unroll
  for (int r = 0; r < 4; ++r)
    a.ins(ptv[e * 8 + half * 4 + r], pti[e * 8 + half * 4 + r]);
  bfly(a, 16);
  if (e == 0) {
    dout[half * 4 + 0] = (float)a.i0;
    dout[half * 4 + 1] = (float)a.i1;
    dout[half * 4 + 2] = (float)a.i2;
    dout[half * 4 + 3] = (float)a.i3;
  }
}

// ---------------------------------------------------------------------------
extern "C" void kernel_launch(void* const* d_in, const int* in_sizes, int n_in,
                              void* d_out, int out_size, void* d_ws, size_t ws_size,
                              hipStream_t stream) {
  const float* qe     = (const float*)d_in[0];
  const float* mem    = (const float*)d_in[1];
  const float* ln_q_g = (const float*)d_in[2];
  const float* ln_q_b = (const float*)d_in[3];
  const float* ln_s_g = (const float*)d_in[4];
  const float* ln_s_b = (const float*)d_in[5];
  const float* ln_p_g = (const float*)d_in[6];
  const float* ln_p_b = (const float*)d_in[7];
  const float* Wq = (const float*)d_in[8];  const float* bq = (const float*)d_in[9];
  const float* Wk = (const float*)d_in[10]; const float* bk = (const float*)d_in[11];
  const float* Wv = (const float*)d_in[12]; const float* bv = (const float*)d_in[13];
  const float* Wo = (const float*)d_in[14]; const float* bo = (const float*)d_in[15];

  char* w = (char*)d_ws;
  size_t off = 0;
  auto alloc = [&](size_t bytes) {
    size_t o = off;
    off += (bytes + 255) & ~(size_t)255;
    return o;
  };
  unsigned short* WT   = (unsigned short*)(w + alloc((size_t)1536 * 768 * 2));
  float*          PB   = (float*)(w + alloc(8 * 1536 * 4));
  float*          BKV  = (float*)(w + alloc(1536 * 4));
  float*          QN   = (float*)(w + alloc(7 * 1536 * 4));
  float*          LT   = (float*)(w + alloc(7 * 32 * 4));
  float*          OUTA = (float*)(w + alloc(1536 * 4));
  float*          PN   = (float*)(w + alloc(1536 * 4));
  float*          CML  = (float*)(w + alloc(32 * 4));
  float*          UBUF = (float*)(w + alloc((size_t)24576 * 4));
  float*          RNORM= (float*)(w + alloc((size_t)NPAD * 4));
  unsigned short* XH   = (unsigned short*)(w + alloc((size_t)NPAD * 768 * 2));
  unsigned short* KB   = (unsigned short*)(w + alloc((size_t)NPAD * 768 * 2));
  float*          PA   = (float*)(w + alloc((size_t)32 * HOPB * 48 * 4));
  float*          PL   = (float*)(w + alloc((size_t)32 * HOPB * 4));
  float*          SB   = (float*)(w + alloc((size_t)NMEM * 32 * 4));
  float*          UP   = (float*)(w + alloc((size_t)UKS * 24576 * 4));
  float*          TVAL = (float*)(w + alloc((size_t)8192 * 8 * 4));
  int*            TIDX = (int*)(w + alloc((size_t)8192 * 8 * 4));
  float*          PTV  = (float*)(w + alloc((size_t)32 * 8 * 4));
  int*            PTI  = (int*)(w + alloc((size_t)32 * 8 * 4));
  if (off > ws_size) {
    fprintf(stderr, "[hopfield] ws too small: need %zu have %zu\n", off, ws_size);
    return;
  }
  float* dout = (float*)d_out;

  k_fold_wt  <<<dim3(12, 12, 2), 256, 0, stream>>>(Wk, Wv, ln_s_g, ln_p_g, WT);
  k_fold_bias<<<dim3(6, 8), 256, 0, stream>>>(Wk, Wv, ln_s_b, ln_p_b, PB);
  k_bias_red <<<6, 256, 0, stream>>>(PB, bk, bv, BKV);
  k_q0       <<<dim3(12, 2), 256, 0, stream>>>(qe, ln_q_g, ln_q_b, Wq, bq, QN, LT);
  k_ln       <<<1024, 256, 0, stream>>>(mem, XH, RNORM);
  k_gemm     <<<98 * 6 * 8, 512, 0, stream>>>(XH, WT, BKV, KB);
  for (int s = 0; s < 5; ++s) {
    k_hop    <<<HOPB, 256, 0, stream>>>(KB, QN, LT, QN, LT, PA, PL, s);
    k_hred   <<<512, 256, 0, stream>>>(PA, PL, QN + (s + 1) * 1536,
                                       LT + (s + 1) * 32);
  }
  k_escore   <<<HOPB, 256, 0, stream>>>(KB, QN + 5 * 1536, LT + 5 * 32, SB, PL);
  k_hredM    <<<32, 256, 0, stream>>>(PL, CML);
  k_upass    <<<UKS, 256, 0, stream>>>(XH, SB, CML, UP);
  k_ured     <<<96, 256, 0, stream>>>(UP, UBUF);
  k_outproj  <<<384, 256, 0, stream>>>(UBUF, WT, BKV, OUTA);
  k_pooled   <<<dim3(12, 2), 256, 0, stream>>>(OUTA, Wo, bo, dout + 8);
  k_pnorm    <<<2, 256, 0, stream>>>(dout + 8, PN);
  k_sim      <<<2048, 256, 0, stream>>>(mem, PN, RNORM, TVAL, TIDX);
  k_top1     <<<32, 256, 0, stream>>>(TVAL, TIDX, PTV, PTI);
  k_top2     <<<1, 64, 0, stream>>>(PTV, PTI, dout);
}